// Round 2
// baseline (26916.333 us; speedup 1.0000x reference)
//
#include <hip/hip_runtime.h>
#include <hip/hip_bf16.h>

#define N_NODES 100000
#define N_EDGES 300000
#define N_GRAPHS 128
#define NODE_VOCAB 200
#define NODE_DIM 128
#define EDGE_DIM 64
#define K_LAYERS 3

// ---------------- static device scratch (no reliance on ws_size) ----------------
__device__ float g_h[2][(size_t)N_NODES * NODE_DIM];      // ping-pong node state
__device__ float g_ebuf[(size_t)2 * N_EDGES * EDGE_DIM];  // edge state [e_in | e_out]
__device__ float g_XWe[(size_t)N_NODES * 256];            // [XA_in|XC_in|XA_out|XC_out]
__device__ float g_XWx[(size_t)N_NODES * 256];            // [xi | xo]
__device__ float g_Wcat[128 * 512];
__device__ float g_wbuf[(size_t)2 * N_EDGES];
__device__ float g_gsum[2][N_GRAPHS * NODE_DIM];
__device__ float g_cnt[2][N_GRAPHS];
__device__ float g_H[N_GRAPHS * NODE_DIM];

// ---------------- node argmax + embed: g_h[0][n] = node_emb[argmax(x[n])] ----------------
__global__ void node_embed_kernel(const float* __restrict__ x, const float* __restrict__ emb,
                                  int N) {
    int wave = threadIdx.x >> 6;
    int lane = threadIdx.x & 63;
    int n = blockIdx.x * 4 + wave;
    if (n >= N) return;
    const float* xr = x + (size_t)n * NODE_VOCAB;
    float v = xr[lane];
    int idx = lane;
    float nv = xr[lane + 64];
    if (nv > v) { v = nv; idx = lane + 64; }
    nv = xr[lane + 128];
    if (nv > v) { v = nv; idx = lane + 128; }
    if (lane < NODE_VOCAB - 192) {
        nv = xr[lane + 192];
        if (nv > v) { v = nv; idx = lane + 192; }
    }
    #pragma unroll
    for (int off = 32; off; off >>= 1) {
        float ov = __shfl_xor(v, off);
        int oi = __shfl_xor(idx, off);
        if (ov > v || (ov == v && oi < idx)) { v = ov; idx = oi; }
    }
    const float* er = emb + (size_t)idx * NODE_DIM;
    g_h[0][(size_t)n * NODE_DIM + lane] = er[lane];
    g_h[0][(size_t)n * NODE_DIM + 64 + lane] = er[64 + lane];
}

// ---------------- edge argmax + embed: g_ebuf[m] = edge_emb[argmax(ea[m])], m < 2E ----------------
__global__ void edge_embed_kernel(const float* __restrict__ ea, const float* __restrict__ emb,
                                  int M) {
    __shared__ int sidx[256];
    __shared__ float semb[8 * 64];
    int t = threadIdx.x;
    if (t < 128) {
        *(float4*)&semb[t * 4] = *(const float4*)(emb + t * 4);
    }
    long eg = (long)blockIdx.x * 256 + t;
    int best = 0;
    if (eg < M) {
        const float* ar = ea + eg * 8;
        float4 v0 = *(const float4*)ar;
        float4 v1 = *(const float4*)(ar + 4);
        float vals[8] = {v0.x, v0.y, v0.z, v0.w, v1.x, v1.y, v1.z, v1.w};
        float bv = vals[0];
        #pragma unroll
        for (int i = 1; i < 8; ++i)
            if (vals[i] > bv) { bv = vals[i]; best = i; }
    }
    sidx[t] = best;
    __syncthreads();
    long base = (long)blockIdx.x * 256 * 64;
    #pragma unroll 4
    for (int i = 0; i < 64; ++i) {
        long id = (long)i * 256 + t;
        int el = (int)(id >> 6);
        int d = (int)(id & 63);
        long eg2 = (long)blockIdx.x * 256 + el;
        if (eg2 < M) g_ebuf[base + id] = semb[sidx[el] * 64 + d];
    }
}

// ---------------- assemble Wcat (128 x 512) ----------------
// cols: [XA_in(64) | XC_in(64) | XA_out(64) | XC_out(64) | xi(128) | xo(128)]
__global__ void assemble_wcat(const float* __restrict__ Wi0, const float* __restrict__ Wo0,
                              const float* __restrict__ Wgi, const float* __restrict__ Wgo) {
    int idx = blockIdx.x * 256 + threadIdx.x;
    int kd = idx >> 9;
    int j = idx & 511;
    float v;
    if (j < 64) v = Wi0[kd * 64 + j];
    else if (j < 128) v = Wi0[(192 + kd) * 64 + (j - 64)];
    else if (j < 192) v = Wo0[kd * 64 + (j - 128)];
    else if (j < 256) v = Wo0[(192 + kd) * 64 + (j - 192)];
    else if (j < 384) v = Wgi[kd * 128 + (j - 256)];
    else v = Wgo[kd * 128 + (j - 384)];
    g_Wcat[idx] = v;
}

// ---------------- node GEMM: [XWe | XWx] = g_h[cur] (M x 128) @ Wcat (128 x 512) ----------------
__global__ __launch_bounds__(256) void gemm_xw_kernel(int cur, int M) {
    const float* __restrict__ A = g_h[cur];
    int m0 = blockIdx.x * 64;
    int n0 = blockIdx.y * 64;
    __shared__ float As[32][68];
    __shared__ float Bs[32][64];
    int t = threadIdx.x;
    int tx = t & 15, ty = t >> 4;
    float acc[4][4] = {};
    for (int k0 = 0; k0 < 128; k0 += 32) {
        #pragma unroll
        for (int i = 0; i < 2; ++i) {
            int idx = t + i * 256;
            int m = idx >> 3;
            int f = idx & 7;
            int gm = m0 + m;
            float4 v = (gm < M) ? *(const float4*)(A + (size_t)gm * 128 + k0 + f * 4)
                                : make_float4(0.f, 0.f, 0.f, 0.f);
            As[f * 4 + 0][m] = v.x;
            As[f * 4 + 1][m] = v.y;
            As[f * 4 + 2][m] = v.z;
            As[f * 4 + 3][m] = v.w;
        }
        #pragma unroll
        for (int i = 0; i < 2; ++i) {
            int idx = t + i * 256;
            int k = idx >> 4;
            int f = idx & 15;
            *(float4*)&Bs[k][f * 4] = *(const float4*)(g_Wcat + (size_t)(k0 + k) * 512 + n0 + f * 4);
        }
        __syncthreads();
        #pragma unroll
        for (int k = 0; k < 32; ++k) {
            float4 a4 = *(const float4*)&As[k][ty * 4];
            float4 b4 = *(const float4*)&Bs[k][tx * 4];
            float av[4] = {a4.x, a4.y, a4.z, a4.w};
            float bv[4] = {b4.x, b4.y, b4.z, b4.w};
            #pragma unroll
            for (int i = 0; i < 4; ++i)
                #pragma unroll
                for (int j = 0; j < 4; ++j)
                    acc[i][j] = fmaf(av[i], bv[j], acc[i][j]);
        }
        __syncthreads();
    }
    #pragma unroll
    for (int i = 0; i < 4; ++i) {
        int gm = m0 + ty * 4 + i;
        if (gm >= M) continue;
        int cj = n0 + tx * 4;
        float* dst = (cj < 256) ? (g_XWe + (size_t)gm * 256 + cj)
                                : (g_XWx + (size_t)gm * 256 + (cj - 256));
        float4 o = {acc[i][0], acc[i][1], acc[i][2], acc[i][3]};
        *(float4*)dst = o;
    }
}

// ---------------- edge update (in-place): e = e @ Wmid + gathered XA + XC ----------------
__global__ __launch_bounds__(256) void edge_update_kernel(const int* __restrict__ row,
                                                          const int* __restrict__ col,
                                                          const float* __restrict__ Wmid_in,
                                                          const float* __restrict__ Wmid_out,
                                                          int E) {
    int b = blockIdx.y;
    int e0 = blockIdx.x * 64;
    const float* Wmid = b ? Wmid_out : Wmid_in;
    float* ebuf = g_ebuf + (size_t)b * E * 64;
    __shared__ float As[64][68];
    __shared__ float Bs[64][64];
    int t = threadIdx.x;
    #pragma unroll
    for (int i = 0; i < 4; ++i) {
        int idx = t + i * 256;
        int m = idx >> 4;
        int f = idx & 15;
        int eg = e0 + m;
        float4 v = (eg < E) ? *(const float4*)(ebuf + (size_t)eg * 64 + f * 4)
                            : make_float4(0.f, 0.f, 0.f, 0.f);
        As[f * 4 + 0][m] = v.x;
        As[f * 4 + 1][m] = v.y;
        As[f * 4 + 2][m] = v.z;
        As[f * 4 + 3][m] = v.w;
    }
    #pragma unroll
    for (int i = 0; i < 4; ++i) {
        int idx = t + i * 256;
        int k = idx >> 4;
        int f = idx & 15;
        *(float4*)&Bs[k][f * 4] = *(const float4*)(Wmid + k * 64 + f * 4);
    }
    __syncthreads();
    int tx = t & 15, ty = t >> 4;
    float acc[4][4] = {};
    #pragma unroll 16
    for (int k = 0; k < 64; ++k) {
        float4 a4 = *(const float4*)&As[k][ty * 4];
        float4 b4 = *(const float4*)&Bs[k][tx * 4];
        float av[4] = {a4.x, a4.y, a4.z, a4.w};
        float bv[4] = {b4.x, b4.y, b4.z, b4.w};
        #pragma unroll
        for (int i = 0; i < 4; ++i)
            #pragma unroll
            for (int j = 0; j < 4; ++j)
                acc[i][j] = fmaf(av[i], bv[j], acc[i][j]);
    }
    #pragma unroll
    for (int i = 0; i < 4; ++i) {
        int eg = e0 + ty * 4 + i;
        if (eg >= E) continue;
        int r = row[eg], c = col[eg];
        int ga = b ? c : r;
        int ja = b ? 128 : 0;
        int gc = b ? r : c;
        int jc = b ? 192 : 64;
        int j0 = tx * 4;
        float4 x1 = *(const float4*)(g_XWe + (size_t)ga * 256 + ja + j0);
        float4 x2 = *(const float4*)(g_XWe + (size_t)gc * 256 + jc + j0);
        float4 o;
        o.x = acc[i][0] + x1.x + x2.x;
        o.y = acc[i][1] + x1.y + x2.y;
        o.z = acc[i][2] + x1.z + x2.z;
        o.w = acc[i][3] + x1.w + x2.w;
        *(float4*)(ebuf + (size_t)eg * 64 + j0) = o;
    }
}

// ---------------- gate: w[m] = sigmoid(e[m] . W1), m < 2E ----------------
__global__ void wgate_kernel(const float* __restrict__ W1_in,
                             const float* __restrict__ W1_out, int E) {
    long idx = (long)blockIdx.x * 256 + threadIdx.x;
    if (idx >= 2L * E) return;
    const float* W1 = (idx < E) ? W1_in : W1_out;
    const float* er = g_ebuf + idx * 64;
    float acc = 0.f;
    #pragma unroll
    for (int j = 0; j < 64; j += 4) {
        float4 ev = *(const float4*)(er + j);
        acc += ev.x * W1[j] + ev.y * W1[j + 1] + ev.z * W1[j + 2] + ev.w * W1[j + 3];
    }
    g_wbuf[idx] = 1.0f / (1.0f + expf(-acc));
}

// ---------------- x_next init: g_h[cur^1] = g_h[cur] + bg_in + bg_out ----------------
__global__ void xinit_kernel(int cur, const float* __restrict__ bgi,
                             const float* __restrict__ bgo, int N) {
    long idx = (long)blockIdx.x * 256 + threadIdx.x;  // over N*32 float4s
    if (idx >= (long)N * 32) return;
    int d4 = (int)(idx & 31);
    float4 hv = *(const float4*)(g_h[cur] + idx * 4);
    float4 bi = *(const float4*)(bgi + d4 * 4);
    float4 bo = *(const float4*)(bgo + d4 * 4);
    float4 o = {hv.x + bi.x + bo.x, hv.y + bi.y + bo.y, hv.z + bi.z + bo.z, hv.w + bi.w + bo.w};
    *(float4*)(g_h[cur ^ 1] + idx * 4) = o;
}

// ---------------- scatter: g_h[cur^1][dst] += w[e] * XWx[src] ----------------
__global__ void scatter_kernel(int cur, const int* __restrict__ row,
                               const int* __restrict__ col, int E) {
    int b = blockIdx.y;
    long idx = (long)blockIdx.x * 256 + threadIdx.x;
    if (idx >= (long)E * 4) return;
    int e = (int)(idx >> 2);
    int q = (int)(idx & 3);
    float wv = g_wbuf[(size_t)b * E + e];
    int s = b ? col[e] : row[e];
    int dn = b ? row[e] : col[e];
    const float* src = g_XWx + (size_t)s * 256 + (b ? 128 : 0) + q * 32;
    float* dst = g_h[cur ^ 1] + (size_t)dn * 128 + q * 32;
    #pragma unroll
    for (int j = 0; j < 32; j += 4) {
        float4 v = *(const float4*)(src + j);
        atomicAdd(dst + j + 0, wv * v.x);
        atomicAdd(dst + j + 1, wv * v.y);
        atomicAdd(dst + j + 2, wv * v.z);
        atomicAdd(dst + j + 3, wv * v.w);
    }
}

// ---------------- mean-pool partials ----------------
__global__ void pool_kernel(int fin, int side, const int* __restrict__ batch, int N) {
    const float* x = g_h[fin];
    float* gsum = g_gsum[side];
    int n0 = blockIdx.x * 128;
    int d = threadIdx.x;  // 128 threads
    if (n0 >= N) return;
    int nend = min(n0 + 128, N);
    float acc = 0.f;
    int curg = batch[n0];
    for (int n = n0; n < nend; ++n) {
        int g = batch[n];
        if (g != curg) {
            atomicAdd(&gsum[curg * 128 + d], acc);
            acc = 0.f;
            curg = g;
        }
        acc += x[(size_t)n * 128 + d];
    }
    atomicAdd(&gsum[curg * 128 + d], acc);
}

__global__ void count_kernel(int side, const int* __restrict__ batch, int N) {
    int g = threadIdx.x;  // 128 threads
    int lo = 0, hi = N;
    while (lo < hi) { int mid = (lo + hi) >> 1; if (batch[mid] < g) lo = mid + 1; else hi = mid; }
    int a = lo;
    lo = 0; hi = N;
    while (lo < hi) { int mid = (lo + hi) >> 1; if (batch[mid] < g + 1) lo = mid + 1; else hi = mid; }
    g_cnt[side][g] = (float)(lo - a);
}

__global__ void zero_gsum_kernel() {
    int i = blockIdx.x * 256 + threadIdx.x;
    if (i < 2 * N_GRAPHS * NODE_DIM) ((float*)g_gsum)[i] = 0.f;
}

// ---------------- classifier ----------------
__global__ void hidden_kernel(const float* __restrict__ W0, const float* __restrict__ b0) {
    int g = blockIdx.x;
    int j = threadIdx.x;  // 128 x 128
    float inv_s = 1.0f / fmaxf(g_cnt[0][g], 1.0f);
    float inv_t = 1.0f / fmaxf(g_cnt[1][g], 1.0f);
    float acc = b0[j];
    for (int k = 0; k < 128; ++k) acc += g_gsum[0][g * 128 + k] * inv_s * W0[k * 128 + j];
    for (int k = 0; k < 128; ++k) acc += g_gsum[1][g * 128 + k] * inv_t * W0[(128 + k) * 128 + j];
    g_H[g * 128 + j] = fmaxf(acc, 0.f);
}

__global__ void loss_kernel(const float* __restrict__ W1, const float* __restrict__ b1,
                            const int* __restrict__ y, float* __restrict__ out) {
    int g = threadIdx.x;  // 128 threads
    float l0 = b1[0], l1 = b1[1];
    for (int j = 0; j < 128; ++j) {
        float hv = g_H[g * 128 + j];
        l0 += hv * W1[j * 2 + 0];
        l1 += hv * W1[j * 2 + 1];
    }
    float m = fmaxf(l0, l1);
    float lse = m + logf(expf(l0 - m) + expf(l1 - m));
    float ly = (y[g] == 0) ? l0 : l1;
    float c = -(ly - lse) * (1.0f / (float)N_GRAPHS);
    __shared__ float red[128];
    red[g] = c;
    __syncthreads();
    for (int s = 64; s; s >>= 1) {
        if (g < s) red[g] += red[g + s];
        __syncthreads();
    }
    if (g == 0) out[0] = red[0];
}

extern "C" void kernel_launch(void* const* d_in, const int* in_sizes, int n_in,
                              void* d_out, int out_size, void* d_ws, size_t ws_size,
                              hipStream_t stream) {
    const float* x_s      = (const float*)d_in[0];
    const float* x_t      = (const float*)d_in[1];
    const float* ea_s     = (const float*)d_in[2];
    const float* ea_t     = (const float*)d_in[3];
    const int*   ei_s     = (const int*)d_in[4];
    const int*   ei_t     = (const int*)d_in[5];
    const int*   batch_s  = (const int*)d_in[6];
    const int*   batch_t  = (const int*)d_in[7];
    const int*   y        = (const int*)d_in[8];
    const float* node_emb = (const float*)d_in[9];
    const float* edge_emb = (const float*)d_in[10];
    const float* W_in_0   = (const float*)d_in[11];
    const float* W_in_1   = (const float*)d_in[12];
    const float* W_out_0  = (const float*)d_in[13];
    const float* W_out_1  = (const float*)d_in[14];
    const float* Wg_in    = (const float*)d_in[15];
    const float* bg_in    = (const float*)d_in[16];
    const float* Wg_out   = (const float*)d_in[17];
    const float* bg_out   = (const float*)d_in[18];
    const float* cls_W0   = (const float*)d_in[19];
    const float* cls_b0   = (const float*)d_in[20];
    const float* cls_W1   = (const float*)d_in[21];
    const float* cls_b1   = (const float*)d_in[22];

    const int N = N_NODES, E = N_EDGES;

    zero_gsum_kernel<<<(2 * N_GRAPHS * NODE_DIM + 255) / 256, 256, 0, stream>>>();

    for (int side = 0; side < 2; ++side) {
        const float* xin   = side ? x_t : x_s;
        const float* eain  = side ? ea_t : ea_s;
        const int*   ei    = side ? ei_t : ei_s;
        const int*   batch = side ? batch_t : batch_s;
        const int* row = ei;
        const int* col = ei + E;

        node_embed_kernel<<<(N + 3) / 4, 256, 0, stream>>>(xin, node_emb, N);
        edge_embed_kernel<<<(2 * E + 255) / 256, 256, 0, stream>>>(eain, edge_emb, 2 * E);

        int cur = 0;
        for (int k = 0; k < K_LAYERS; ++k) {
            const float* Wi0 = W_in_0 + (size_t)k * 320 * 64;
            const float* Wo0 = W_out_0 + (size_t)k * 320 * 64;
            assemble_wcat<<<256, 256, 0, stream>>>(Wi0, Wo0, Wg_in + (size_t)k * 128 * 128,
                                                   Wg_out + (size_t)k * 128 * 128);
            gemm_xw_kernel<<<dim3((N + 63) / 64, 8), 256, 0, stream>>>(cur, N);
            edge_update_kernel<<<dim3((E + 63) / 64, 2), 256, 0, stream>>>(
                row, col, Wi0 + 128 * 64, Wo0 + 128 * 64, E);
            wgate_kernel<<<(2 * E + 255) / 256, 256, 0, stream>>>(
                W_in_1 + (size_t)k * 64, W_out_1 + (size_t)k * 64, E);
            xinit_kernel<<<((size_t)N * 32 + 255) / 256, 256, 0, stream>>>(
                cur, bg_in + (size_t)k * 128, bg_out + (size_t)k * 128, N);
            scatter_kernel<<<dim3(((size_t)E * 4 + 255) / 256, 2), 256, 0, stream>>>(
                cur, row, col, E);
            cur ^= 1;
        }
        pool_kernel<<<(N + 127) / 128, 128, 0, stream>>>(cur, side, batch, N);
        count_kernel<<<1, 128, 0, stream>>>(side, batch, N);
    }

    hidden_kernel<<<128, 128, 0, stream>>>(cls_W0, cls_b0);
    loss_kernel<<<1, 128, 0, stream>>>(cls_W1, cls_b1, y, (float*)d_out);
}

// Round 3
// 4196.326 us; speedup vs baseline: 6.4143x; 6.4143x over previous
//
#include <hip/hip_runtime.h>
#include <hip/hip_bf16.h>

#define N_NODES 100000
#define N_EDGES 300000
#define N_GRAPHS 128
#define NODE_VOCAB 200
#define NODE_DIM 128
#define EDGE_DIM 64
#define K_LAYERS 3

// ---------------- static device scratch (no reliance on ws_size) ----------------
__device__ float g_h[2][(size_t)N_NODES * NODE_DIM];      // ping-pong node state
__device__ float g_ebuf[(size_t)2 * N_EDGES * EDGE_DIM];  // edge state [e_in | e_out]
__device__ float g_XWe[(size_t)N_NODES * 256];            // [XA_in|XC_in|XA_out|XC_out]
__device__ float g_XWx[(size_t)N_NODES * 256];            // [xi | xo]
__device__ float g_Wcat[128 * 512];
__device__ float g_wbuf[(size_t)2 * N_EDGES];
__device__ float g_gsum[2][N_GRAPHS * NODE_DIM];
__device__ float g_cnt[2][N_GRAPHS];
__device__ float g_H[N_GRAPHS * NODE_DIM];
// CSR (rebuilt per side; constant across layers)
__device__ int  g_deg_in[N_NODES];
__device__ int  g_deg_out[N_NODES];
__device__ int  g_off_in[N_NODES + 1];
__device__ int  g_off_out[N_NODES + 1];
__device__ int  g_cur_in[N_NODES];
__device__ int  g_cur_out[N_NODES];
__device__ int2 g_lst_in[N_EDGES];   // (src=row, e) keyed by col
__device__ int2 g_lst_out[N_EDGES];  // (src=col, e) keyed by row

// ---------------- node argmax + embed ----------------
__global__ void node_embed_kernel(const float* __restrict__ x, const float* __restrict__ emb,
                                  int N) {
    int wave = threadIdx.x >> 6;
    int lane = threadIdx.x & 63;
    int n = blockIdx.x * 4 + wave;
    if (n >= N) return;
    const float* xr = x + (size_t)n * NODE_VOCAB;
    float v = xr[lane];
    int idx = lane;
    float nv = xr[lane + 64];
    if (nv > v) { v = nv; idx = lane + 64; }
    nv = xr[lane + 128];
    if (nv > v) { v = nv; idx = lane + 128; }
    if (lane < NODE_VOCAB - 192) {
        nv = xr[lane + 192];
        if (nv > v) { v = nv; idx = lane + 192; }
    }
    #pragma unroll
    for (int off = 32; off; off >>= 1) {
        float ov = __shfl_xor(v, off);
        int oi = __shfl_xor(idx, off);
        if (ov > v || (ov == v && oi < idx)) { v = ov; idx = oi; }
    }
    const float* er = emb + (size_t)idx * NODE_DIM;
    g_h[0][(size_t)n * NODE_DIM + lane] = er[lane];
    g_h[0][(size_t)n * NODE_DIM + 64 + lane] = er[64 + lane];
}

// ---------------- edge argmax + embed ----------------
__global__ void edge_embed_kernel(const float* __restrict__ ea, const float* __restrict__ emb,
                                  int M) {
    __shared__ int sidx[256];
    __shared__ float semb[8 * 64];
    int t = threadIdx.x;
    if (t < 128) {
        *(float4*)&semb[t * 4] = *(const float4*)(emb + t * 4);
    }
    long eg = (long)blockIdx.x * 256 + t;
    int best = 0;
    if (eg < M) {
        const float* ar = ea + eg * 8;
        float4 v0 = *(const float4*)ar;
        float4 v1 = *(const float4*)(ar + 4);
        float vals[8] = {v0.x, v0.y, v0.z, v0.w, v1.x, v1.y, v1.z, v1.w};
        float bv = vals[0];
        #pragma unroll
        for (int i = 1; i < 8; ++i)
            if (vals[i] > bv) { bv = vals[i]; best = i; }
    }
    sidx[t] = best;
    __syncthreads();
    long base = (long)blockIdx.x * 256 * 64;
    #pragma unroll 4
    for (int i = 0; i < 64; ++i) {
        long id = (long)i * 256 + t;
        int el = (int)(id >> 6);
        int d = (int)(id & 63);
        long eg2 = (long)blockIdx.x * 256 + el;
        if (eg2 < M) g_ebuf[base + id] = semb[sidx[el] * 64 + d];
    }
}

// ---------------- CSR build ----------------
__global__ void csr_count_kernel(const int* __restrict__ row, const int* __restrict__ col,
                                 int E) {
    int e = blockIdx.x * 256 + threadIdx.x;
    if (e >= E) return;
    atomicAdd(&g_deg_in[col[e]], 1);
    atomicAdd(&g_deg_out[row[e]], 1);
}

__global__ void csr_zero_kernel() {
    int i = blockIdx.x * 256 + threadIdx.x;
    if (i < N_NODES) { g_deg_in[i] = 0; g_deg_out[i] = 0; }
}

// single-block exclusive scan of deg -> off (N=100000), also copies to cursor
__global__ void csr_scan_kernel(int which, int total) {
    const int* deg = which ? g_deg_out : g_deg_in;
    int* off = which ? g_off_out : g_off_in;
    int* cur = which ? g_cur_out : g_cur_in;
    __shared__ int part[1024];
    int t = threadIdx.x;
    const int chunk = (N_NODES + 1023) / 1024;
    int lo = t * chunk;
    int hi = lo + chunk; if (hi > N_NODES) hi = N_NODES;
    int s = 0;
    for (int i = lo; i < hi; ++i) s += deg[i];
    part[t] = s;
    __syncthreads();
    #pragma unroll
    for (int d = 1; d < 1024; d <<= 1) {
        int add = (t >= d) ? part[t - d] : 0;
        __syncthreads();
        part[t] += add;
        __syncthreads();
    }
    int run = part[t] - s;  // exclusive prefix of this chunk
    for (int i = lo; i < hi; ++i) {
        off[i] = run;
        cur[i] = run;
        run += deg[i];
    }
    if (t == 1023) off[N_NODES] = total;
}

__global__ void csr_fill_kernel(const int* __restrict__ row, const int* __restrict__ col,
                                int E) {
    int e = blockIdx.x * 256 + threadIdx.x;
    if (e >= E) return;
    int r = row[e], c = col[e];
    int p = atomicAdd(&g_cur_in[c], 1);
    g_lst_in[p] = make_int2(r, e);
    int q = atomicAdd(&g_cur_out[r], 1);
    g_lst_out[q] = make_int2(c, e);
}

// ---------------- assemble Wcat (128 x 512) ----------------
__global__ void assemble_wcat(const float* __restrict__ Wi0, const float* __restrict__ Wo0,
                              const float* __restrict__ Wgi, const float* __restrict__ Wgo) {
    int idx = blockIdx.x * 256 + threadIdx.x;
    int kd = idx >> 9;
    int j = idx & 511;
    float v;
    if (j < 64) v = Wi0[kd * 64 + j];
    else if (j < 128) v = Wi0[(192 + kd) * 64 + (j - 64)];
    else if (j < 192) v = Wo0[kd * 64 + (j - 128)];
    else if (j < 256) v = Wo0[(192 + kd) * 64 + (j - 192)];
    else if (j < 384) v = Wgi[kd * 128 + (j - 256)];
    else v = Wgo[kd * 128 + (j - 384)];
    g_Wcat[idx] = v;
}

// ---------------- node GEMM: [XWe | XWx] = g_h[cur] (M x 128) @ Wcat (128 x 512) ----------------
__global__ __launch_bounds__(256) void gemm_xw_kernel(int cur, int M) {
    const float* __restrict__ A = g_h[cur];
    int m0 = blockIdx.x * 64;
    int n0 = blockIdx.y * 64;
    __shared__ float As[32][68];
    __shared__ float Bs[32][64];
    int t = threadIdx.x;
    int tx = t & 15, ty = t >> 4;
    float acc[4][4] = {};
    for (int k0 = 0; k0 < 128; k0 += 32) {
        #pragma unroll
        for (int i = 0; i < 2; ++i) {
            int idx = t + i * 256;
            int m = idx >> 3;
            int f = idx & 7;
            int gm = m0 + m;
            float4 v = (gm < M) ? *(const float4*)(A + (size_t)gm * 128 + k0 + f * 4)
                                : make_float4(0.f, 0.f, 0.f, 0.f);
            As[f * 4 + 0][m] = v.x;
            As[f * 4 + 1][m] = v.y;
            As[f * 4 + 2][m] = v.z;
            As[f * 4 + 3][m] = v.w;
        }
        #pragma unroll
        for (int i = 0; i < 2; ++i) {
            int idx = t + i * 256;
            int k = idx >> 4;
            int f = idx & 15;
            *(float4*)&Bs[k][f * 4] = *(const float4*)(g_Wcat + (size_t)(k0 + k) * 512 + n0 + f * 4);
        }
        __syncthreads();
        #pragma unroll
        for (int k = 0; k < 32; ++k) {
            float4 a4 = *(const float4*)&As[k][ty * 4];
            float4 b4 = *(const float4*)&Bs[k][tx * 4];
            float av[4] = {a4.x, a4.y, a4.z, a4.w};
            float bv[4] = {b4.x, b4.y, b4.z, b4.w};
            #pragma unroll
            for (int i = 0; i < 4; ++i)
                #pragma unroll
                for (int j = 0; j < 4; ++j)
                    acc[i][j] = fmaf(av[i], bv[j], acc[i][j]);
        }
        __syncthreads();
    }
    #pragma unroll
    for (int i = 0; i < 4; ++i) {
        int gm = m0 + ty * 4 + i;
        if (gm >= M) continue;
        int cj = n0 + tx * 4;
        float* dst = (cj < 256) ? (g_XWe + (size_t)gm * 256 + cj)
                                : (g_XWx + (size_t)gm * 256 + (cj - 256));
        float4 o = {acc[i][0], acc[i][1], acc[i][2], acc[i][3]};
        *(float4*)dst = o;
    }
}

// ---------------- edge update (in-place): e = e @ Wmid + gathered XA + XC ----------------
__global__ __launch_bounds__(256) void edge_update_kernel(const int* __restrict__ row,
                                                          const int* __restrict__ col,
                                                          const float* __restrict__ Wmid_in,
                                                          const float* __restrict__ Wmid_out,
                                                          int E) {
    int b = blockIdx.y;
    int e0 = blockIdx.x * 64;
    const float* Wmid = b ? Wmid_out : Wmid_in;
    float* ebuf = g_ebuf + (size_t)b * E * 64;
    __shared__ float As[64][68];
    __shared__ float Bs[64][64];
    int t = threadIdx.x;
    #pragma unroll
    for (int i = 0; i < 4; ++i) {
        int idx = t + i * 256;
        int m = idx >> 4;
        int f = idx & 15;
        int eg = e0 + m;
        float4 v = (eg < E) ? *(const float4*)(ebuf + (size_t)eg * 64 + f * 4)
                            : make_float4(0.f, 0.f, 0.f, 0.f);
        As[f * 4 + 0][m] = v.x;
        As[f * 4 + 1][m] = v.y;
        As[f * 4 + 2][m] = v.z;
        As[f * 4 + 3][m] = v.w;
    }
    #pragma unroll
    for (int i = 0; i < 4; ++i) {
        int idx = t + i * 256;
        int k = idx >> 4;
        int f = idx & 15;
        *(float4*)&Bs[k][f * 4] = *(const float4*)(Wmid + k * 64 + f * 4);
    }
    __syncthreads();
    int tx = t & 15, ty = t >> 4;
    float acc[4][4] = {};
    #pragma unroll 16
    for (int k = 0; k < 64; ++k) {
        float4 a4 = *(const float4*)&As[k][ty * 4];
        float4 b4 = *(const float4*)&Bs[k][tx * 4];
        float av[4] = {a4.x, a4.y, a4.z, a4.w};
        float bv[4] = {b4.x, b4.y, b4.z, b4.w};
        #pragma unroll
        for (int i = 0; i < 4; ++i)
            #pragma unroll
            for (int j = 0; j < 4; ++j)
                acc[i][j] = fmaf(av[i], bv[j], acc[i][j]);
    }
    #pragma unroll
    for (int i = 0; i < 4; ++i) {
        int eg = e0 + ty * 4 + i;
        if (eg >= E) continue;
        int r = row[eg], c = col[eg];
        int ga = b ? c : r;
        int ja = b ? 128 : 0;
        int gc = b ? r : c;
        int jc = b ? 192 : 64;
        int j0 = tx * 4;
        float4 x1 = *(const float4*)(g_XWe + (size_t)ga * 256 + ja + j0);
        float4 x2 = *(const float4*)(g_XWe + (size_t)gc * 256 + jc + j0);
        float4 o;
        o.x = acc[i][0] + x1.x + x2.x;
        o.y = acc[i][1] + x1.y + x2.y;
        o.z = acc[i][2] + x1.z + x2.z;
        o.w = acc[i][3] + x1.w + x2.w;
        *(float4*)(ebuf + (size_t)eg * 64 + j0) = o;
    }
}

// ---------------- gate: w[m] = sigmoid(e[m] . W1), m < 2E ----------------
__global__ void wgate_kernel(const float* __restrict__ W1_in,
                             const float* __restrict__ W1_out, int E) {
    long idx = (long)blockIdx.x * 256 + threadIdx.x;
    if (idx >= 2L * E) return;
    const float* W1 = (idx < E) ? W1_in : W1_out;
    const float* er = g_ebuf + idx * 64;
    float acc = 0.f;
    #pragma unroll
    for (int j = 0; j < 64; j += 4) {
        float4 ev = *(const float4*)(er + j);
        acc += ev.x * W1[j] + ev.y * W1[j + 1] + ev.z * W1[j + 2] + ev.w * W1[j + 3];
    }
    g_wbuf[idx] = 1.0f / (1.0f + expf(-acc));
}

// ---------------- fused aggregate: x_next = x + bgi + bgo + CSR-gathered in/out sums ----------------
__global__ __launch_bounds__(256) void aggregate_kernel(int cur, const float* __restrict__ bgi,
                                                        const float* __restrict__ bgo, int N) {
    int wave = threadIdx.x >> 6;
    int lane = threadIdx.x & 63;
    int n = blockIdx.x * 4 + wave;
    if (n >= N) return;
    float2 acc = ((const float2*)(g_h[cur] + (size_t)n * 128))[lane];
    float2 bi = ((const float2*)bgi)[lane];
    float2 bo = ((const float2*)bgo)[lane];
    acc.x += bi.x + bo.x;
    acc.y += bi.y + bo.y;
    int p0 = g_off_in[n], p1 = g_off_in[n + 1];
    for (int p = p0; p < p1; ++p) {
        int2 se = g_lst_in[p];
        float wv = g_wbuf[se.y];
        float2 v = ((const float2*)(g_XWx + (size_t)se.x * 256))[lane];
        acc.x += wv * v.x;
        acc.y += wv * v.y;
    }
    p0 = g_off_out[n]; p1 = g_off_out[n + 1];
    for (int p = p0; p < p1; ++p) {
        int2 se = g_lst_out[p];
        float wv = g_wbuf[(size_t)N_EDGES + se.y];
        float2 v = ((const float2*)(g_XWx + (size_t)se.x * 256 + 128))[lane];
        acc.x += wv * v.x;
        acc.y += wv * v.y;
    }
    ((float2*)(g_h[cur ^ 1] + (size_t)n * 128))[lane] = acc;
}

// ---------------- mean-pool partials ----------------
__global__ void pool_kernel(int fin, int side, const int* __restrict__ batch, int N) {
    const float* x = g_h[fin];
    float* gsum = g_gsum[side];
    int n0 = blockIdx.x * 128;
    int d = threadIdx.x;  // 128 threads
    if (n0 >= N) return;
    int nend = min(n0 + 128, N);
    float acc = 0.f;
    int curg = batch[n0];
    for (int n = n0; n < nend; ++n) {
        int g = batch[n];
        if (g != curg) {
            atomicAdd(&gsum[curg * 128 + d], acc);
            acc = 0.f;
            curg = g;
        }
        acc += x[(size_t)n * 128 + d];
    }
    atomicAdd(&gsum[curg * 128 + d], acc);
}

__global__ void count_kernel(int side, const int* __restrict__ batch, int N) {
    int g = threadIdx.x;  // 128 threads
    int lo = 0, hi = N;
    while (lo < hi) { int mid = (lo + hi) >> 1; if (batch[mid] < g) lo = mid + 1; else hi = mid; }
    int a = lo;
    lo = 0; hi = N;
    while (lo < hi) { int mid = (lo + hi) >> 1; if (batch[mid] < g + 1) lo = mid + 1; else hi = mid; }
    g_cnt[side][g] = (float)(lo - a);
}

__global__ void zero_gsum_kernel() {
    int i = blockIdx.x * 256 + threadIdx.x;
    if (i < 2 * N_GRAPHS * NODE_DIM) ((float*)g_gsum)[i] = 0.f;
}

// ---------------- classifier ----------------
__global__ void hidden_kernel(const float* __restrict__ W0, const float* __restrict__ b0) {
    int g = blockIdx.x;
    int j = threadIdx.x;  // 128 x 128
    float inv_s = 1.0f / fmaxf(g_cnt[0][g], 1.0f);
    float inv_t = 1.0f / fmaxf(g_cnt[1][g], 1.0f);
    float acc = b0[j];
    for (int k = 0; k < 128; ++k) acc += g_gsum[0][g * 128 + k] * inv_s * W0[k * 128 + j];
    for (int k = 0; k < 128; ++k) acc += g_gsum[1][g * 128 + k] * inv_t * W0[(128 + k) * 128 + j];
    g_H[g * 128 + j] = fmaxf(acc, 0.f);
}

__global__ void loss_kernel(const float* __restrict__ W1, const float* __restrict__ b1,
                            const int* __restrict__ y, float* __restrict__ out) {
    int g = threadIdx.x;  // 128 threads
    float l0 = b1[0], l1 = b1[1];
    for (int j = 0; j < 128; ++j) {
        float hv = g_H[g * 128 + j];
        l0 += hv * W1[j * 2 + 0];
        l1 += hv * W1[j * 2 + 1];
    }
    float m = fmaxf(l0, l1);
    float lse = m + logf(expf(l0 - m) + expf(l1 - m));
    float ly = (y[g] == 0) ? l0 : l1;
    float c = -(ly - lse) * (1.0f / (float)N_GRAPHS);
    __shared__ float red[128];
    red[g] = c;
    __syncthreads();
    for (int s = 64; s; s >>= 1) {
        if (g < s) red[g] += red[g + s];
        __syncthreads();
    }
    if (g == 0) out[0] = red[0];
}

extern "C" void kernel_launch(void* const* d_in, const int* in_sizes, int n_in,
                              void* d_out, int out_size, void* d_ws, size_t ws_size,
                              hipStream_t stream) {
    const float* x_s      = (const float*)d_in[0];
    const float* x_t      = (const float*)d_in[1];
    const float* ea_s     = (const float*)d_in[2];
    const float* ea_t     = (const float*)d_in[3];
    const int*   ei_s     = (const int*)d_in[4];
    const int*   ei_t     = (const int*)d_in[5];
    const int*   batch_s  = (const int*)d_in[6];
    const int*   batch_t  = (const int*)d_in[7];
    const int*   y        = (const int*)d_in[8];
    const float* node_emb = (const float*)d_in[9];
    const float* edge_emb = (const float*)d_in[10];
    const float* W_in_0   = (const float*)d_in[11];
    const float* W_in_1   = (const float*)d_in[12];
    const float* W_out_0  = (const float*)d_in[13];
    const float* W_out_1  = (const float*)d_in[14];
    const float* Wg_in    = (const float*)d_in[15];
    const float* bg_in    = (const float*)d_in[16];
    const float* Wg_out   = (const float*)d_in[17];
    const float* bg_out   = (const float*)d_in[18];
    const float* cls_W0   = (const float*)d_in[19];
    const float* cls_b0   = (const float*)d_in[20];
    const float* cls_W1   = (const float*)d_in[21];
    const float* cls_b1   = (const float*)d_in[22];

    const int N = N_NODES, E = N_EDGES;

    zero_gsum_kernel<<<(2 * N_GRAPHS * NODE_DIM + 255) / 256, 256, 0, stream>>>();

    for (int side = 0; side < 2; ++side) {
        const float* xin   = side ? x_t : x_s;
        const float* eain  = side ? ea_t : ea_s;
        const int*   ei    = side ? ei_t : ei_s;
        const int*   batch = side ? batch_t : batch_s;
        const int* row = ei;
        const int* col = ei + E;

        node_embed_kernel<<<(N + 3) / 4, 256, 0, stream>>>(xin, node_emb, N);
        edge_embed_kernel<<<(2 * E + 255) / 256, 256, 0, stream>>>(eain, edge_emb, 2 * E);

        // ---- CSR build (once per side; edge_index constant across layers) ----
        csr_zero_kernel<<<(N + 255) / 256, 256, 0, stream>>>();
        csr_count_kernel<<<(E + 255) / 256, 256, 0, stream>>>(row, col, E);
        csr_scan_kernel<<<1, 1024, 0, stream>>>(0, E);
        csr_scan_kernel<<<1, 1024, 0, stream>>>(1, E);
        csr_fill_kernel<<<(E + 255) / 256, 256, 0, stream>>>(row, col, E);

        int cur = 0;
        for (int k = 0; k < K_LAYERS; ++k) {
            const float* Wi0 = W_in_0 + (size_t)k * 320 * 64;
            const float* Wo0 = W_out_0 + (size_t)k * 320 * 64;
            assemble_wcat<<<256, 256, 0, stream>>>(Wi0, Wo0, Wg_in + (size_t)k * 128 * 128,
                                                   Wg_out + (size_t)k * 128 * 128);
            gemm_xw_kernel<<<dim3((N + 63) / 64, 8), 256, 0, stream>>>(cur, N);
            edge_update_kernel<<<dim3((E + 63) / 64, 2), 256, 0, stream>>>(
                row, col, Wi0 + 128 * 64, Wo0 + 128 * 64, E);
            wgate_kernel<<<(2 * E + 255) / 256, 256, 0, stream>>>(
                W_in_1 + (size_t)k * 64, W_out_1 + (size_t)k * 64, E);
            aggregate_kernel<<<(N + 3) / 4, 256, 0, stream>>>(
                cur, bg_in + (size_t)k * 128, bg_out + (size_t)k * 128, N);
            cur ^= 1;
        }
        pool_kernel<<<(N + 127) / 128, 128, 0, stream>>>(cur, side, batch, N);
        count_kernel<<<1, 128, 0, stream>>>(side, batch, N);
    }

    hidden_kernel<<<128, 128, 0, stream>>>(cls_W0, cls_b0);
    loss_kernel<<<1, 128, 0, stream>>>(cls_W1, cls_b1, y, (float*)d_out);
}

// Round 4
// 3182.116 us; speedup vs baseline: 8.4586x; 1.3187x over previous
//
#include <hip/hip_runtime.h>
#include <hip/hip_bf16.h>

#define N_NODES 100000
#define N_EDGES 300000
#define N_GRAPHS 128
#define NODE_VOCAB 200
#define NODE_DIM 128
#define EDGE_DIM 64
#define K_LAYERS 3

#define SCAN_CHUNK 2048
#define SCAN_NBLK ((N_NODES + SCAN_CHUNK - 1) / SCAN_CHUNK)  // 49

// ---------------- static device scratch (no reliance on ws_size) ----------------
__device__ float g_h[2][(size_t)N_NODES * NODE_DIM];      // ping-pong node state
__device__ float g_ebuf[(size_t)2 * N_EDGES * EDGE_DIM];  // edge state [e_in | e_out]
__device__ float g_XWe[(size_t)N_NODES * 256];            // [XA_in|XC_in|XA_out|XC_out]
__device__ float g_XWx[(size_t)N_NODES * 256];            // [xi | xo]
__device__ float g_Wcat[128 * 512];
__device__ float g_wbuf[(size_t)2 * N_EDGES];
__device__ float g_gsum[2][N_GRAPHS * NODE_DIM];
__device__ float g_cnt[2][N_GRAPHS];
__device__ float g_H[N_GRAPHS * NODE_DIM];
// CSR (rebuilt per side; constant across layers)
__device__ int  g_deg_in[N_NODES];
__device__ int  g_deg_out[N_NODES];
__device__ int  g_off_in[N_NODES + 1];
__device__ int  g_off_out[N_NODES + 1];
__device__ int  g_cur_in[N_NODES];
__device__ int  g_cur_out[N_NODES];
__device__ int2 g_lst_in[N_EDGES];   // (src=row, e) keyed by col
__device__ int2 g_lst_out[N_EDGES];  // (src=col, e) keyed by row
__device__ int  g_bsum[2][SCAN_NBLK];
__device__ int  g_boff[2][SCAN_NBLK];

// ---------------- node argmax + embed ----------------
__global__ void node_embed_kernel(const float* __restrict__ x, const float* __restrict__ emb,
                                  int N) {
    int wave = threadIdx.x >> 6;
    int lane = threadIdx.x & 63;
    int n = blockIdx.x * 4 + wave;
    if (n >= N) return;
    const float* xr = x + (size_t)n * NODE_VOCAB;
    float v = xr[lane];
    int idx = lane;
    float nv = xr[lane + 64];
    if (nv > v) { v = nv; idx = lane + 64; }
    nv = xr[lane + 128];
    if (nv > v) { v = nv; idx = lane + 128; }
    if (lane < NODE_VOCAB - 192) {
        nv = xr[lane + 192];
        if (nv > v) { v = nv; idx = lane + 192; }
    }
    #pragma unroll
    for (int off = 32; off; off >>= 1) {
        float ov = __shfl_xor(v, off);
        int oi = __shfl_xor(idx, off);
        if (ov > v || (ov == v && oi < idx)) { v = ov; idx = oi; }
    }
    const float* er = emb + (size_t)idx * NODE_DIM;
    g_h[0][(size_t)n * NODE_DIM + lane] = er[lane];
    g_h[0][(size_t)n * NODE_DIM + 64 + lane] = er[64 + lane];
}

// ---------------- edge argmax + embed ----------------
__global__ void edge_embed_kernel(const float* __restrict__ ea, const float* __restrict__ emb,
                                  int M) {
    __shared__ int sidx[256];
    __shared__ float semb[8 * 64];
    int t = threadIdx.x;
    if (t < 128) {
        *(float4*)&semb[t * 4] = *(const float4*)(emb + t * 4);
    }
    long eg = (long)blockIdx.x * 256 + t;
    int best = 0;
    if (eg < M) {
        const float* ar = ea + eg * 8;
        float4 v0 = *(const float4*)ar;
        float4 v1 = *(const float4*)(ar + 4);
        float vals[8] = {v0.x, v0.y, v0.z, v0.w, v1.x, v1.y, v1.z, v1.w};
        float bv = vals[0];
        #pragma unroll
        for (int i = 1; i < 8; ++i)
            if (vals[i] > bv) { bv = vals[i]; best = i; }
    }
    sidx[t] = best;
    __syncthreads();
    long base = (long)blockIdx.x * 256 * 64;
    #pragma unroll 4
    for (int i = 0; i < 64; ++i) {
        long id = (long)i * 256 + t;
        int el = (int)(id >> 6);
        int d = (int)(id & 63);
        long eg2 = (long)blockIdx.x * 256 + el;
        if (eg2 < M) g_ebuf[base + id] = semb[sidx[el] * 64 + d];
    }
}

// ---------------- CSR build ----------------
__global__ void csr_zero_kernel() {
    int i = blockIdx.x * 256 + threadIdx.x;
    if (i < N_NODES) { g_deg_in[i] = 0; g_deg_out[i] = 0; }
}

__global__ void csr_count_kernel(const int* __restrict__ row, const int* __restrict__ col,
                                 int E) {
    int e = blockIdx.x * 256 + threadIdx.x;
    if (e >= E) return;
    atomicAdd(&g_deg_in[col[e]], 1);
    atomicAdd(&g_deg_out[row[e]], 1);
}

// phase 1: per-block sums over chunks of SCAN_CHUNK degrees. grid (SCAN_NBLK, 2) x 256
__global__ void csr_bsum_kernel() {
    int which = blockIdx.y;
    const int* deg = which ? g_deg_out : g_deg_in;
    int b = blockIdx.x;
    int t = threadIdx.x;
    int base = b * SCAN_CHUNK;
    int s = 0;
    #pragma unroll
    for (int i = 0; i < SCAN_CHUNK / 256; ++i) {
        int idx = base + i * 256 + t;
        if (idx < N_NODES) s += deg[idx];
    }
    __shared__ int red[256];
    red[t] = s;
    __syncthreads();
    for (int d = 128; d; d >>= 1) {
        if (t < d) red[t] += red[t + d];
        __syncthreads();
    }
    if (t == 0) g_bsum[which][b] = red[0];
}

// phase 2: exclusive scan of the SCAN_NBLK block sums (one wave per direction). grid 2 x 64
__global__ void csr_bscan_kernel() {
    int which = blockIdx.x;
    int t = threadIdx.x;  // 64 threads
    int v = (t < SCAN_NBLK) ? g_bsum[which][t] : 0;
    int orig = v;
    #pragma unroll
    for (int d = 1; d < 64; d <<= 1) {
        int u = __shfl_up(v, d, 64);
        if (t >= d) v += u;
    }
    if (t < SCAN_NBLK) g_boff[which][t] = v - orig;
}

// phase 3: per-block local scan + write off/cur. grid (SCAN_NBLK, 2) x 256
__global__ void csr_off_kernel(int total) {
    int which = blockIdx.y;
    const int* deg = which ? g_deg_out : g_deg_in;
    int* off = which ? g_off_out : g_off_in;
    int* cur = which ? g_cur_out : g_cur_in;
    int b = blockIdx.x;
    int t = threadIdx.x;
    const int per = SCAN_CHUNK / 256;  // 8
    int lo = b * SCAN_CHUNK + t * per;
    int d8[per];
    int s = 0;
    #pragma unroll
    for (int i = 0; i < per; ++i) {
        int idx = lo + i;
        d8[i] = (idx < N_NODES) ? deg[idx] : 0;
        s += d8[i];
    }
    __shared__ int part[256];
    part[t] = s;
    __syncthreads();
    for (int d = 1; d < 256; d <<= 1) {
        int add = (t >= d) ? part[t - d] : 0;
        __syncthreads();
        part[t] += add;
        __syncthreads();
    }
    int run = g_boff[which][b] + part[t] - s;
    #pragma unroll
    for (int i = 0; i < per; ++i) {
        int idx = lo + i;
        if (idx < N_NODES) {
            off[idx] = run;
            cur[idx] = run;
            run += d8[i];
        }
    }
    if (b == 0 && t == 0) off[N_NODES] = total;
}

__global__ void csr_fill_kernel(const int* __restrict__ row, const int* __restrict__ col,
                                int E) {
    int e = blockIdx.x * 256 + threadIdx.x;
    if (e >= E) return;
    int r = row[e], c = col[e];
    int p = atomicAdd(&g_cur_in[c], 1);
    g_lst_in[p] = make_int2(r, e);
    int q = atomicAdd(&g_cur_out[r], 1);
    g_lst_out[q] = make_int2(c, e);
}

// ---------------- assemble Wcat (128 x 512) ----------------
__global__ void assemble_wcat(const float* __restrict__ Wi0, const float* __restrict__ Wo0,
                              const float* __restrict__ Wgi, const float* __restrict__ Wgo) {
    int idx = blockIdx.x * 256 + threadIdx.x;
    int kd = idx >> 9;
    int j = idx & 511;
    float v;
    if (j < 64) v = Wi0[kd * 64 + j];
    else if (j < 128) v = Wi0[(192 + kd) * 64 + (j - 64)];
    else if (j < 192) v = Wo0[kd * 64 + (j - 128)];
    else if (j < 256) v = Wo0[(192 + kd) * 64 + (j - 192)];
    else if (j < 384) v = Wgi[kd * 128 + (j - 256)];
    else v = Wgo[kd * 128 + (j - 384)];
    g_Wcat[idx] = v;
}

// ---------------- node GEMM: [XWe | XWx] = g_h[cur] (M x 128) @ Wcat (128 x 512) ----------------
__global__ __launch_bounds__(256) void gemm_xw_kernel(int cur, int M) {
    const float* __restrict__ A = g_h[cur];
    int m0 = blockIdx.x * 64;
    int n0 = blockIdx.y * 64;
    __shared__ float As[32][68];
    __shared__ float Bs[32][64];
    int t = threadIdx.x;
    int tx = t & 15, ty = t >> 4;
    float acc[4][4] = {};
    for (int k0 = 0; k0 < 128; k0 += 32) {
        #pragma unroll
        for (int i = 0; i < 2; ++i) {
            int idx = t + i * 256;
            int m = idx >> 3;
            int f = idx & 7;
            int gm = m0 + m;
            float4 v = (gm < M) ? *(const float4*)(A + (size_t)gm * 128 + k0 + f * 4)
                                : make_float4(0.f, 0.f, 0.f, 0.f);
            As[f * 4 + 0][m] = v.x;
            As[f * 4 + 1][m] = v.y;
            As[f * 4 + 2][m] = v.z;
            As[f * 4 + 3][m] = v.w;
        }
        #pragma unroll
        for (int i = 0; i < 2; ++i) {
            int idx = t + i * 256;
            int k = idx >> 4;
            int f = idx & 15;
            *(float4*)&Bs[k][f * 4] = *(const float4*)(g_Wcat + (size_t)(k0 + k) * 512 + n0 + f * 4);
        }
        __syncthreads();
        #pragma unroll
        for (int k = 0; k < 32; ++k) {
            float4 a4 = *(const float4*)&As[k][ty * 4];
            float4 b4 = *(const float4*)&Bs[k][tx * 4];
            float av[4] = {a4.x, a4.y, a4.z, a4.w};
            float bv[4] = {b4.x, b4.y, b4.z, b4.w};
            #pragma unroll
            for (int i = 0; i < 4; ++i)
                #pragma unroll
                for (int j = 0; j < 4; ++j)
                    acc[i][j] = fmaf(av[i], bv[j], acc[i][j]);
        }
        __syncthreads();
    }
    #pragma unroll
    for (int i = 0; i < 4; ++i) {
        int gm = m0 + ty * 4 + i;
        if (gm >= M) continue;
        int cj = n0 + tx * 4;
        float* dst = (cj < 256) ? (g_XWe + (size_t)gm * 256 + cj)
                                : (g_XWx + (size_t)gm * 256 + (cj - 256));
        float4 o = {acc[i][0], acc[i][1], acc[i][2], acc[i][3]};
        *(float4*)dst = o;
    }
}

// ------- edge update (in-place) + fused gate: e = e@Wmid + XA + XC; w = sigmoid(e.W1) -------
__global__ __launch_bounds__(256) void edge_update_kernel(const int* __restrict__ row,
                                                          const int* __restrict__ col,
                                                          const float* __restrict__ Wmid_in,
                                                          const float* __restrict__ Wmid_out,
                                                          const float* __restrict__ W1_in,
                                                          const float* __restrict__ W1_out,
                                                          int E) {
    int b = blockIdx.y;
    int e0 = blockIdx.x * 64;
    const float* Wmid = b ? Wmid_out : Wmid_in;
    const float* W1 = b ? W1_out : W1_in;
    float* ebuf = g_ebuf + (size_t)b * E * 64;
    __shared__ float As[64][68];
    __shared__ float Bs[64][64];
    __shared__ float sW1[64];
    int t = threadIdx.x;
    if (t < 64) sW1[t] = W1[t];
    #pragma unroll
    for (int i = 0; i < 4; ++i) {
        int idx = t + i * 256;
        int m = idx >> 4;
        int f = idx & 15;
        int eg = e0 + m;
        float4 v = (eg < E) ? *(const float4*)(ebuf + (size_t)eg * 64 + f * 4)
                            : make_float4(0.f, 0.f, 0.f, 0.f);
        As[f * 4 + 0][m] = v.x;
        As[f * 4 + 1][m] = v.y;
        As[f * 4 + 2][m] = v.z;
        As[f * 4 + 3][m] = v.w;
    }
    #pragma unroll
    for (int i = 0; i < 4; ++i) {
        int idx = t + i * 256;
        int k = idx >> 4;
        int f = idx & 15;
        *(float4*)&Bs[k][f * 4] = *(const float4*)(Wmid + k * 64 + f * 4);
    }
    __syncthreads();
    int tx = t & 15, ty = t >> 4;
    float acc[4][4] = {};
    #pragma unroll 16
    for (int k = 0; k < 64; ++k) {
        float4 a4 = *(const float4*)&As[k][ty * 4];
        float4 b4 = *(const float4*)&Bs[k][tx * 4];
        float av[4] = {a4.x, a4.y, a4.z, a4.w};
        float bv[4] = {b4.x, b4.y, b4.z, b4.w};
        #pragma unroll
        for (int i = 0; i < 4; ++i)
            #pragma unroll
            for (int j = 0; j < 4; ++j)
                acc[i][j] = fmaf(av[i], bv[j], acc[i][j]);
    }
    float w1x = sW1[tx * 4 + 0];
    float w1y = sW1[tx * 4 + 1];
    float w1z = sW1[tx * 4 + 2];
    float w1w = sW1[tx * 4 + 3];
    #pragma unroll
    for (int i = 0; i < 4; ++i) {
        int eg = e0 + ty * 4 + i;
        if (eg >= E) continue;
        int r = row[eg], c = col[eg];
        int ga = b ? c : r;
        int ja = b ? 128 : 0;
        int gc = b ? r : c;
        int jc = b ? 192 : 64;
        int j0 = tx * 4;
        float4 x1 = *(const float4*)(g_XWe + (size_t)ga * 256 + ja + j0);
        float4 x2 = *(const float4*)(g_XWe + (size_t)gc * 256 + jc + j0);
        float4 o;
        o.x = acc[i][0] + x1.x + x2.x;
        o.y = acc[i][1] + x1.y + x2.y;
        o.z = acc[i][2] + x1.z + x2.z;
        o.w = acc[i][3] + x1.w + x2.w;
        *(float4*)(ebuf + (size_t)eg * 64 + j0) = o;
        // fused gate: partial dot with W1, reduce across the 16 tx lanes
        float p = o.x * w1x + o.y * w1y + o.z * w1z + o.w * w1w;
        p += __shfl_xor(p, 1);
        p += __shfl_xor(p, 2);
        p += __shfl_xor(p, 4);
        p += __shfl_xor(p, 8);
        if (tx == 0) g_wbuf[(size_t)b * E + eg] = 1.0f / (1.0f + expf(-p));
    }
}

// ---------------- fused aggregate: x_next = x + bgi + bgo + CSR-gathered in/out sums ----------------
__global__ __launch_bounds__(256) void aggregate_kernel(int cur, const float* __restrict__ bgi,
                                                        const float* __restrict__ bgo, int N) {
    int wave = threadIdx.x >> 6;
    int lane = threadIdx.x & 63;
    int n = blockIdx.x * 4 + wave;
    if (n >= N) return;
    float2 acc = ((const float2*)(g_h[cur] + (size_t)n * 128))[lane];
    float2 bi = ((const float2*)bgi)[lane];
    float2 bo = ((const float2*)bgo)[lane];
    acc.x += bi.x + bo.x;
    acc.y += bi.y + bo.y;
    int p0 = g_off_in[n], p1 = g_off_in[n + 1];
    for (int p = p0; p < p1; ++p) {
        int2 se = g_lst_in[p];
        float wv = g_wbuf[se.y];
        float2 v = ((const float2*)(g_XWx + (size_t)se.x * 256))[lane];
        acc.x += wv * v.x;
        acc.y += wv * v.y;
    }
    p0 = g_off_out[n]; p1 = g_off_out[n + 1];
    for (int p = p0; p < p1; ++p) {
        int2 se = g_lst_out[p];
        float wv = g_wbuf[(size_t)N_EDGES + se.y];
        float2 v = ((const float2*)(g_XWx + (size_t)se.x * 256 + 128))[lane];
        acc.x += wv * v.x;
        acc.y += wv * v.y;
    }
    ((float2*)(g_h[cur ^ 1] + (size_t)n * 128))[lane] = acc;
}

// ---------------- mean-pool partials ----------------
__global__ void pool_kernel(int fin, int side, const int* __restrict__ batch, int N) {
    const float* x = g_h[fin];
    float* gsum = g_gsum[side];
    int n0 = blockIdx.x * 128;
    int d = threadIdx.x;  // 128 threads
    if (n0 >= N) return;
    int nend = min(n0 + 128, N);
    float acc = 0.f;
    int curg = batch[n0];
    for (int n = n0; n < nend; ++n) {
        int g = batch[n];
        if (g != curg) {
            atomicAdd(&gsum[curg * 128 + d], acc);
            acc = 0.f;
            curg = g;
        }
        acc += x[(size_t)n * 128 + d];
    }
    atomicAdd(&gsum[curg * 128 + d], acc);
}

__global__ void count_kernel(int side, const int* __restrict__ batch, int N) {
    int g = threadIdx.x;  // 128 threads
    int lo = 0, hi = N;
    while (lo < hi) { int mid = (lo + hi) >> 1; if (batch[mid] < g) lo = mid + 1; else hi = mid; }
    int a = lo;
    lo = 0; hi = N;
    while (lo < hi) { int mid = (lo + hi) >> 1; if (batch[mid] < g + 1) lo = mid + 1; else hi = mid; }
    g_cnt[side][g] = (float)(lo - a);
}

__global__ void zero_gsum_kernel() {
    int i = blockIdx.x * 256 + threadIdx.x;
    if (i < 2 * N_GRAPHS * NODE_DIM) ((float*)g_gsum)[i] = 0.f;
}

// ---------------- classifier ----------------
__global__ void hidden_kernel(const float* __restrict__ W0, const float* __restrict__ b0) {
    int g = blockIdx.x;
    int j = threadIdx.x;  // 128 x 128
    float inv_s = 1.0f / fmaxf(g_cnt[0][g], 1.0f);
    float inv_t = 1.0f / fmaxf(g_cnt[1][g], 1.0f);
    float acc = b0[j];
    for (int k = 0; k < 128; ++k) acc += g_gsum[0][g * 128 + k] * inv_s * W0[k * 128 + j];
    for (int k = 0; k < 128; ++k) acc += g_gsum[1][g * 128 + k] * inv_t * W0[(128 + k) * 128 + j];
    g_H[g * 128 + j] = fmaxf(acc, 0.f);
}

__global__ void loss_kernel(const float* __restrict__ W1, const float* __restrict__ b1,
                            const int* __restrict__ y, float* __restrict__ out) {
    int g = threadIdx.x;  // 128 threads
    float l0 = b1[0], l1 = b1[1];
    for (int j = 0; j < 128; ++j) {
        float hv = g_H[g * 128 + j];
        l0 += hv * W1[j * 2 + 0];
        l1 += hv * W1[j * 2 + 1];
    }
    float m = fmaxf(l0, l1);
    float lse = m + logf(expf(l0 - m) + expf(l1 - m));
    float ly = (y[g] == 0) ? l0 : l1;
    float c = -(ly - lse) * (1.0f / (float)N_GRAPHS);
    __shared__ float red[128];
    red[g] = c;
    __syncthreads();
    for (int s = 64; s; s >>= 1) {
        if (g < s) red[g] += red[g + s];
        __syncthreads();
    }
    if (g == 0) out[0] = red[0];
}

extern "C" void kernel_launch(void* const* d_in, const int* in_sizes, int n_in,
                              void* d_out, int out_size, void* d_ws, size_t ws_size,
                              hipStream_t stream) {
    const float* x_s      = (const float*)d_in[0];
    const float* x_t      = (const float*)d_in[1];
    const float* ea_s     = (const float*)d_in[2];
    const float* ea_t     = (const float*)d_in[3];
    const int*   ei_s     = (const int*)d_in[4];
    const int*   ei_t     = (const int*)d_in[5];
    const int*   batch_s  = (const int*)d_in[6];
    const int*   batch_t  = (const int*)d_in[7];
    const int*   y        = (const int*)d_in[8];
    const float* node_emb = (const float*)d_in[9];
    const float* edge_emb = (const float*)d_in[10];
    const float* W_in_0   = (const float*)d_in[11];
    const float* W_in_1   = (const float*)d_in[12];
    const float* W_out_0  = (const float*)d_in[13];
    const float* W_out_1  = (const float*)d_in[14];
    const float* Wg_in    = (const float*)d_in[15];
    const float* bg_in    = (const float*)d_in[16];
    const float* Wg_out   = (const float*)d_in[17];
    const float* bg_out   = (const float*)d_in[18];
    const float* cls_W0   = (const float*)d_in[19];
    const float* cls_b0   = (const float*)d_in[20];
    const float* cls_W1   = (const float*)d_in[21];
    const float* cls_b1   = (const float*)d_in[22];

    const int N = N_NODES, E = N_EDGES;

    zero_gsum_kernel<<<(2 * N_GRAPHS * NODE_DIM + 255) / 256, 256, 0, stream>>>();

    for (int side = 0; side < 2; ++side) {
        const float* xin   = side ? x_t : x_s;
        const float* eain  = side ? ea_t : ea_s;
        const int*   ei    = side ? ei_t : ei_s;
        const int*   batch = side ? batch_t : batch_s;
        const int* row = ei;
        const int* col = ei + E;

        node_embed_kernel<<<(N + 3) / 4, 256, 0, stream>>>(xin, node_emb, N);
        edge_embed_kernel<<<(2 * E + 255) / 256, 256, 0, stream>>>(eain, edge_emb, 2 * E);

        // ---- CSR build (once per side; edge_index constant across layers) ----
        csr_zero_kernel<<<(N + 255) / 256, 256, 0, stream>>>();
        csr_count_kernel<<<(E + 255) / 256, 256, 0, stream>>>(row, col, E);
        csr_bsum_kernel<<<dim3(SCAN_NBLK, 2), 256, 0, stream>>>();
        csr_bscan_kernel<<<2, 64, 0, stream>>>();
        csr_off_kernel<<<dim3(SCAN_NBLK, 2), 256, 0, stream>>>(E);
        csr_fill_kernel<<<(E + 255) / 256, 256, 0, stream>>>(row, col, E);

        int cur = 0;
        for (int k = 0; k < K_LAYERS; ++k) {
            const float* Wi0 = W_in_0 + (size_t)k * 320 * 64;
            const float* Wo0 = W_out_0 + (size_t)k * 320 * 64;
            assemble_wcat<<<256, 256, 0, stream>>>(Wi0, Wo0, Wg_in + (size_t)k * 128 * 128,
                                                   Wg_out + (size_t)k * 128 * 128);
            gemm_xw_kernel<<<dim3((N + 63) / 64, 8), 256, 0, stream>>>(cur, N);
            edge_update_kernel<<<dim3((E + 63) / 64, 2), 256, 0, stream>>>(
                row, col, Wi0 + 128 * 64, Wo0 + 128 * 64,
                W_in_1 + (size_t)k * 64, W_out_1 + (size_t)k * 64, E);
            aggregate_kernel<<<(N + 3) / 4, 256, 0, stream>>>(
                cur, bg_in + (size_t)k * 128, bg_out + (size_t)k * 128, N);
            cur ^= 1;
        }
        pool_kernel<<<(N + 127) / 128, 128, 0, stream>>>(cur, side, batch, N);
        count_kernel<<<1, 128, 0, stream>>>(side, batch, N);
    }

    hidden_kernel<<<128, 128, 0, stream>>>(cls_W0, cls_b0);
    loss_kernel<<<1, 128, 0, stream>>>(cls_W1, cls_b1, y, (float*)d_out);
}

// Round 5
// 2484.731 us; speedup vs baseline: 10.8327x; 1.2807x over previous
//
#include <hip/hip_runtime.h>
#include <hip/hip_bf16.h>

#define N_NODES 100000
#define N_EDGES 300000
#define N_GRAPHS 128
#define NODE_VOCAB 200
#define NODE_DIM 128
#define EDGE_DIM 64
#define K_LAYERS 3

#define SCAN_CHUNK 2048
#define SCAN_NBLK ((N_NODES + SCAN_CHUNK - 1) / SCAN_CHUNK)  // 49

typedef unsigned short ushort_t;
typedef __attribute__((ext_vector_type(8))) __bf16 bf16x8;
typedef __attribute__((ext_vector_type(4))) float f32x4;

__device__ inline ushort_t f2bf(float f) {
    unsigned int u = __float_as_uint(f);
    unsigned int r = (u + 0x7fff + ((u >> 16) & 1)) >> 16;
    return (ushort_t)r;
}

// ---------------- static device scratch (no reliance on ws_size) ----------------
__device__ float g_h[2][(size_t)N_NODES * NODE_DIM];      // ping-pong node state (fp32)
__device__ ushort_t g_hb[(size_t)N_NODES * NODE_DIM];     // bf16 mirror of CURRENT state
__device__ float g_ebuf[(size_t)2 * N_EDGES * EDGE_DIM];  // edge state [e_in | e_out]
__device__ float g_XWe[(size_t)N_NODES * 256];            // [XA_in|XC_in|XA_out|XC_out]
__device__ float g_XWx[(size_t)N_NODES * 256];            // [xi | xo]
__device__ ushort_t g_WcatT[512 * 128];                   // Wcat^T bf16 [n][k]
__device__ float g_wbuf[(size_t)2 * N_EDGES];
__device__ float g_gsum[2][N_GRAPHS * NODE_DIM];
__device__ float g_cnt[2][N_GRAPHS];
__device__ float g_H[N_GRAPHS * NODE_DIM];
// CSR (rebuilt per side; constant across layers)
__device__ int  g_deg_in[N_NODES];
__device__ int  g_deg_out[N_NODES];
__device__ int  g_off_in[N_NODES + 1];
__device__ int  g_off_out[N_NODES + 1];
__device__ int  g_cur_in[N_NODES];
__device__ int  g_cur_out[N_NODES];
__device__ int2 g_lst_in[N_EDGES];   // (src=row, e) keyed by col
__device__ int2 g_lst_out[N_EDGES];  // (src=col, e) keyed by row
__device__ int  g_bsum[2][SCAN_NBLK];
__device__ int  g_boff[2][SCAN_NBLK];

// ---------------- node argmax + embed (also writes bf16 mirror) ----------------
__global__ void node_embed_kernel(const float* __restrict__ x, const float* __restrict__ emb,
                                  int N) {
    int wave = threadIdx.x >> 6;
    int lane = threadIdx.x & 63;
    int n = blockIdx.x * 4 + wave;
    if (n >= N) return;
    const float* xr = x + (size_t)n * NODE_VOCAB;
    float v = xr[lane];
    int idx = lane;
    float nv = xr[lane + 64];
    if (nv > v) { v = nv; idx = lane + 64; }
    nv = xr[lane + 128];
    if (nv > v) { v = nv; idx = lane + 128; }
    if (lane < NODE_VOCAB - 192) {
        nv = xr[lane + 192];
        if (nv > v) { v = nv; idx = lane + 192; }
    }
    #pragma unroll
    for (int off = 32; off; off >>= 1) {
        float ov = __shfl_xor(v, off);
        int oi = __shfl_xor(idx, off);
        if (ov > v || (ov == v && oi < idx)) { v = ov; idx = oi; }
    }
    const float* er = emb + (size_t)idx * NODE_DIM;
    float a = er[lane], b = er[64 + lane];
    g_h[0][(size_t)n * NODE_DIM + lane] = a;
    g_h[0][(size_t)n * NODE_DIM + 64 + lane] = b;
    g_hb[(size_t)n * NODE_DIM + lane] = f2bf(a);
    g_hb[(size_t)n * NODE_DIM + 64 + lane] = f2bf(b);
}

// ---------------- edge argmax + embed ----------------
__global__ void edge_embed_kernel(const float* __restrict__ ea, const float* __restrict__ emb,
                                  int M) {
    __shared__ int sidx[256];
    __shared__ float semb[8 * 64];
    int t = threadIdx.x;
    if (t < 128) {
        *(float4*)&semb[t * 4] = *(const float4*)(emb + t * 4);
    }
    long eg = (long)blockIdx.x * 256 + t;
    int best = 0;
    if (eg < M) {
        const float* ar = ea + eg * 8;
        float4 v0 = *(const float4*)ar;
        float4 v1 = *(const float4*)(ar + 4);
        float vals[8] = {v0.x, v0.y, v0.z, v0.w, v1.x, v1.y, v1.z, v1.w};
        float bv = vals[0];
        #pragma unroll
        for (int i = 1; i < 8; ++i)
            if (vals[i] > bv) { bv = vals[i]; best = i; }
    }
    sidx[t] = best;
    __syncthreads();
    long base = (long)blockIdx.x * 256 * 64;
    #pragma unroll 4
    for (int i = 0; i < 64; ++i) {
        long id = (long)i * 256 + t;
        int el = (int)(id >> 6);
        int d = (int)(id & 63);
        long eg2 = (long)blockIdx.x * 256 + el;
        if (eg2 < M) g_ebuf[base + id] = semb[sidx[el] * 64 + d];
    }
}

// ---------------- CSR build ----------------
__global__ void csr_zero_kernel() {
    int i = blockIdx.x * 256 + threadIdx.x;
    if (i < N_NODES) { g_deg_in[i] = 0; g_deg_out[i] = 0; }
}

__global__ void csr_count_kernel(const int* __restrict__ row, const int* __restrict__ col,
                                 int E) {
    int e = blockIdx.x * 256 + threadIdx.x;
    if (e >= E) return;
    atomicAdd(&g_deg_in[col[e]], 1);
    atomicAdd(&g_deg_out[row[e]], 1);
}

// phase 1: per-block sums over chunks of SCAN_CHUNK degrees. grid (SCAN_NBLK, 2) x 256
__global__ void csr_bsum_kernel() {
    int which = blockIdx.y;
    const int* deg = which ? g_deg_out : g_deg_in;
    int b = blockIdx.x;
    int t = threadIdx.x;
    int base = b * SCAN_CHUNK;
    int s = 0;
    #pragma unroll
    for (int i = 0; i < SCAN_CHUNK / 256; ++i) {
        int idx = base + i * 256 + t;
        if (idx < N_NODES) s += deg[idx];
    }
    __shared__ int red[256];
    red[t] = s;
    __syncthreads();
    for (int d = 128; d; d >>= 1) {
        if (t < d) red[t] += red[t + d];
        __syncthreads();
    }
    if (t == 0) g_bsum[which][b] = red[0];
}

// phase 2: exclusive scan of the SCAN_NBLK block sums. grid 2 x 64
__global__ void csr_bscan_kernel() {
    int which = blockIdx.x;
    int t = threadIdx.x;  // 64 threads
    int v = (t < SCAN_NBLK) ? g_bsum[which][t] : 0;
    int orig = v;
    #pragma unroll
    for (int d = 1; d < 64; d <<= 1) {
        int u = __shfl_up(v, d, 64);
        if (t >= d) v += u;
    }
    if (t < SCAN_NBLK) g_boff[which][t] = v - orig;
}

// phase 3: per-block local scan + write off/cur. grid (SCAN_NBLK, 2) x 256
__global__ void csr_off_kernel(int total) {
    int which = blockIdx.y;
    const int* deg = which ? g_deg_out : g_deg_in;
    int* off = which ? g_off_out : g_off_in;
    int* cur = which ? g_cur_out : g_cur_in;
    int b = blockIdx.x;
    int t = threadIdx.x;
    const int per = SCAN_CHUNK / 256;  // 8
    int lo = b * SCAN_CHUNK + t * per;
    int d8[per];
    int s = 0;
    #pragma unroll
    for (int i = 0; i < per; ++i) {
        int idx = lo + i;
        d8[i] = (idx < N_NODES) ? deg[idx] : 0;
        s += d8[i];
    }
    __shared__ int part[256];
    part[t] = s;
    __syncthreads();
    for (int d = 1; d < 256; d <<= 1) {
        int add = (t >= d) ? part[t - d] : 0;
        __syncthreads();
        part[t] += add;
        __syncthreads();
    }
    int run = g_boff[which][b] + part[t] - s;
    #pragma unroll
    for (int i = 0; i < per; ++i) {
        int idx = lo + i;
        if (idx < N_NODES) {
            off[idx] = run;
            cur[idx] = run;
            run += d8[i];
        }
    }
    if (b == 0 && t == 0) off[N_NODES] = total;
}

__global__ void csr_fill_kernel(const int* __restrict__ row, const int* __restrict__ col,
                                int E) {
    int e = blockIdx.x * 256 + threadIdx.x;
    if (e >= E) return;
    int r = row[e], c = col[e];
    int p = atomicAdd(&g_cur_in[c], 1);
    g_lst_in[p] = make_int2(r, e);
    int q = atomicAdd(&g_cur_out[r], 1);
    g_lst_out[q] = make_int2(c, e);
}

// ---------------- assemble Wcat^T (512 x 128, bf16) ----------------
// n-cols: [XA_in(64) | XC_in(64) | XA_out(64) | XC_out(64) | xi(128) | xo(128)]
__global__ void assemble_wcat(const float* __restrict__ Wi0, const float* __restrict__ Wo0,
                              const float* __restrict__ Wgi, const float* __restrict__ Wgo) {
    int idx = blockIdx.x * 256 + threadIdx.x;
    int kd = idx >> 9;
    int j = idx & 511;
    float v;
    if (j < 64) v = Wi0[kd * 64 + j];
    else if (j < 128) v = Wi0[(192 + kd) * 64 + (j - 64)];
    else if (j < 192) v = Wo0[kd * 64 + (j - 128)];
    else if (j < 256) v = Wo0[(192 + kd) * 64 + (j - 192)];
    else if (j < 384) v = Wgi[kd * 128 + (j - 256)];
    else v = Wgo[kd * 128 + (j - 384)];
    g_WcatT[j * 128 + kd] = f2bf(v);
}

// ---------------- node GEMM via MFMA: [XWe | XWx] = x_bf16 (M x 128) @ Wcat (128 x 512) ----------------
// grid (ceil(M/64), 2), 256 threads = 4 waves; wave w covers cols blockIdx.y*256 + w*64 .. +63
__global__ __launch_bounds__(256) void gemm_xw_mfma(int M) {
    int m0 = blockIdx.x * 64;
    int t = threadIdx.x;
    int wave = t >> 6, lane = t & 63;
    int nbase = blockIdx.y * 256 + wave * 64;
    __shared__ ushort_t As[64 * 128];  // 16 KB, XOR-swizzled: elem k ^= (row&7)<<3

    // stage A tile (64 rows x 128 bf16 = 256B/row), coalesced 16B/thread
    #pragma unroll
    for (int i = 0; i < 4; ++i) {
        int idx = t + i * 256;           // 0..1023
        int m = idx >> 4, c = idx & 15;  // row, 16B-chunk (8 elems)
        int gm = m0 + m;
        uint4 v = make_uint4(0u, 0u, 0u, 0u);
        if (gm < M) v = *(const uint4*)(g_hb + (size_t)gm * 128 + c * 8);
        *(uint4*)&As[m * 128 + ((c * 8) ^ ((m & 7) << 3))] = v;
    }
    __syncthreads();

    int lr = lane & 15, lk = lane >> 4;
    f32x4 acc[4][4];
    #pragma unroll
    for (int i = 0; i < 4; ++i)
        #pragma unroll
        for (int j = 0; j < 4; ++j)
            acc[i][j] = (f32x4){0.f, 0.f, 0.f, 0.f};

    const ushort_t* Bbase = g_WcatT + (size_t)nbase * 128;
    #pragma unroll
    for (int ks = 0; ks < 4; ++ks) {
        bf16x8 a[4], b[4];
        int ke = ks * 32 + lk * 8;
        #pragma unroll
        for (int mt = 0; mt < 4; ++mt) {
            int row = mt * 16 + lr;
            a[mt] = *(const bf16x8*)&As[row * 128 + (ke ^ ((row & 7) << 3))];
        }
        #pragma unroll
        for (int nt = 0; nt < 4; ++nt) {
            b[nt] = *(const bf16x8*)(Bbase + (size_t)(nt * 16 + lr) * 128 + ke);
        }
        #pragma unroll
        for (int mt = 0; mt < 4; ++mt)
            #pragma unroll
            for (int nt = 0; nt < 4; ++nt)
                acc[mt][nt] = __builtin_amdgcn_mfma_f32_16x16x32_bf16(a[mt], b[nt], acc[mt][nt], 0, 0, 0);
    }

    // epilogue: D row = lk*4 + r (within 16-tile), col = lr
    #pragma unroll
    for (int mt = 0; mt < 4; ++mt) {
        #pragma unroll
        for (int r = 0; r < 4; ++r) {
            int gm = m0 + mt * 16 + lk * 4 + r;
            if (gm >= M) continue;
            #pragma unroll
            for (int nt = 0; nt < 4; ++nt) {
                int n = nbase + nt * 16 + lr;
                float* dst = (n < 256) ? (g_XWe + (size_t)gm * 256 + n)
                                       : (g_XWx + (size_t)gm * 256 + (n - 256));
                *dst = acc[mt][nt][r];
            }
        }
    }
}

// ------- edge update (in-place) + fused gate: e = e@Wmid + XA + XC; w = sigmoid(e.W1) -------
__global__ __launch_bounds__(256) void edge_update_kernel(const int* __restrict__ row,
                                                          const int* __restrict__ col,
                                                          const float* __restrict__ Wmid_in,
                                                          const float* __restrict__ Wmid_out,
                                                          const float* __restrict__ W1_in,
                                                          const float* __restrict__ W1_out,
                                                          int E) {
    int b = blockIdx.y;
    int e0 = blockIdx.x * 64;
    const float* Wmid = b ? Wmid_out : Wmid_in;
    const float* W1 = b ? W1_out : W1_in;
    float* ebuf = g_ebuf + (size_t)b * E * 64;
    __shared__ float As[64][68];
    __shared__ float Bs[64][64];
    __shared__ float sW1[64];
    int t = threadIdx.x;
    if (t < 64) sW1[t] = W1[t];
    #pragma unroll
    for (int i = 0; i < 4; ++i) {
        int idx = t + i * 256;
        int m = idx >> 4;
        int f = idx & 15;
        int eg = e0 + m;
        float4 v = (eg < E) ? *(const float4*)(ebuf + (size_t)eg * 64 + f * 4)
                            : make_float4(0.f, 0.f, 0.f, 0.f);
        As[f * 4 + 0][m] = v.x;
        As[f * 4 + 1][m] = v.y;
        As[f * 4 + 2][m] = v.z;
        As[f * 4 + 3][m] = v.w;
    }
    #pragma unroll
    for (int i = 0; i < 4; ++i) {
        int idx = t + i * 256;
        int k = idx >> 4;
        int f = idx & 15;
        *(float4*)&Bs[k][f * 4] = *(const float4*)(Wmid + k * 64 + f * 4);
    }
    __syncthreads();
    int tx = t & 15, ty = t >> 4;
    float acc[4][4] = {};
    #pragma unroll 16
    for (int k = 0; k < 64; ++k) {
        float4 a4 = *(const float4*)&As[k][ty * 4];
        float4 b4 = *(const float4*)&Bs[k][tx * 4];
        float av[4] = {a4.x, a4.y, a4.z, a4.w};
        float bv[4] = {b4.x, b4.y, b4.z, b4.w};
        #pragma unroll
        for (int i = 0; i < 4; ++i)
            #pragma unroll
            for (int j = 0; j < 4; ++j)
                acc[i][j] = fmaf(av[i], bv[j], acc[i][j]);
    }
    float w1x = sW1[tx * 4 + 0];
    float w1y = sW1[tx * 4 + 1];
    float w1z = sW1[tx * 4 + 2];
    float w1w = sW1[tx * 4 + 3];
    #pragma unroll
    for (int i = 0; i < 4; ++i) {
        int eg = e0 + ty * 4 + i;
        if (eg >= E) continue;
        int r = row[eg], c = col[eg];
        int ga = b ? c : r;
        int ja = b ? 128 : 0;
        int gc = b ? r : c;
        int jc = b ? 192 : 64;
        int j0 = tx * 4;
        float4 x1 = *(const float4*)(g_XWe + (size_t)ga * 256 + ja + j0);
        float4 x2 = *(const float4*)(g_XWe + (size_t)gc * 256 + jc + j0);
        float4 o;
        o.x = acc[i][0] + x1.x + x2.x;
        o.y = acc[i][1] + x1.y + x2.y;
        o.z = acc[i][2] + x1.z + x2.z;
        o.w = acc[i][3] + x1.w + x2.w;
        *(float4*)(ebuf + (size_t)eg * 64 + j0) = o;
        // fused gate: partial dot with W1, reduce across the 16 tx lanes
        float p = o.x * w1x + o.y * w1y + o.z * w1z + o.w * w1w;
        p += __shfl_xor(p, 1);
        p += __shfl_xor(p, 2);
        p += __shfl_xor(p, 4);
        p += __shfl_xor(p, 8);
        if (tx == 0) g_wbuf[(size_t)b * E + eg] = 1.0f / (1.0f + expf(-p));
    }
}

// ---------------- fused aggregate: x_next = x + bgi + bgo + CSR-gathered in/out sums ----------------
// also writes bf16 mirror for next layer's MFMA GEMM
__global__ __launch_bounds__(256) void aggregate_kernel(int cur, const float* __restrict__ bgi,
                                                        const float* __restrict__ bgo, int N) {
    int wave = threadIdx.x >> 6;
    int lane = threadIdx.x & 63;
    int n = blockIdx.x * 4 + wave;
    if (n >= N) return;
    float2 acc = ((const float2*)(g_h[cur] + (size_t)n * 128))[lane];
    float2 bi = ((const float2*)bgi)[lane];
    float2 bo = ((const float2*)bgo)[lane];
    acc.x += bi.x + bo.x;
    acc.y += bi.y + bo.y;
    int p0 = g_off_in[n], p1 = g_off_in[n + 1];
    for (int p = p0; p < p1; ++p) {
        int2 se = g_lst_in[p];
        float wv = g_wbuf[se.y];
        float2 v = ((const float2*)(g_XWx + (size_t)se.x * 256))[lane];
        acc.x += wv * v.x;
        acc.y += wv * v.y;
    }
    p0 = g_off_out[n]; p1 = g_off_out[n + 1];
    for (int p = p0; p < p1; ++p) {
        int2 se = g_lst_out[p];
        float wv = g_wbuf[(size_t)N_EDGES + se.y];
        float2 v = ((const float2*)(g_XWx + (size_t)se.x * 256 + 128))[lane];
        acc.x += wv * v.x;
        acc.y += wv * v.y;
    }
    ((float2*)(g_h[cur ^ 1] + (size_t)n * 128))[lane] = acc;
    unsigned int pk = ((unsigned int)f2bf(acc.y) << 16) | (unsigned int)f2bf(acc.x);
    ((unsigned int*)g_hb)[(size_t)n * 64 + lane] = pk;
}

// ---------------- mean-pool partials ----------------
__global__ void pool_kernel(int fin, int side, const int* __restrict__ batch, int N) {
    const float* x = g_h[fin];
    float* gsum = g_gsum[side];
    int n0 = blockIdx.x * 128;
    int d = threadIdx.x;  // 128 threads
    if (n0 >= N) return;
    int nend = min(n0 + 128, N);
    float acc = 0.f;
    int curg = batch[n0];
    for (int n = n0; n < nend; ++n) {
        int g = batch[n];
        if (g != curg) {
            atomicAdd(&gsum[curg * 128 + d], acc);
            acc = 0.f;
            curg = g;
        }
        acc += x[(size_t)n * 128 + d];
    }
    atomicAdd(&gsum[curg * 128 + d], acc);
}

__global__ void count_kernel(int side, const int* __restrict__ batch, int N) {
    int g = threadIdx.x;  // 128 threads
    int lo = 0, hi = N;
    while (lo < hi) { int mid = (lo + hi) >> 1; if (batch[mid] < g) lo = mid + 1; else hi = mid; }
    int a = lo;
    lo = 0; hi = N;
    while (lo < hi) { int mid = (lo + hi) >> 1; if (batch[mid] < g + 1) lo = mid + 1; else hi = mid; }
    g_cnt[side][g] = (float)(lo - a);
}

__global__ void zero_gsum_kernel() {
    int i = blockIdx.x * 256 + threadIdx.x;
    if (i < 2 * N_GRAPHS * NODE_DIM) ((float*)g_gsum)[i] = 0.f;
}

// ---------------- classifier ----------------
__global__ void hidden_kernel(const float* __restrict__ W0, const float* __restrict__ b0) {
    int g = blockIdx.x;
    int j = threadIdx.x;  // 128 x 128
    float inv_s = 1.0f / fmaxf(g_cnt[0][g], 1.0f);
    float inv_t = 1.0f / fmaxf(g_cnt[1][g], 1.0f);
    float acc = b0[j];
    for (int k = 0; k < 128; ++k) acc += g_gsum[0][g * 128 + k] * inv_s * W0[k * 128 + j];
    for (int k = 0; k < 128; ++k) acc += g_gsum[1][g * 128 + k] * inv_t * W0[(128 + k) * 128 + j];
    g_H[g * 128 + j] = fmaxf(acc, 0.f);
}

__global__ void loss_kernel(const float* __restrict__ W1, const float* __restrict__ b1,
                            const int* __restrict__ y, float* __restrict__ out) {
    int g = threadIdx.x;  // 128 threads
    float l0 = b1[0], l1 = b1[1];
    for (int j = 0; j < 128; ++j) {
        float hv = g_H[g * 128 + j];
        l0 += hv * W1[j * 2 + 0];
        l1 += hv * W1[j * 2 + 1];
    }
    float m = fmaxf(l0, l1);
    float lse = m + logf(expf(l0 - m) + expf(l1 - m));
    float ly = (y[g] == 0) ? l0 : l1;
    float c = -(ly - lse) * (1.0f / (float)N_GRAPHS);
    __shared__ float red[128];
    red[g] = c;
    __syncthreads();
    for (int s = 64; s; s >>= 1) {
        if (g < s) red[g] += red[g + s];
        __syncthreads();
    }
    if (g == 0) out[0] = red[0];
}

extern "C" void kernel_launch(void* const* d_in, const int* in_sizes, int n_in,
                              void* d_out, int out_size, void* d_ws, size_t ws_size,
                              hipStream_t stream) {
    const float* x_s      = (const float*)d_in[0];
    const float* x_t      = (const float*)d_in[1];
    const float* ea_s     = (const float*)d_in[2];
    const float* ea_t     = (const float*)d_in[3];
    const int*   ei_s     = (const int*)d_in[4];
    const int*   ei_t     = (const int*)d_in[5];
    const int*   batch_s  = (const int*)d_in[6];
    const int*   batch_t  = (const int*)d_in[7];
    const int*   y        = (const int*)d_in[8];
    const float* node_emb = (const float*)d_in[9];
    const float* edge_emb = (const float*)d_in[10];
    const float* W_in_0   = (const float*)d_in[11];
    const float* W_in_1   = (const float*)d_in[12];
    const float* W_out_0  = (const float*)d_in[13];
    const float* W_out_1  = (const float*)d_in[14];
    const float* Wg_in    = (const float*)d_in[15];
    const float* bg_in    = (const float*)d_in[16];
    const float* Wg_out   = (const float*)d_in[17];
    const float* bg_out   = (const float*)d_in[18];
    const float* cls_W0   = (const float*)d_in[19];
    const float* cls_b0   = (const float*)d_in[20];
    const float* cls_W1   = (const float*)d_in[21];
    const float* cls_b1   = (const float*)d_in[22];

    const int N = N_NODES, E = N_EDGES;

    zero_gsum_kernel<<<(2 * N_GRAPHS * NODE_DIM + 255) / 256, 256, 0, stream>>>();

    for (int side = 0; side < 2; ++side) {
        const float* xin   = side ? x_t : x_s;
        const float* eain  = side ? ea_t : ea_s;
        const int*   ei    = side ? ei_t : ei_s;
        const int*   batch = side ? batch_t : batch_s;
        const int* row = ei;
        const int* col = ei + E;

        node_embed_kernel<<<(N + 3) / 4, 256, 0, stream>>>(xin, node_emb, N);
        edge_embed_kernel<<<(2 * E + 255) / 256, 256, 0, stream>>>(eain, edge_emb, 2 * E);

        // ---- CSR build (once per side; edge_index constant across layers) ----
        csr_zero_kernel<<<(N + 255) / 256, 256, 0, stream>>>();
        csr_count_kernel<<<(E + 255) / 256, 256, 0, stream>>>(row, col, E);
        csr_bsum_kernel<<<dim3(SCAN_NBLK, 2), 256, 0, stream>>>();
        csr_bscan_kernel<<<2, 64, 0, stream>>>();
        csr_off_kernel<<<dim3(SCAN_NBLK, 2), 256, 0, stream>>>(E);
        csr_fill_kernel<<<(E + 255) / 256, 256, 0, stream>>>(row, col, E);

        int cur = 0;
        for (int k = 0; k < K_LAYERS; ++k) {
            const float* Wi0 = W_in_0 + (size_t)k * 320 * 64;
            const float* Wo0 = W_out_0 + (size_t)k * 320 * 64;
            assemble_wcat<<<256, 256, 0, stream>>>(Wi0, Wo0, Wg_in + (size_t)k * 128 * 128,
                                                   Wg_out + (size_t)k * 128 * 128);
            gemm_xw_mfma<<<dim3((N + 63) / 64, 2), 256, 0, stream>>>(N);
            edge_update_kernel<<<dim3((E + 63) / 64, 2), 256, 0, stream>>>(
                row, col, Wi0 + 128 * 64, Wo0 + 128 * 64,
                W_in_1 + (size_t)k * 64, W_out_1 + (size_t)k * 64, E);
            aggregate_kernel<<<(N + 3) / 4, 256, 0, stream>>>(
                cur, bg_in + (size_t)k * 128, bg_out + (size_t)k * 128, N);
            cur ^= 1;
        }
        pool_kernel<<<(N + 127) / 128, 128, 0, stream>>>(cur, side, batch, N);
        count_kernel<<<1, 128, 0, stream>>>(side, batch, N);
    }

    hidden_kernel<<<128, 128, 0, stream>>>(cls_W0, cls_b0);
    loss_kernel<<<1, 128, 0, stream>>>(cls_W1, cls_b1, y, (float*)d_out);
}

// Round 6
// 2349.824 us; speedup vs baseline: 11.4546x; 1.0574x over previous
//
#include <hip/hip_runtime.h>
#include <hip/hip_bf16.h>

#define N_NODES 100000
#define N_EDGES 300000
#define N_GRAPHS 128
#define NODE_VOCAB 200
#define NODE_DIM 128
#define EDGE_DIM 64
#define K_LAYERS 3

#define SCAN_CHUNK 2048
#define SCAN_NBLK ((N_NODES + SCAN_CHUNK - 1) / SCAN_CHUNK)  // 49

typedef unsigned short ushort_t;
typedef __attribute__((ext_vector_type(8))) __bf16 bf16x8;
typedef __attribute__((ext_vector_type(4))) float f32x4;

__device__ inline ushort_t f2bf(float f) {
    unsigned int u = __float_as_uint(f);
    unsigned int r = (u + 0x7fff + ((u >> 16) & 1)) >> 16;
    return (ushort_t)r;
}

// ---------------- static device scratch (no reliance on ws_size) ----------------
__device__ float g_h[2][(size_t)N_NODES * NODE_DIM];        // ping-pong node state (fp32)
__device__ ushort_t g_hb[(size_t)N_NODES * NODE_DIM];       // bf16 mirror of CURRENT state
__device__ ushort_t g_ebuf_b[(size_t)2 * N_EDGES * EDGE_DIM]; // edge state bf16 [e_in | e_out]
__device__ float g_XWe[(size_t)N_NODES * 256];              // [XA_in|XC_in|XA_out|XC_out]
__device__ float g_XWx[(size_t)N_NODES * 256];              // [xi | xo]
__device__ ushort_t g_WcatT[512 * 128];                     // Wcat^T bf16 [n][k]
__device__ ushort_t g_WmidT[2][64 * 64];                    // Wmid^T bf16 [outcol][k]
__device__ float g_wbuf[(size_t)2 * N_EDGES];
__device__ float g_gsum[2][N_GRAPHS * NODE_DIM];
__device__ float g_cnt[2][N_GRAPHS];
__device__ float g_H[N_GRAPHS * NODE_DIM];
// CSR (rebuilt per side; constant across layers)
__device__ int  g_deg_in[N_NODES];
__device__ int  g_deg_out[N_NODES];
__device__ int  g_off_in[N_NODES + 1];
__device__ int  g_off_out[N_NODES + 1];
__device__ int  g_cur_in[N_NODES];
__device__ int  g_cur_out[N_NODES];
__device__ int2 g_lst_in[N_EDGES];   // (src=row, e) keyed by col
__device__ int2 g_lst_out[N_EDGES];  // (src=col, e) keyed by row
__device__ int  g_bsum[2][SCAN_NBLK];
__device__ int  g_boff[2][SCAN_NBLK];

// ---------------- node argmax + embed (also writes bf16 mirror) ----------------
__global__ void node_embed_kernel(const float* __restrict__ x, const float* __restrict__ emb,
                                  int N) {
    int wave = threadIdx.x >> 6;
    int lane = threadIdx.x & 63;
    int n = blockIdx.x * 4 + wave;
    if (n >= N) return;
    const float* xr = x + (size_t)n * NODE_VOCAB;
    float v = xr[lane];
    int idx = lane;
    float nv = xr[lane + 64];
    if (nv > v) { v = nv; idx = lane + 64; }
    nv = xr[lane + 128];
    if (nv > v) { v = nv; idx = lane + 128; }
    if (lane < NODE_VOCAB - 192) {
        nv = xr[lane + 192];
        if (nv > v) { v = nv; idx = lane + 192; }
    }
    #pragma unroll
    for (int off = 32; off; off >>= 1) {
        float ov = __shfl_xor(v, off);
        int oi = __shfl_xor(idx, off);
        if (ov > v || (ov == v && oi < idx)) { v = ov; idx = oi; }
    }
    const float* er = emb + (size_t)idx * NODE_DIM;
    float a = er[lane], b = er[64 + lane];
    g_h[0][(size_t)n * NODE_DIM + lane] = a;
    g_h[0][(size_t)n * NODE_DIM + 64 + lane] = b;
    g_hb[(size_t)n * NODE_DIM + lane] = f2bf(a);
    g_hb[(size_t)n * NODE_DIM + 64 + lane] = f2bf(b);
}

// ---------------- edge argmax + embed (bf16 out) ----------------
__global__ void edge_embed_kernel(const float* __restrict__ ea, const float* __restrict__ emb,
                                  int M) {
    __shared__ int sidx[256];
    __shared__ float semb[8 * 64];
    int t = threadIdx.x;
    if (t < 128) {
        *(float4*)&semb[t * 4] = *(const float4*)(emb + t * 4);
    }
    long eg = (long)blockIdx.x * 256 + t;
    int best = 0;
    if (eg < M) {
        const float* ar = ea + eg * 8;
        float4 v0 = *(const float4*)ar;
        float4 v1 = *(const float4*)(ar + 4);
        float vals[8] = {v0.x, v0.y, v0.z, v0.w, v1.x, v1.y, v1.z, v1.w};
        float bv = vals[0];
        #pragma unroll
        for (int i = 1; i < 8; ++i)
            if (vals[i] > bv) { bv = vals[i]; best = i; }
    }
    sidx[t] = best;
    __syncthreads();
    long base = (long)blockIdx.x * 256 * 64;
    #pragma unroll 4
    for (int i = 0; i < 64; ++i) {
        long id = (long)i * 256 + t;
        int el = (int)(id >> 6);
        int d = (int)(id & 63);
        long eg2 = (long)blockIdx.x * 256 + el;
        if (eg2 < M) g_ebuf_b[base + id] = f2bf(semb[sidx[el] * 64 + d]);
    }
}

// ---------------- CSR build ----------------
__global__ void csr_zero_kernel() {
    int i = blockIdx.x * 256 + threadIdx.x;
    if (i < N_NODES) { g_deg_in[i] = 0; g_deg_out[i] = 0; }
}

__global__ void csr_count_kernel(const int* __restrict__ row, const int* __restrict__ col,
                                 int E) {
    int e = blockIdx.x * 256 + threadIdx.x;
    if (e >= E) return;
    atomicAdd(&g_deg_in[col[e]], 1);
    atomicAdd(&g_deg_out[row[e]], 1);
}

// phase 1: per-block sums over chunks of SCAN_CHUNK degrees. grid (SCAN_NBLK, 2) x 256
__global__ void csr_bsum_kernel() {
    int which = blockIdx.y;
    const int* deg = which ? g_deg_out : g_deg_in;
    int b = blockIdx.x;
    int t = threadIdx.x;
    int base = b * SCAN_CHUNK;
    int s = 0;
    #pragma unroll
    for (int i = 0; i < SCAN_CHUNK / 256; ++i) {
        int idx = base + i * 256 + t;
        if (idx < N_NODES) s += deg[idx];
    }
    __shared__ int red[256];
    red[t] = s;
    __syncthreads();
    for (int d = 128; d; d >>= 1) {
        if (t < d) red[t] += red[t + d];
        __syncthreads();
    }
    if (t == 0) g_bsum[which][b] = red[0];
}

// phase 2: exclusive scan of the SCAN_NBLK block sums. grid 2 x 64
__global__ void csr_bscan_kernel() {
    int which = blockIdx.x;
    int t = threadIdx.x;  // 64 threads
    int v = (t < SCAN_NBLK) ? g_bsum[which][t] : 0;
    int orig = v;
    #pragma unroll
    for (int d = 1; d < 64; d <<= 1) {
        int u = __shfl_up(v, d, 64);
        if (t >= d) v += u;
    }
    if (t < SCAN_NBLK) g_boff[which][t] = v - orig;
}

// phase 3: per-block local scan + write off/cur. grid (SCAN_NBLK, 2) x 256
__global__ void csr_off_kernel(int total) {
    int which = blockIdx.y;
    const int* deg = which ? g_deg_out : g_deg_in;
    int* off = which ? g_off_out : g_off_in;
    int* cur = which ? g_cur_out : g_cur_in;
    int b = blockIdx.x;
    int t = threadIdx.x;
    const int per = SCAN_CHUNK / 256;  // 8
    int lo = b * SCAN_CHUNK + t * per;
    int d8[per];
    int s = 0;
    #pragma unroll
    for (int i = 0; i < per; ++i) {
        int idx = lo + i;
        d8[i] = (idx < N_NODES) ? deg[idx] : 0;
        s += d8[i];
    }
    __shared__ int part[256];
    part[t] = s;
    __syncthreads();
    for (int d = 1; d < 256; d <<= 1) {
        int add = (t >= d) ? part[t - d] : 0;
        __syncthreads();
        part[t] += add;
        __syncthreads();
    }
    int run = g_boff[which][b] + part[t] - s;
    #pragma unroll
    for (int i = 0; i < per; ++i) {
        int idx = lo + i;
        if (idx < N_NODES) {
            off[idx] = run;
            cur[idx] = run;
            run += d8[i];
        }
    }
    if (b == 0 && t == 0) off[N_NODES] = total;
}

__global__ void csr_fill_kernel(const int* __restrict__ row, const int* __restrict__ col,
                                int E) {
    int e = blockIdx.x * 256 + threadIdx.x;
    if (e >= E) return;
    int r = row[e], c = col[e];
    int p = atomicAdd(&g_cur_in[c], 1);
    g_lst_in[p] = make_int2(r, e);
    int q = atomicAdd(&g_cur_out[r], 1);
    g_lst_out[q] = make_int2(c, e);
}

// ---------------- assemble Wcat^T (512 x 128, bf16) ----------------
// n-cols: [XA_in(64) | XC_in(64) | XA_out(64) | XC_out(64) | xi(128) | xo(128)]
__global__ void assemble_wcat(const float* __restrict__ Wi0, const float* __restrict__ Wo0,
                              const float* __restrict__ Wgi, const float* __restrict__ Wgo) {
    int idx = blockIdx.x * 256 + threadIdx.x;
    int kd = idx >> 9;
    int j = idx & 511;
    float v;
    if (j < 64) v = Wi0[kd * 64 + j];
    else if (j < 128) v = Wi0[(192 + kd) * 64 + (j - 64)];
    else if (j < 192) v = Wo0[kd * 64 + (j - 128)];
    else if (j < 256) v = Wo0[(192 + kd) * 64 + (j - 192)];
    else if (j < 384) v = Wgi[kd * 128 + (j - 256)];
    else v = Wgo[kd * 128 + (j - 384)];
    g_WcatT[j * 128 + kd] = f2bf(v);
}

// ---------------- assemble Wmid^T (2 x 64 x 64, bf16): WmidT[b][oc][k] = W[(128+k)*64+oc] ----------------
__global__ void assemble_wmidt(const float* __restrict__ Wi0, const float* __restrict__ Wo0) {
    int idx = blockIdx.x * 256 + threadIdx.x;  // 8192 total
    int b = idx >> 12;
    int rem = idx & 4095;
    int oc = rem >> 6, kk = rem & 63;
    const float* W = (b ? Wo0 : Wi0) + 128 * 64;
    g_WmidT[b][oc * 64 + kk] = f2bf(W[kk * 64 + oc]);
}

// ---------------- node GEMM via MFMA: [XWe | XWx] = x_bf16 (M x 128) @ Wcat (128 x 512) ----------------
__global__ __launch_bounds__(256) void gemm_xw_mfma(int M) {
    int m0 = blockIdx.x * 64;
    int t = threadIdx.x;
    int wave = t >> 6, lane = t & 63;
    int nbase = blockIdx.y * 256 + wave * 64;
    __shared__ ushort_t As[64 * 128];  // 16 KB, XOR-swizzled: elem k ^= (row&7)<<3

    #pragma unroll
    for (int i = 0; i < 4; ++i) {
        int idx = t + i * 256;           // 0..1023
        int m = idx >> 4, c = idx & 15;  // row, 16B-chunk (8 elems)
        int gm = m0 + m;
        uint4 v = make_uint4(0u, 0u, 0u, 0u);
        if (gm < M) v = *(const uint4*)(g_hb + (size_t)gm * 128 + c * 8);
        *(uint4*)&As[m * 128 + ((c * 8) ^ ((m & 7) << 3))] = v;
    }
    __syncthreads();

    int lr = lane & 15, lk = lane >> 4;
    f32x4 acc[4][4];
    #pragma unroll
    for (int i = 0; i < 4; ++i)
        #pragma unroll
        for (int j = 0; j < 4; ++j)
            acc[i][j] = (f32x4){0.f, 0.f, 0.f, 0.f};

    const ushort_t* Bbase = g_WcatT + (size_t)nbase * 128;
    #pragma unroll
    for (int ks = 0; ks < 4; ++ks) {
        bf16x8 a[4], b[4];
        int ke = ks * 32 + lk * 8;
        #pragma unroll
        for (int mt = 0; mt < 4; ++mt) {
            int row = mt * 16 + lr;
            a[mt] = *(const bf16x8*)&As[row * 128 + (ke ^ ((row & 7) << 3))];
        }
        #pragma unroll
        for (int nt = 0; nt < 4; ++nt) {
            b[nt] = *(const bf16x8*)(Bbase + (size_t)(nt * 16 + lr) * 128 + ke);
        }
        #pragma unroll
        for (int mt = 0; mt < 4; ++mt)
            #pragma unroll
            for (int nt = 0; nt < 4; ++nt)
                acc[mt][nt] = __builtin_amdgcn_mfma_f32_16x16x32_bf16(a[mt], b[nt], acc[mt][nt], 0, 0, 0);
    }

    #pragma unroll
    for (int mt = 0; mt < 4; ++mt) {
        #pragma unroll
        for (int r = 0; r < 4; ++r) {
            int gm = m0 + mt * 16 + lk * 4 + r;
            if (gm >= M) continue;
            #pragma unroll
            for (int nt = 0; nt < 4; ++nt) {
                int n = nbase + nt * 16 + lr;
                float* dst = (n < 256) ? (g_XWe + (size_t)gm * 256 + n)
                                       : (g_XWx + (size_t)gm * 256 + (n - 256));
                *dst = acc[mt][nt][r];
            }
        }
    }
}

// ------- edge update via swapped MFMA (no LDS, no barriers) + fused gate -------
// D' = Wmid^T @ e^T : lane owns 4 consecutive out-cols (j0=mt*16+lk*4) of edge (lr).
__global__ __launch_bounds__(256) void edge_update_mfma(const int* __restrict__ row,
                                                        const int* __restrict__ col,
                                                        const float* __restrict__ W1_in,
                                                        const float* __restrict__ W1_out,
                                                        int E) {
    int b = blockIdx.y;
    int t = threadIdx.x;
    int wave = t >> 6, lane = t & 63;
    int lr = lane & 15, lk = lane >> 4;
    int e0 = blockIdx.x * 256 + wave * 64;
    const float* W1 = b ? W1_out : W1_in;
    const ushort_t* WT = g_WmidT[b];
    ushort_t* ebuf = g_ebuf_b + (size_t)b * E * 64;

    // Wmid^T fragments: wf[mt][ks] <- WT[(mt*16+lr)][ks*32 + lk*8 ..+8]
    bf16x8 wf[4][2];
    #pragma unroll
    for (int mt = 0; mt < 4; ++mt)
        #pragma unroll
        for (int ks = 0; ks < 2; ++ks)
            wf[mt][ks] = *(const bf16x8*)&WT[(mt * 16 + lr) * 64 + ks * 32 + lk * 8];

    bf16x8 zero8;
    #pragma unroll
    for (int q = 0; q < 8; ++q) zero8[q] = (__bf16)0.0f;

    #pragma unroll
    for (int half = 0; half < 2; ++half) {
        // e fragments for 2 n-tiles (32 edges)
        bf16x8 ef[2][2];
        #pragma unroll
        for (int j = 0; j < 2; ++j) {
            int eg = e0 + (half * 2 + j) * 16 + lr;
            if (eg < E) {
                const ushort_t* er = ebuf + (size_t)eg * 64 + lk * 8;
                ef[j][0] = *(const bf16x8*)er;
                ef[j][1] = *(const bf16x8*)(er + 32);
            } else {
                ef[j][0] = zero8;
                ef[j][1] = zero8;
            }
        }
        f32x4 acc[4][2];
        #pragma unroll
        for (int mt = 0; mt < 4; ++mt)
            #pragma unroll
            for (int j = 0; j < 2; ++j)
                acc[mt][j] = (f32x4){0.f, 0.f, 0.f, 0.f};
        #pragma unroll
        for (int ks = 0; ks < 2; ++ks)
            #pragma unroll
            for (int mt = 0; mt < 4; ++mt)
                #pragma unroll
                for (int j = 0; j < 2; ++j)
                    acc[mt][j] = __builtin_amdgcn_mfma_f32_16x16x32_bf16(wf[mt][ks], ef[j][ks], acc[mt][j], 0, 0, 0);

        #pragma unroll
        for (int j = 0; j < 2; ++j) {
            int eg = e0 + (half * 2 + j) * 16 + lr;
            if (eg < E) {
                int r = row[eg], c = col[eg];
                int ga = b ? c : r;
                int gc = b ? r : c;
                const float* x1p = g_XWe + (size_t)ga * 256 + (b ? 128 : 0);
                const float* x2p = g_XWe + (size_t)gc * 256 + (b ? 192 : 64);
                float p = 0.f;
                #pragma unroll
                for (int mt = 0; mt < 4; ++mt) {
                    int j0 = mt * 16 + lk * 4;
                    float4 x1 = *(const float4*)(x1p + j0);
                    float4 x2 = *(const float4*)(x2p + j0);
                    f32x4 av = acc[mt][j];
                    float ox = av[0] + x1.x + x2.x;
                    float oy = av[1] + x1.y + x2.y;
                    float oz = av[2] + x1.z + x2.z;
                    float ow = av[3] + x1.w + x2.w;
                    uint2 pk;
                    pk.x = ((unsigned int)f2bf(oy) << 16) | (unsigned int)f2bf(ox);
                    pk.y = ((unsigned int)f2bf(ow) << 16) | (unsigned int)f2bf(oz);
                    *(uint2*)&ebuf[(size_t)eg * 64 + j0] = pk;
                    float4 wv = *(const float4*)(W1 + j0);
                    p += ox * wv.x + oy * wv.y + oz * wv.z + ow * wv.w;
                }
                p += __shfl_xor(p, 16);
                p += __shfl_xor(p, 32);
                if (lk == 0) g_wbuf[(size_t)b * E + eg] = 1.0f / (1.0f + expf(-p));
            }
        }
    }
}

// ---------------- fused aggregate: x_next = x + bgi + bgo + CSR-gathered in/out sums ----------------
// also writes bf16 mirror for next layer's MFMA GEMM
__global__ __launch_bounds__(256) void aggregate_kernel(int cur, const float* __restrict__ bgi,
                                                        const float* __restrict__ bgo, int N) {
    int wave = threadIdx.x >> 6;
    int lane = threadIdx.x & 63;
    int n = blockIdx.x * 4 + wave;
    if (n >= N) return;
    float2 acc = ((const float2*)(g_h[cur] + (size_t)n * 128))[lane];
    float2 bi = ((const float2*)bgi)[lane];
    float2 bo = ((const float2*)bgo)[lane];
    acc.x += bi.x + bo.x;
    acc.y += bi.y + bo.y;
    int p0 = g_off_in[n], p1 = g_off_in[n + 1];
    for (int p = p0; p < p1; ++p) {
        int2 se = g_lst_in[p];
        float wv = g_wbuf[se.y];
        float2 v = ((const float2*)(g_XWx + (size_t)se.x * 256))[lane];
        acc.x += wv * v.x;
        acc.y += wv * v.y;
    }
    p0 = g_off_out[n]; p1 = g_off_out[n + 1];
    for (int p = p0; p < p1; ++p) {
        int2 se = g_lst_out[p];
        float wv = g_wbuf[(size_t)N_EDGES + se.y];
        float2 v = ((const float2*)(g_XWx + (size_t)se.x * 256 + 128))[lane];
        acc.x += wv * v.x;
        acc.y += wv * v.y;
    }
    ((float2*)(g_h[cur ^ 1] + (size_t)n * 128))[lane] = acc;
    unsigned int pk = ((unsigned int)f2bf(acc.y) << 16) | (unsigned int)f2bf(acc.x);
    ((unsigned int*)g_hb)[(size_t)n * 64 + lane] = pk;
}

// ---------------- mean-pool partials ----------------
__global__ void pool_kernel(int fin, int side, const int* __restrict__ batch, int N) {
    const float* x = g_h[fin];
    float* gsum = g_gsum[side];
    int n0 = blockIdx.x * 128;
    int d = threadIdx.x;  // 128 threads
    if (n0 >= N) return;
    int nend = min(n0 + 128, N);
    float acc = 0.f;
    int curg = batch[n0];
    for (int n = n0; n < nend; ++n) {
        int g = batch[n];
        if (g != curg) {
            atomicAdd(&gsum[curg * 128 + d], acc);
            acc = 0.f;
            curg = g;
        }
        acc += x[(size_t)n * 128 + d];
    }
    atomicAdd(&gsum[curg * 128 + d], acc);
}

__global__ void count_kernel(int side, const int* __restrict__ batch, int N) {
    int g = threadIdx.x;  // 128 threads
    int lo = 0, hi = N;
    while (lo < hi) { int mid = (lo + hi) >> 1; if (batch[mid] < g) lo = mid + 1; else hi = mid; }
    int a = lo;
    lo = 0; hi = N;
    while (lo < hi) { int mid = (lo + hi) >> 1; if (batch[mid] < g + 1) lo = mid + 1; else hi = mid; }
    g_cnt[side][g] = (float)(lo - a);
}

__global__ void zero_gsum_kernel() {
    int i = blockIdx.x * 256 + threadIdx.x;
    if (i < 2 * N_GRAPHS * NODE_DIM) ((float*)g_gsum)[i] = 0.f;
}

// ---------------- classifier ----------------
__global__ void hidden_kernel(const float* __restrict__ W0, const float* __restrict__ b0) {
    int g = blockIdx.x;
    int j = threadIdx.x;  // 128 x 128
    float inv_s = 1.0f / fmaxf(g_cnt[0][g], 1.0f);
    float inv_t = 1.0f / fmaxf(g_cnt[1][g], 1.0f);
    float acc = b0[j];
    for (int k = 0; k < 128; ++k) acc += g_gsum[0][g * 128 + k] * inv_s * W0[k * 128 + j];
    for (int k = 0; k < 128; ++k) acc += g_gsum[1][g * 128 + k] * inv_t * W0[(128 + k) * 128 + j];
    g_H[g * 128 + j] = fmaxf(acc, 0.f);
}

__global__ void loss_kernel(const float* __restrict__ W1, const float* __restrict__ b1,
                            const int* __restrict__ y, float* __restrict__ out) {
    int g = threadIdx.x;  // 128 threads
    float l0 = b1[0], l1 = b1[1];
    for (int j = 0; j < 128; ++j) {
        float hv = g_H[g * 128 + j];
        l0 += hv * W1[j * 2 + 0];
        l1 += hv * W1[j * 2 + 1];
    }
    float m = fmaxf(l0, l1);
    float lse = m + logf(expf(l0 - m) + expf(l1 - m));
    float ly = (y[g] == 0) ? l0 : l1;
    float c = -(ly - lse) * (1.0f / (float)N_GRAPHS);
    __shared__ float red[128];
    red[g] = c;
    __syncthreads();
    for (int s = 64; s; s >>= 1) {
        if (g < s) red[g] += red[g + s];
        __syncthreads();
    }
    if (g == 0) out[0] = red[0];
}

extern "C" void kernel_launch(void* const* d_in, const int* in_sizes, int n_in,
                              void* d_out, int out_size, void* d_ws, size_t ws_size,
                              hipStream_t stream) {
    const float* x_s      = (const float*)d_in[0];
    const float* x_t      = (const float*)d_in[1];
    const float* ea_s     = (const float*)d_in[2];
    const float* ea_t     = (const float*)d_in[3];
    const int*   ei_s     = (const int*)d_in[4];
    const int*   ei_t     = (const int*)d_in[5];
    const int*   batch_s  = (const int*)d_in[6];
    const int*   batch_t  = (const int*)d_in[7];
    const int*   y        = (const int*)d_in[8];
    const float* node_emb = (const float*)d_in[9];
    const float* edge_emb = (const float*)d_in[10];
    const float* W_in_0   = (const float*)d_in[11];
    const float* W_in_1   = (const float*)d_in[12];
    const float* W_out_0  = (const float*)d_in[13];
    const float* W_out_1  = (const float*)d_in[14];
    const float* Wg_in    = (const float*)d_in[15];
    const float* bg_in    = (const float*)d_in[16];
    const float* Wg_out   = (const float*)d_in[17];
    const float* bg_out   = (const float*)d_in[18];
    const float* cls_W0   = (const float*)d_in[19];
    const float* cls_b0   = (const float*)d_in[20];
    const float* cls_W1   = (const float*)d_in[21];
    const float* cls_b1   = (const float*)d_in[22];

    const int N = N_NODES, E = N_EDGES;

    zero_gsum_kernel<<<(2 * N_GRAPHS * NODE_DIM + 255) / 256, 256, 0, stream>>>();

    for (int side = 0; side < 2; ++side) {
        const float* xin   = side ? x_t : x_s;
        const float* eain  = side ? ea_t : ea_s;
        const int*   ei    = side ? ei_t : ei_s;
        const int*   batch = side ? batch_t : batch_s;
        const int* row = ei;
        const int* col = ei + E;

        node_embed_kernel<<<(N + 3) / 4, 256, 0, stream>>>(xin, node_emb, N);
        edge_embed_kernel<<<(2 * E + 255) / 256, 256, 0, stream>>>(eain, edge_emb, 2 * E);

        // ---- CSR build (once per side; edge_index constant across layers) ----
        csr_zero_kernel<<<(N + 255) / 256, 256, 0, stream>>>();
        csr_count_kernel<<<(E + 255) / 256, 256, 0, stream>>>(row, col, E);
        csr_bsum_kernel<<<dim3(SCAN_NBLK, 2), 256, 0, stream>>>();
        csr_bscan_kernel<<<2, 64, 0, stream>>>();
        csr_off_kernel<<<dim3(SCAN_NBLK, 2), 256, 0, stream>>>(E);
        csr_fill_kernel<<<(E + 255) / 256, 256, 0, stream>>>(row, col, E);

        int cur = 0;
        for (int k = 0; k < K_LAYERS; ++k) {
            const float* Wi0 = W_in_0 + (size_t)k * 320 * 64;
            const float* Wo0 = W_out_0 + (size_t)k * 320 * 64;
            assemble_wcat<<<256, 256, 0, stream>>>(Wi0, Wo0, Wg_in + (size_t)k * 128 * 128,
                                                   Wg_out + (size_t)k * 128 * 128);
            assemble_wmidt<<<32, 256, 0, stream>>>(Wi0, Wo0);
            gemm_xw_mfma<<<dim3((N + 63) / 64, 2), 256, 0, stream>>>(N);
            edge_update_mfma<<<dim3((E + 255) / 256, 2), 256, 0, stream>>>(
                row, col, W_in_1 + (size_t)k * 64, W_out_1 + (size_t)k * 64, E);
            aggregate_kernel<<<(N + 3) / 4, 256, 0, stream>>>(
                cur, bg_in + (size_t)k * 128, bg_out + (size_t)k * 128, N);
            cur ^= 1;
        }
        pool_kernel<<<(N + 127) / 128, 128, 0, stream>>>(cur, side, batch, N);
        count_kernel<<<1, 128, 0, stream>>>(side, batch, N);
    }

    hidden_kernel<<<128, 128, 0, stream>>>(cls_W0, cls_b0);
    loss_kernel<<<1, 128, 0, stream>>>(cls_W1, cls_b1, y, (float*)d_out);
}

// Round 7
// 1898.402 us; speedup vs baseline: 14.1784x; 1.2378x over previous
//
#include <hip/hip_runtime.h>
#include <hip/hip_bf16.h>

#define N_NODES 100000
#define N_EDGES 300000
#define N_GRAPHS 128
#define NODE_VOCAB 200
#define NODE_DIM 128
#define EDGE_DIM 64
#define K_LAYERS 3

#define SCAN_CHUNK 2048
#define SCAN_NBLK ((N_NODES + SCAN_CHUNK - 1) / SCAN_CHUNK)  // 49

typedef unsigned short ushort_t;
typedef __attribute__((ext_vector_type(8))) __bf16 bf16x8;
typedef __attribute__((ext_vector_type(4))) float f32x4;

__device__ inline ushort_t f2bf(float f) {
    unsigned int u = __float_as_uint(f);
    unsigned int r = (u + 0x7fff + ((u >> 16) & 1)) >> 16;
    return (ushort_t)r;
}
__device__ inline float bf2f(ushort_t u) {
    return __uint_as_float(((unsigned int)u) << 16);
}

// ---------------- static device scratch (no reliance on ws_size) ----------------
__device__ float g_h[2][(size_t)N_NODES * NODE_DIM];          // ping-pong node state (fp32)
__device__ ushort_t g_hb[(size_t)N_NODES * NODE_DIM];         // bf16 mirror of CURRENT state
__device__ ushort_t g_ebuf_b[(size_t)2 * N_EDGES * EDGE_DIM]; // edge state bf16 [e_in | e_out]
__device__ ushort_t g_XWe_b[(size_t)N_NODES * 256];           // bf16 [XA_in|XC_in|XA_out|XC_out]
__device__ ushort_t g_XWx_b[(size_t)N_NODES * 256];           // bf16 [xi | xo]
__device__ ushort_t g_WcatT[512 * 128];                       // Wcat^T bf16 [n][k]
__device__ ushort_t g_WmidT[2][64 * 64];                      // Wmid^T bf16 [outcol][k]
__device__ float g_wbuf[(size_t)2 * N_EDGES];
__device__ float g_gsum[2][N_GRAPHS * NODE_DIM];
__device__ float g_cnt[2][N_GRAPHS];
__device__ float g_H[N_GRAPHS * NODE_DIM];
// CSR (rebuilt per side; constant across layers)
__device__ int  g_deg_in[N_NODES];
__device__ int  g_deg_out[N_NODES];
__device__ int  g_off_in[N_NODES + 1];
__device__ int  g_off_out[N_NODES + 1];
__device__ int  g_cur_in[N_NODES];
__device__ int  g_cur_out[N_NODES];
__device__ int2 g_lst_in[N_EDGES];   // (src=row, e) keyed by col
__device__ int2 g_lst_out[N_EDGES];  // (src=col, e) keyed by row
__device__ int  g_bsum[2][SCAN_NBLK];
__device__ int  g_boff[2][SCAN_NBLK];

// ---------------- node argmax + embed (also writes bf16 mirror) ----------------
__global__ void node_embed_kernel(const float* __restrict__ x, const float* __restrict__ emb,
                                  int N) {
    int wave = threadIdx.x >> 6;
    int lane = threadIdx.x & 63;
    int n = blockIdx.x * 4 + wave;
    if (n >= N) return;
    const float* xr = x + (size_t)n * NODE_VOCAB;
    float v = xr[lane];
    int idx = lane;
    float nv = xr[lane + 64];
    if (nv > v) { v = nv; idx = lane + 64; }
    nv = xr[lane + 128];
    if (nv > v) { v = nv; idx = lane + 128; }
    if (lane < NODE_VOCAB - 192) {
        nv = xr[lane + 192];
        if (nv > v) { v = nv; idx = lane + 192; }
    }
    #pragma unroll
    for (int off = 32; off; off >>= 1) {
        float ov = __shfl_xor(v, off);
        int oi = __shfl_xor(idx, off);
        if (ov > v || (ov == v && oi < idx)) { v = ov; idx = oi; }
    }
    const float* er = emb + (size_t)idx * NODE_DIM;
    float a = er[lane], b = er[64 + lane];
    g_h[0][(size_t)n * NODE_DIM + lane] = a;
    g_h[0][(size_t)n * NODE_DIM + 64 + lane] = b;
    g_hb[(size_t)n * NODE_DIM + lane] = f2bf(a);
    g_hb[(size_t)n * NODE_DIM + 64 + lane] = f2bf(b);
}

// ---------------- edge argmax + embed (bf16 out) ----------------
__global__ void edge_embed_kernel(const float* __restrict__ ea, const float* __restrict__ emb,
                                  int M) {
    __shared__ int sidx[256];
    __shared__ float semb[8 * 64];
    int t = threadIdx.x;
    if (t < 128) {
        *(float4*)&semb[t * 4] = *(const float4*)(emb + t * 4);
    }
    long eg = (long)blockIdx.x * 256 + t;
    int best = 0;
    if (eg < M) {
        const float* ar = ea + eg * 8;
        float4 v0 = *(const float4*)ar;
        float4 v1 = *(const float4*)(ar + 4);
        float vals[8] = {v0.x, v0.y, v0.z, v0.w, v1.x, v1.y, v1.z, v1.w};
        float bv = vals[0];
        #pragma unroll
        for (int i = 1; i < 8; ++i)
            if (vals[i] > bv) { bv = vals[i]; best = i; }
    }
    sidx[t] = best;
    __syncthreads();
    long base = (long)blockIdx.x * 256 * 64;
    #pragma unroll 4
    for (int i = 0; i < 64; ++i) {
        long id = (long)i * 256 + t;
        int el = (int)(id >> 6);
        int d = (int)(id & 63);
        long eg2 = (long)blockIdx.x * 256 + el;
        if (eg2 < M) g_ebuf_b[base + id] = f2bf(semb[sidx[el] * 64 + d]);
    }
}

// ---------------- CSR build ----------------
__global__ void csr_zero_kernel() {
    int i = blockIdx.x * 256 + threadIdx.x;
    if (i < N_NODES) { g_deg_in[i] = 0; g_deg_out[i] = 0; }
}

__global__ void csr_count_kernel(const int* __restrict__ row, const int* __restrict__ col,
                                 int E) {
    int e = blockIdx.x * 256 + threadIdx.x;
    if (e >= E) return;
    atomicAdd(&g_deg_in[col[e]], 1);
    atomicAdd(&g_deg_out[row[e]], 1);
}

// phase 1: per-block sums over chunks of SCAN_CHUNK degrees. grid (SCAN_NBLK, 2) x 256
__global__ void csr_bsum_kernel() {
    int which = blockIdx.y;
    const int* deg = which ? g_deg_out : g_deg_in;
    int b = blockIdx.x;
    int t = threadIdx.x;
    int base = b * SCAN_CHUNK;
    int s = 0;
    #pragma unroll
    for (int i = 0; i < SCAN_CHUNK / 256; ++i) {
        int idx = base + i * 256 + t;
        if (idx < N_NODES) s += deg[idx];
    }
    __shared__ int red[256];
    red[t] = s;
    __syncthreads();
    for (int d = 128; d; d >>= 1) {
        if (t < d) red[t] += red[t + d];
        __syncthreads();
    }
    if (t == 0) g_bsum[which][b] = red[0];
}

// phase 2: exclusive scan of the SCAN_NBLK block sums. grid 2 x 64
__global__ void csr_bscan_kernel() {
    int which = blockIdx.x;
    int t = threadIdx.x;  // 64 threads
    int v = (t < SCAN_NBLK) ? g_bsum[which][t] : 0;
    int orig = v;
    #pragma unroll
    for (int d = 1; d < 64; d <<= 1) {
        int u = __shfl_up(v, d, 64);
        if (t >= d) v += u;
    }
    if (t < SCAN_NBLK) g_boff[which][t] = v - orig;
}

// phase 3: per-block local scan + write off/cur. grid (SCAN_NBLK, 2) x 256
__global__ void csr_off_kernel(int total) {
    int which = blockIdx.y;
    const int* deg = which ? g_deg_out : g_deg_in;
    int* off = which ? g_off_out : g_off_in;
    int* cur = which ? g_cur_out : g_cur_in;
    int b = blockIdx.x;
    int t = threadIdx.x;
    const int per = SCAN_CHUNK / 256;  // 8
    int lo = b * SCAN_CHUNK + t * per;
    int d8[per];
    int s = 0;
    #pragma unroll
    for (int i = 0; i < per; ++i) {
        int idx = lo + i;
        d8[i] = (idx < N_NODES) ? deg[idx] : 0;
        s += d8[i];
    }
    __shared__ int part[256];
    part[t] = s;
    __syncthreads();
    for (int d = 1; d < 256; d <<= 1) {
        int add = (t >= d) ? part[t - d] : 0;
        __syncthreads();
        part[t] += add;
        __syncthreads();
    }
    int run = g_boff[which][b] + part[t] - s;
    #pragma unroll
    for (int i = 0; i < per; ++i) {
        int idx = lo + i;
        if (idx < N_NODES) {
            off[idx] = run;
            cur[idx] = run;
            run += d8[i];
        }
    }
    if (b == 0 && t == 0) off[N_NODES] = total;
}

__global__ void csr_fill_kernel(const int* __restrict__ row, const int* __restrict__ col,
                                int E) {
    int e = blockIdx.x * 256 + threadIdx.x;
    if (e >= E) return;
    int r = row[e], c = col[e];
    int p = atomicAdd(&g_cur_in[c], 1);
    g_lst_in[p] = make_int2(r, e);
    int q = atomicAdd(&g_cur_out[r], 1);
    g_lst_out[q] = make_int2(c, e);
}

// ---------------- assemble Wcat^T (512 x 128, bf16) ----------------
__global__ void assemble_wcat(const float* __restrict__ Wi0, const float* __restrict__ Wo0,
                              const float* __restrict__ Wgi, const float* __restrict__ Wgo) {
    int idx = blockIdx.x * 256 + threadIdx.x;
    int kd = idx >> 9;
    int j = idx & 511;
    float v;
    if (j < 64) v = Wi0[kd * 64 + j];
    else if (j < 128) v = Wi0[(192 + kd) * 64 + (j - 64)];
    else if (j < 192) v = Wo0[kd * 64 + (j - 128)];
    else if (j < 256) v = Wo0[(192 + kd) * 64 + (j - 192)];
    else if (j < 384) v = Wgi[kd * 128 + (j - 256)];
    else v = Wgo[kd * 128 + (j - 384)];
    g_WcatT[j * 128 + kd] = f2bf(v);
}

// ---------------- assemble Wmid^T (2 x 64 x 64, bf16) ----------------
__global__ void assemble_wmidt(const float* __restrict__ Wi0, const float* __restrict__ Wo0) {
    int idx = blockIdx.x * 256 + threadIdx.x;  // 8192 total
    int b = idx >> 12;
    int rem = idx & 4095;
    int oc = rem >> 6, kk = rem & 63;
    const float* W = (b ? Wo0 : Wi0) + 128 * 64;
    g_WmidT[b][oc * 64 + kk] = f2bf(W[kk * 64 + oc]);
}

// ---------------- node GEMM via MFMA: [XWe | XWx](bf16) = x_bf16 (M x 128) @ Wcat (128 x 512) ----------------
__global__ __launch_bounds__(256) void gemm_xw_mfma(int M) {
    int m0 = blockIdx.x * 64;
    int t = threadIdx.x;
    int wave = t >> 6, lane = t & 63;
    int nbase = blockIdx.y * 256 + wave * 64;
    __shared__ ushort_t As[64 * 128];  // 16 KB, XOR-swizzled: elem k ^= (row&7)<<3

    #pragma unroll
    for (int i = 0; i < 4; ++i) {
        int idx = t + i * 256;           // 0..1023
        int m = idx >> 4, c = idx & 15;  // row, 16B-chunk (8 elems)
        int gm = m0 + m;
        uint4 v = make_uint4(0u, 0u, 0u, 0u);
        if (gm < M) v = *(const uint4*)(g_hb + (size_t)gm * 128 + c * 8);
        *(uint4*)&As[m * 128 + ((c * 8) ^ ((m & 7) << 3))] = v;
    }
    __syncthreads();

    int lr = lane & 15, lk = lane >> 4;
    f32x4 acc[4][4];
    #pragma unroll
    for (int i = 0; i < 4; ++i)
        #pragma unroll
        for (int j = 0; j < 4; ++j)
            acc[i][j] = (f32x4){0.f, 0.f, 0.f, 0.f};

    const ushort_t* Bbase = g_WcatT + (size_t)nbase * 128;
    #pragma unroll
    for (int ks = 0; ks < 4; ++ks) {
        bf16x8 a[4], b[4];
        int ke = ks * 32 + lk * 8;
        #pragma unroll
        for (int mt = 0; mt < 4; ++mt) {
            int row = mt * 16 + lr;
            a[mt] = *(const bf16x8*)&As[row * 128 + (ke ^ ((row & 7) << 3))];
        }
        #pragma unroll
        for (int nt = 0; nt < 4; ++nt) {
            b[nt] = *(const bf16x8*)(Bbase + (size_t)(nt * 16 + lr) * 128 + ke);
        }
        #pragma unroll
        for (int mt = 0; mt < 4; ++mt)
            #pragma unroll
            for (int nt = 0; nt < 4; ++nt)
                acc[mt][nt] = __builtin_amdgcn_mfma_f32_16x16x32_bf16(a[mt], b[nt], acc[mt][nt], 0, 0, 0);
    }

    #pragma unroll
    for (int mt = 0; mt < 4; ++mt) {
        #pragma unroll
        for (int r = 0; r < 4; ++r) {
            int gm = m0 + mt * 16 + lk * 4 + r;
            if (gm >= M) continue;
            #pragma unroll
            for (int nt = 0; nt < 4; ++nt) {
                int n = nbase + nt * 16 + lr;
                ushort_t* dst = (n < 256) ? (g_XWe_b + (size_t)gm * 256 + n)
                                          : (g_XWx_b + (size_t)gm * 256 + (n - 256));
                *dst = f2bf(acc[mt][nt][r]);
            }
        }
    }
}

// ------- edge update via swapped MFMA (no LDS, no barriers) + fused gate -------
__global__ __launch_bounds__(256) void edge_update_mfma(const int* __restrict__ row,
                                                        const int* __restrict__ col,
                                                        const float* __restrict__ W1_in,
                                                        const float* __restrict__ W1_out,
                                                        int E) {
    int b = blockIdx.y;
    int t = threadIdx.x;
    int wave = t >> 6, lane = t & 63;
    int lr = lane & 15, lk = lane >> 4;
    int e0 = blockIdx.x * 256 + wave * 64;
    const float* W1 = b ? W1_out : W1_in;
    const ushort_t* WT = g_WmidT[b];
    ushort_t* ebuf = g_ebuf_b + (size_t)b * E * 64;

    bf16x8 wf[4][2];
    #pragma unroll
    for (int mt = 0; mt < 4; ++mt)
        #pragma unroll
        for (int ks = 0; ks < 2; ++ks)
            wf[mt][ks] = *(const bf16x8*)&WT[(mt * 16 + lr) * 64 + ks * 32 + lk * 8];

    bf16x8 zero8;
    #pragma unroll
    for (int q = 0; q < 8; ++q) zero8[q] = (__bf16)0.0f;

    #pragma unroll
    for (int half = 0; half < 2; ++half) {
        bf16x8 ef[2][2];
        #pragma unroll
        for (int j = 0; j < 2; ++j) {
            int eg = e0 + (half * 2 + j) * 16 + lr;
            if (eg < E) {
                const ushort_t* er = ebuf + (size_t)eg * 64 + lk * 8;
                ef[j][0] = *(const bf16x8*)er;
                ef[j][1] = *(const bf16x8*)(er + 32);
            } else {
                ef[j][0] = zero8;
                ef[j][1] = zero8;
            }
        }
        f32x4 acc[4][2];
        #pragma unroll
        for (int mt = 0; mt < 4; ++mt)
            #pragma unroll
            for (int j = 0; j < 2; ++j)
                acc[mt][j] = (f32x4){0.f, 0.f, 0.f, 0.f};
        #pragma unroll
        for (int ks = 0; ks < 2; ++ks)
            #pragma unroll
            for (int mt = 0; mt < 4; ++mt)
                #pragma unroll
                for (int j = 0; j < 2; ++j)
                    acc[mt][j] = __builtin_amdgcn_mfma_f32_16x16x32_bf16(wf[mt][ks], ef[j][ks], acc[mt][j], 0, 0, 0);

        #pragma unroll
        for (int j = 0; j < 2; ++j) {
            int eg = e0 + (half * 2 + j) * 16 + lr;
            if (eg < E) {
                int r = row[eg], c = col[eg];
                int ga = b ? c : r;
                int gc = b ? r : c;
                const ushort_t* x1p = g_XWe_b + (size_t)ga * 256 + (b ? 128 : 0);
                const ushort_t* x2p = g_XWe_b + (size_t)gc * 256 + (b ? 192 : 64);
                float p = 0.f;
                #pragma unroll
                for (int mt = 0; mt < 4; ++mt) {
                    int j0 = mt * 16 + lk * 4;
                    uint2 u1 = *(const uint2*)(x1p + j0);
                    uint2 u2 = *(const uint2*)(x2p + j0);
                    f32x4 av = acc[mt][j];
                    float ox = av[0] + bf2f((ushort_t)(u1.x & 0xffff)) + bf2f((ushort_t)(u2.x & 0xffff));
                    float oy = av[1] + bf2f((ushort_t)(u1.x >> 16)) + bf2f((ushort_t)(u2.x >> 16));
                    float oz = av[2] + bf2f((ushort_t)(u1.y & 0xffff)) + bf2f((ushort_t)(u2.y & 0xffff));
                    float ow = av[3] + bf2f((ushort_t)(u1.y >> 16)) + bf2f((ushort_t)(u2.y >> 16));
                    uint2 pk;
                    pk.x = ((unsigned int)f2bf(oy) << 16) | (unsigned int)f2bf(ox);
                    pk.y = ((unsigned int)f2bf(ow) << 16) | (unsigned int)f2bf(oz);
                    *(uint2*)&ebuf[(size_t)eg * 64 + j0] = pk;
                    float4 wv = *(const float4*)(W1 + j0);
                    p += ox * wv.x + oy * wv.y + oz * wv.z + ow * wv.w;
                }
                p += __shfl_xor(p, 16);
                p += __shfl_xor(p, 32);
                if (lk == 0) g_wbuf[(size_t)b * E + eg] = 1.0f / (1.0f + expf(-p));
            }
        }
    }
}

// ---------------- fused aggregate: x_next = x + bgi + bgo + CSR-gathered in/out sums ----------------
__global__ __launch_bounds__(256) void aggregate_kernel(int cur, const float* __restrict__ bgi,
                                                        const float* __restrict__ bgo, int N) {
    int wave = threadIdx.x >> 6;
    int lane = threadIdx.x & 63;
    int n = blockIdx.x * 4 + wave;
    if (n >= N) return;
    float2 acc = ((const float2*)(g_h[cur] + (size_t)n * 128))[lane];
    float2 bi = ((const float2*)bgi)[lane];
    float2 bo = ((const float2*)bgo)[lane];
    acc.x += bi.x + bo.x;
    acc.y += bi.y + bo.y;
    int p0 = g_off_in[n], p1 = g_off_in[n + 1];
    for (int p = p0; p < p1; ++p) {
        int2 se = g_lst_in[p];
        float wv = g_wbuf[se.y];
        unsigned int pv = *(const unsigned int*)(g_XWx_b + (size_t)se.x * 256 + lane * 2);
        acc.x += wv * bf2f((ushort_t)(pv & 0xffff));
        acc.y += wv * bf2f((ushort_t)(pv >> 16));
    }
    p0 = g_off_out[n]; p1 = g_off_out[n + 1];
    for (int p = p0; p < p1; ++p) {
        int2 se = g_lst_out[p];
        float wv = g_wbuf[(size_t)N_EDGES + se.y];
        unsigned int pv = *(const unsigned int*)(g_XWx_b + (size_t)se.x * 256 + 128 + lane * 2);
        acc.x += wv * bf2f((ushort_t)(pv & 0xffff));
        acc.y += wv * bf2f((ushort_t)(pv >> 16));
    }
    ((float2*)(g_h[cur ^ 1] + (size_t)n * 128))[lane] = acc;
    unsigned int pk = ((unsigned int)f2bf(acc.y) << 16) | (unsigned int)f2bf(acc.x);
    ((unsigned int*)g_hb)[(size_t)n * 64 + lane] = pk;
}

// ---------------- mean-pool partials ----------------
__global__ void pool_kernel(int fin, int side, const int* __restrict__ batch, int N) {
    const float* x = g_h[fin];
    float* gsum = g_gsum[side];
    int n0 = blockIdx.x * 128;
    int d = threadIdx.x;  // 128 threads
    if (n0 >= N) return;
    int nend = min(n0 + 128, N);
    float acc = 0.f;
    int curg = batch[n0];
    for (int n = n0; n < nend; ++n) {
        int g = batch[n];
        if (g != curg) {
            atomicAdd(&gsum[curg * 128 + d], acc);
            acc = 0.f;
            curg = g;
        }
        acc += x[(size_t)n * 128 + d];
    }
    atomicAdd(&gsum[curg * 128 + d], acc);
}

__global__ void count_kernel(int side, const int* __restrict__ batch, int N) {
    int g = threadIdx.x;  // 128 threads
    int lo = 0, hi = N;
    while (lo < hi) { int mid = (lo + hi) >> 1; if (batch[mid] < g) lo = mid + 1; else hi = mid; }
    int a = lo;
    lo = 0; hi = N;
    while (lo < hi) { int mid = (lo + hi) >> 1; if (batch[mid] < g + 1) lo = mid + 1; else hi = mid; }
    g_cnt[side][g] = (float)(lo - a);
}

__global__ void zero_gsum_kernel() {
    int i = blockIdx.x * 256 + threadIdx.x;
    if (i < 2 * N_GRAPHS * NODE_DIM) ((float*)g_gsum)[i] = 0.f;
}

// ---------------- classifier ----------------
__global__ void hidden_kernel(const float* __restrict__ W0, const float* __restrict__ b0) {
    int g = blockIdx.x;
    int j = threadIdx.x;  // 128 x 128
    float inv_s = 1.0f / fmaxf(g_cnt[0][g], 1.0f);
    float inv_t = 1.0f / fmaxf(g_cnt[1][g], 1.0f);
    float acc = b0[j];
    for (int k = 0; k < 128; ++k) acc += g_gsum[0][g * 128 + k] * inv_s * W0[k * 128 + j];
    for (int k = 0; k < 128; ++k) acc += g_gsum[1][g * 128 + k] * inv_t * W0[(128 + k) * 128 + j];
    g_H[g * 128 + j] = fmaxf(acc, 0.f);
}

__global__ void loss_kernel(const float* __restrict__ W1, const float* __restrict__ b1,
                            const int* __restrict__ y, float* __restrict__ out) {
    int g = threadIdx.x;  // 128 threads
    float l0 = b1[0], l1 = b1[1];
    for (int j = 0; j < 128; ++j) {
        float hv = g_H[g * 128 + j];
        l0 += hv * W1[j * 2 + 0];
        l1 += hv * W1[j * 2 + 1];
    }
    float m = fmaxf(l0, l1);
    float lse = m + logf(expf(l0 - m) + expf(l1 - m));
    float ly = (y[g] == 0) ? l0 : l1;
    float c = -(ly - lse) * (1.0f / (float)N_GRAPHS);
    __shared__ float red[128];
    red[g] = c;
    __syncthreads();
    for (int s = 64; s; s >>= 1) {
        if (g < s) red[g] += red[g + s];
        __syncthreads();
    }
    if (g == 0) out[0] = red[0];
}

extern "C" void kernel_launch(void* const* d_in, const int* in_sizes, int n_in,
                              void* d_out, int out_size, void* d_ws, size_t ws_size,
                              hipStream_t stream) {
    const float* x_s      = (const float*)d_in[0];
    const float* x_t      = (const float*)d_in[1];
    const float* ea_s     = (const float*)d_in[2];
    const float* ea_t     = (const float*)d_in[3];
    const int*   ei_s     = (const int*)d_in[4];
    const int*   ei_t     = (const int*)d_in[5];
    const int*   batch_s  = (const int*)d_in[6];
    const int*   batch_t  = (const int*)d_in[7];
    const int*   y        = (const int*)d_in[8];
    const float* node_emb = (const float*)d_in[9];
    const float* edge_emb = (const float*)d_in[10];
    const float* W_in_0   = (const float*)d_in[11];
    const float* W_in_1   = (const float*)d_in[12];
    const float* W_out_0  = (const float*)d_in[13];
    const float* W_out_1  = (const float*)d_in[14];
    const float* Wg_in    = (const float*)d_in[15];
    const float* bg_in    = (const float*)d_in[16];
    const float* Wg_out   = (const float*)d_in[17];
    const float* bg_out   = (const float*)d_in[18];
    const float* cls_W0   = (const float*)d_in[19];
    const float* cls_b0   = (const float*)d_in[20];
    const float* cls_W1   = (const float*)d_in[21];
    const float* cls_b1   = (const float*)d_in[22];

    const int N = N_NODES, E = N_EDGES;

    zero_gsum_kernel<<<(2 * N_GRAPHS * NODE_DIM + 255) / 256, 256, 0, stream>>>();

    for (int side = 0; side < 2; ++side) {
        const float* xin   = side ? x_t : x_s;
        const float* eain  = side ? ea_t : ea_s;
        const int*   ei    = side ? ei_t : ei_s;
        const int*   batch = side ? batch_t : batch_s;
        const int* row = ei;
        const int* col = ei + E;

        node_embed_kernel<<<(N + 3) / 4, 256, 0, stream>>>(xin, node_emb, N);
        edge_embed_kernel<<<(2 * E + 255) / 256, 256, 0, stream>>>(eain, edge_emb, 2 * E);

        // ---- CSR build (once per side; edge_index constant across layers) ----
        csr_zero_kernel<<<(N + 255) / 256, 256, 0, stream>>>();
        csr_count_kernel<<<(E + 255) / 256, 256, 0, stream>>>(row, col, E);
        csr_bsum_kernel<<<dim3(SCAN_NBLK, 2), 256, 0, stream>>>();
        csr_bscan_kernel<<<2, 64, 0, stream>>>();
        csr_off_kernel<<<dim3(SCAN_NBLK, 2), 256, 0, stream>>>(E);
        csr_fill_kernel<<<(E + 255) / 256, 256, 0, stream>>>(row, col, E);

        int cur = 0;
        for (int k = 0; k < K_LAYERS; ++k) {
            const float* Wi0 = W_in_0 + (size_t)k * 320 * 64;
            const float* Wo0 = W_out_0 + (size_t)k * 320 * 64;
            assemble_wcat<<<256, 256, 0, stream>>>(Wi0, Wo0, Wg_in + (size_t)k * 128 * 128,
                                                   Wg_out + (size_t)k * 128 * 128);
            assemble_wmidt<<<32, 256, 0, stream>>>(Wi0, Wo0);
            gemm_xw_mfma<<<dim3((N + 63) / 64, 2), 256, 0, stream>>>(N);
            edge_update_mfma<<<dim3((E + 255) / 256, 2), 256, 0, stream>>>(
                row, col, W_in_1 + (size_t)k * 64, W_out_1 + (size_t)k * 64, E);
            aggregate_kernel<<<(N + 3) / 4, 256, 0, stream>>>(
                cur, bg_in + (size_t)k * 128, bg_out + (size_t)k * 128, N);
            cur ^= 1;
        }
        pool_kernel<<<(N + 127) / 128, 128, 0, stream>>>(cur, side, batch, N);
        count_kernel<<<1, 128, 0, stream>>>(side, batch, N);
    }

    hidden_kernel<<<128, 128, 0, stream>>>(cls_W0, cls_b0);
    loss_kernel<<<1, 128, 0, stream>>>(cls_W1, cls_b1, y, (float*)d_out);
}

// Round 8
// 1682.030 us; speedup vs baseline: 16.0023x; 1.1286x over previous
//
#include <hip/hip_runtime.h>
#include <hip/hip_bf16.h>

#define N_NODES 100000
#define N_EDGES 300000
#define N_GRAPHS 128
#define NODE_VOCAB 200
#define NODE_DIM 128
#define EDGE_DIM 64
#define K_LAYERS 3

#define SCAN_CHUNK 2048
#define SCAN_NBLK ((N_NODES + SCAN_CHUNK - 1) / SCAN_CHUNK)  // 49

typedef unsigned short ushort_t;
typedef __attribute__((ext_vector_type(8))) __bf16 bf16x8;
typedef __attribute__((ext_vector_type(4))) float f32x4;

__device__ inline ushort_t f2bf(float f) {
    unsigned int u = __float_as_uint(f);
    unsigned int r = (u + 0x7fff + ((u >> 16) & 1)) >> 16;
    return (ushort_t)r;
}
__device__ inline float bf2f(ushort_t u) {
    return __uint_as_float(((unsigned int)u) << 16);
}

// ---------------- static device scratch (no reliance on ws_size) ----------------
__device__ ushort_t g_hb[2][(size_t)N_NODES * NODE_DIM];      // bf16 ping-pong node state
__device__ ushort_t g_ebuf_b[(size_t)2 * N_EDGES * EDGE_DIM]; // edge state bf16 [e_in | e_out]
__device__ ushort_t g_XWe_b[(size_t)N_NODES * 256];           // bf16 [XA_in|XC_in|XA_out|XC_out]
__device__ ushort_t g_XWx_b[(size_t)N_NODES * 256];           // bf16 [xi | xo]
__device__ ushort_t g_WcatT[512 * 128];                       // Wcat^T bf16 [n][k]
__device__ ushort_t g_WmidT[2][64 * 64];                      // Wmid^T bf16 [outcol][k]
__device__ float g_wbuf[(size_t)2 * N_EDGES];
__device__ float g_gsum[2][N_GRAPHS * NODE_DIM];
__device__ float g_cnt[2][N_GRAPHS];
__device__ float g_H[N_GRAPHS * NODE_DIM];
// CSR (rebuilt per side; constant across layers)
__device__ int  g_deg_in[N_NODES];
__device__ int  g_deg_out[N_NODES];
__device__ int  g_off_in[N_NODES + 1];
__device__ int  g_off_out[N_NODES + 1];
__device__ int  g_cur_in[N_NODES];
__device__ int  g_cur_out[N_NODES];
__device__ int2 g_lst_in[N_EDGES];   // (src=row, e) keyed by col
__device__ int2 g_lst_out[N_EDGES];  // (src=col, e) keyed by row
__device__ int  g_bsum[2][SCAN_NBLK];
__device__ int  g_boff[2][SCAN_NBLK];

// ---------------- node argmax + embed (bf16 state out) ----------------
__global__ void node_embed_kernel(const float* __restrict__ x, const float* __restrict__ emb,
                                  int N) {
    int wave = threadIdx.x >> 6;
    int lane = threadIdx.x & 63;
    int n = blockIdx.x * 4 + wave;
    if (n >= N) return;
    const float* xr = x + (size_t)n * NODE_VOCAB;
    float v = xr[lane];
    int idx = lane;
    float nv = xr[lane + 64];
    if (nv > v) { v = nv; idx = lane + 64; }
    nv = xr[lane + 128];
    if (nv > v) { v = nv; idx = lane + 128; }
    if (lane < NODE_VOCAB - 192) {
        nv = xr[lane + 192];
        if (nv > v) { v = nv; idx = lane + 192; }
    }
    #pragma unroll
    for (int off = 32; off; off >>= 1) {
        float ov = __shfl_xor(v, off);
        int oi = __shfl_xor(idx, off);
        if (ov > v || (ov == v && oi < idx)) { v = ov; idx = oi; }
    }
    const float* er = emb + (size_t)idx * NODE_DIM;
    g_hb[0][(size_t)n * NODE_DIM + lane] = f2bf(er[lane]);
    g_hb[0][(size_t)n * NODE_DIM + 64 + lane] = f2bf(er[64 + lane]);
}

// ---------------- edge argmax + embed (bf16 out) ----------------
__global__ void edge_embed_kernel(const float* __restrict__ ea, const float* __restrict__ emb,
                                  int M) {
    __shared__ int sidx[256];
    __shared__ float semb[8 * 64];
    int t = threadIdx.x;
    if (t < 128) {
        *(float4*)&semb[t * 4] = *(const float4*)(emb + t * 4);
    }
    long eg = (long)blockIdx.x * 256 + t;
    int best = 0;
    if (eg < M) {
        const float* ar = ea + eg * 8;
        float4 v0 = *(const float4*)ar;
        float4 v1 = *(const float4*)(ar + 4);
        float vals[8] = {v0.x, v0.y, v0.z, v0.w, v1.x, v1.y, v1.z, v1.w};
        float bv = vals[0];
        #pragma unroll
        for (int i = 1; i < 8; ++i)
            if (vals[i] > bv) { bv = vals[i]; best = i; }
    }
    sidx[t] = best;
    __syncthreads();
    long base = (long)blockIdx.x * 256 * 64;
    #pragma unroll 4
    for (int i = 0; i < 64; ++i) {
        long id = (long)i * 256 + t;
        int el = (int)(id >> 6);
        int d = (int)(id & 63);
        long eg2 = (long)blockIdx.x * 256 + el;
        if (eg2 < M) g_ebuf_b[base + id] = f2bf(semb[sidx[el] * 64 + d]);
    }
}

// ---------------- CSR build ----------------
__global__ void csr_zero_kernel() {
    int i = blockIdx.x * 256 + threadIdx.x;
    if (i < N_NODES) { g_deg_in[i] = 0; g_deg_out[i] = 0; }
}

__global__ void csr_count_kernel(const int* __restrict__ row, const int* __restrict__ col,
                                 int E) {
    int e = blockIdx.x * 256 + threadIdx.x;
    if (e >= E) return;
    atomicAdd(&g_deg_in[col[e]], 1);
    atomicAdd(&g_deg_out[row[e]], 1);
}

// phase 1: per-block sums over chunks of SCAN_CHUNK degrees. grid (SCAN_NBLK, 2) x 256
__global__ void csr_bsum_kernel() {
    int which = blockIdx.y;
    const int* deg = which ? g_deg_out : g_deg_in;
    int b = blockIdx.x;
    int t = threadIdx.x;
    int base = b * SCAN_CHUNK;
    int s = 0;
    #pragma unroll
    for (int i = 0; i < SCAN_CHUNK / 256; ++i) {
        int idx = base + i * 256 + t;
        if (idx < N_NODES) s += deg[idx];
    }
    __shared__ int red[256];
    red[t] = s;
    __syncthreads();
    for (int d = 128; d; d >>= 1) {
        if (t < d) red[t] += red[t + d];
        __syncthreads();
    }
    if (t == 0) g_bsum[which][b] = red[0];
}

// phase 2: exclusive scan of the SCAN_NBLK block sums. grid 2 x 64
__global__ void csr_bscan_kernel() {
    int which = blockIdx.x;
    int t = threadIdx.x;  // 64 threads
    int v = (t < SCAN_NBLK) ? g_bsum[which][t] : 0;
    int orig = v;
    #pragma unroll
    for (int d = 1; d < 64; d <<= 1) {
        int u = __shfl_up(v, d, 64);
        if (t >= d) v += u;
    }
    if (t < SCAN_NBLK) g_boff[which][t] = v - orig;
}

// phase 3: per-block local scan + write off/cur. grid (SCAN_NBLK, 2) x 256
__global__ void csr_off_kernel(int total) {
    int which = blockIdx.y;
    const int* deg = which ? g_deg_out : g_deg_in;
    int* off = which ? g_off_out : g_off_in;
    int* cur = which ? g_cur_out : g_cur_in;
    int b = blockIdx.x;
    int t = threadIdx.x;
    const int per = SCAN_CHUNK / 256;  // 8
    int lo = b * SCAN_CHUNK + t * per;
    int d8[per];
    int s = 0;
    #pragma unroll
    for (int i = 0; i < per; ++i) {
        int idx = lo + i;
        d8[i] = (idx < N_NODES) ? deg[idx] : 0;
        s += d8[i];
    }
    __shared__ int part[256];
    part[t] = s;
    __syncthreads();
    for (int d = 1; d < 256; d <<= 1) {
        int add = (t >= d) ? part[t - d] : 0;
        __syncthreads();
        part[t] += add;
        __syncthreads();
    }
    int run = g_boff[which][b] + part[t] - s;
    #pragma unroll
    for (int i = 0; i < per; ++i) {
        int idx = lo + i;
        if (idx < N_NODES) {
            off[idx] = run;
            cur[idx] = run;
            run += d8[i];
        }
    }
    if (b == 0 && t == 0) off[N_NODES] = total;
}

__global__ void csr_fill_kernel(const int* __restrict__ row, const int* __restrict__ col,
                                int E) {
    int e = blockIdx.x * 256 + threadIdx.x;
    if (e >= E) return;
    int r = row[e], c = col[e];
    int p = atomicAdd(&g_cur_in[c], 1);
    g_lst_in[p] = make_int2(r, e);
    int q = atomicAdd(&g_cur_out[r], 1);
    g_lst_out[q] = make_int2(c, e);
}

// ---------------- assemble Wcat^T (512 x 128, bf16) ----------------
__global__ void assemble_wcat(const float* __restrict__ Wi0, const float* __restrict__ Wo0,
                              const float* __restrict__ Wgi, const float* __restrict__ Wgo) {
    int idx = blockIdx.x * 256 + threadIdx.x;
    int kd = idx >> 9;
    int j = idx & 511;
    float v;
    if (j < 64) v = Wi0[kd * 64 + j];
    else if (j < 128) v = Wi0[(192 + kd) * 64 + (j - 64)];
    else if (j < 192) v = Wo0[kd * 64 + (j - 128)];
    else if (j < 256) v = Wo0[(192 + kd) * 64 + (j - 192)];
    else if (j < 384) v = Wgi[kd * 128 + (j - 256)];
    else v = Wgo[kd * 128 + (j - 384)];
    g_WcatT[j * 128 + kd] = f2bf(v);
}

// ---------------- assemble Wmid^T (2 x 64 x 64, bf16) ----------------
__global__ void assemble_wmidt(const float* __restrict__ Wi0, const float* __restrict__ Wo0) {
    int idx = blockIdx.x * 256 + threadIdx.x;  // 8192 total
    int b = idx >> 12;
    int rem = idx & 4095;
    int oc = rem >> 6, kk = rem & 63;
    const float* W = (b ? Wo0 : Wi0) + 128 * 64;
    g_WmidT[b][oc * 64 + kk] = f2bf(W[kk * 64 + oc]);
}

// ---------------- node GEMM via MFMA: [XWe | XWx](bf16) = x_bf16 (M x 128) @ Wcat (128 x 512) ----------------
__global__ __launch_bounds__(256) void gemm_xw_mfma(int cur, int M) {
    const ushort_t* __restrict__ hb = g_hb[cur];
    int m0 = blockIdx.x * 64;
    int t = threadIdx.x;
    int wave = t >> 6, lane = t & 63;
    int nbase = blockIdx.y * 256 + wave * 64;
    __shared__ ushort_t As[64 * 128];  // 16 KB, XOR-swizzled: elem k ^= (row&7)<<3

    #pragma unroll
    for (int i = 0; i < 4; ++i) {
        int idx = t + i * 256;           // 0..1023
        int m = idx >> 4, c = idx & 15;  // row, 16B-chunk (8 elems)
        int gm = m0 + m;
        uint4 v = make_uint4(0u, 0u, 0u, 0u);
        if (gm < M) v = *(const uint4*)(hb + (size_t)gm * 128 + c * 8);
        *(uint4*)&As[m * 128 + ((c * 8) ^ ((m & 7) << 3))] = v;
    }
    __syncthreads();

    int lr = lane & 15, lk = lane >> 4;
    f32x4 acc[4][4];
    #pragma unroll
    for (int i = 0; i < 4; ++i)
        #pragma unroll
        for (int j = 0; j < 4; ++j)
            acc[i][j] = (f32x4){0.f, 0.f, 0.f, 0.f};

    const ushort_t* Bbase = g_WcatT + (size_t)nbase * 128;
    #pragma unroll
    for (int ks = 0; ks < 4; ++ks) {
        bf16x8 a[4], b[4];
        int ke = ks * 32 + lk * 8;
        #pragma unroll
        for (int mt = 0; mt < 4; ++mt) {
            int row = mt * 16 + lr;
            a[mt] = *(const bf16x8*)&As[row * 128 + (ke ^ ((row & 7) << 3))];
        }
        #pragma unroll
        for (int nt = 0; nt < 4; ++nt) {
            b[nt] = *(const bf16x8*)(Bbase + (size_t)(nt * 16 + lr) * 128 + ke);
        }
        #pragma unroll
        for (int mt = 0; mt < 4; ++mt)
            #pragma unroll
            for (int nt = 0; nt < 4; ++nt)
                acc[mt][nt] = __builtin_amdgcn_mfma_f32_16x16x32_bf16(a[mt], b[nt], acc[mt][nt], 0, 0, 0);
    }

    #pragma unroll
    for (int mt = 0; mt < 4; ++mt) {
        #pragma unroll
        for (int r = 0; r < 4; ++r) {
            int gm = m0 + mt * 16 + lk * 4 + r;
            if (gm >= M) continue;
            #pragma unroll
            for (int nt = 0; nt < 4; ++nt) {
                int n = nbase + nt * 16 + lr;
                ushort_t* dst = (n < 256) ? (g_XWe_b + (size_t)gm * 256 + n)
                                          : (g_XWx_b + (size_t)gm * 256 + (n - 256));
                *dst = f2bf(acc[mt][nt][r]);
            }
        }
    }
}

// ------- edge update via swapped MFMA (no LDS, no barriers) + fused gate -------
// store_e==0 on the last layer: the updated e is dead (only w is needed).
__global__ __launch_bounds__(256) void edge_update_mfma(const int* __restrict__ row,
                                                        const int* __restrict__ col,
                                                        const float* __restrict__ W1_in,
                                                        const float* __restrict__ W1_out,
                                                        int store_e, int E) {
    int b = blockIdx.y;
    int t = threadIdx.x;
    int wave = t >> 6, lane = t & 63;
    int lr = lane & 15, lk = lane >> 4;
    int e0 = blockIdx.x * 256 + wave * 64;
    const float* W1 = b ? W1_out : W1_in;
    const ushort_t* WT = g_WmidT[b];
    ushort_t* ebuf = g_ebuf_b + (size_t)b * E * 64;

    bf16x8 wf[4][2];
    #pragma unroll
    for (int mt = 0; mt < 4; ++mt)
        #pragma unroll
        for (int ks = 0; ks < 2; ++ks)
            wf[mt][ks] = *(const bf16x8*)&WT[(mt * 16 + lr) * 64 + ks * 32 + lk * 8];

    bf16x8 zero8;
    #pragma unroll
    for (int q = 0; q < 8; ++q) zero8[q] = (__bf16)0.0f;

    #pragma unroll
    for (int half = 0; half < 2; ++half) {
        bf16x8 ef[2][2];
        #pragma unroll
        for (int j = 0; j < 2; ++j) {
            int eg = e0 + (half * 2 + j) * 16 + lr;
            if (eg < E) {
                const ushort_t* er = ebuf + (size_t)eg * 64 + lk * 8;
                ef[j][0] = *(const bf16x8*)er;
                ef[j][1] = *(const bf16x8*)(er + 32);
            } else {
                ef[j][0] = zero8;
                ef[j][1] = zero8;
            }
        }
        f32x4 acc[4][2];
        #pragma unroll
        for (int mt = 0; mt < 4; ++mt)
            #pragma unroll
            for (int j = 0; j < 2; ++j)
                acc[mt][j] = (f32x4){0.f, 0.f, 0.f, 0.f};
        #pragma unroll
        for (int ks = 0; ks < 2; ++ks)
            #pragma unroll
            for (int mt = 0; mt < 4; ++mt)
                #pragma unroll
                for (int j = 0; j < 2; ++j)
                    acc[mt][j] = __builtin_amdgcn_mfma_f32_16x16x32_bf16(wf[mt][ks], ef[j][ks], acc[mt][j], 0, 0, 0);

        #pragma unroll
        for (int j = 0; j < 2; ++j) {
            int eg = e0 + (half * 2 + j) * 16 + lr;
            if (eg < E) {
                int r = row[eg], c = col[eg];
                int ga = b ? c : r;
                int gc = b ? r : c;
                const ushort_t* x1p = g_XWe_b + (size_t)ga * 256 + (b ? 128 : 0);
                const ushort_t* x2p = g_XWe_b + (size_t)gc * 256 + (b ? 192 : 64);
                float p = 0.f;
                #pragma unroll
                for (int mt = 0; mt < 4; ++mt) {
                    int j0 = mt * 16 + lk * 4;
                    uint2 u1 = *(const uint2*)(x1p + j0);
                    uint2 u2 = *(const uint2*)(x2p + j0);
                    f32x4 av = acc[mt][j];
                    float ox = av[0] + bf2f((ushort_t)(u1.x & 0xffff)) + bf2f((ushort_t)(u2.x & 0xffff));
                    float oy = av[1] + bf2f((ushort_t)(u1.x >> 16)) + bf2f((ushort_t)(u2.x >> 16));
                    float oz = av[2] + bf2f((ushort_t)(u1.y & 0xffff)) + bf2f((ushort_t)(u2.y & 0xffff));
                    float ow = av[3] + bf2f((ushort_t)(u1.y >> 16)) + bf2f((ushort_t)(u2.y >> 16));
                    if (store_e) {
                        uint2 pk;
                        pk.x = ((unsigned int)f2bf(oy) << 16) | (unsigned int)f2bf(ox);
                        pk.y = ((unsigned int)f2bf(ow) << 16) | (unsigned int)f2bf(oz);
                        *(uint2*)&ebuf[(size_t)eg * 64 + j0] = pk;
                    }
                    float4 wv = *(const float4*)(W1 + j0);
                    p += ox * wv.x + oy * wv.y + oz * wv.z + ow * wv.w;
                }
                p += __shfl_xor(p, 16);
                p += __shfl_xor(p, 32);
                if (lk == 0) g_wbuf[(size_t)b * E + eg] = 1.0f / (1.0f + expf(-p));
            }
        }
    }
}

// ---------------- fused aggregate: x_next(bf16) = x + bgi + bgo + CSR-gathered in/out sums ----------------
__global__ __launch_bounds__(256) void aggregate_kernel(int cur, const float* __restrict__ bgi,
                                                        const float* __restrict__ bgo, int N) {
    int wave = threadIdx.x >> 6;
    int lane = threadIdx.x & 63;
    int n = blockIdx.x * 4 + wave;
    if (n >= N) return;
    unsigned int xv = *(const unsigned int*)(g_hb[cur] + (size_t)n * 128 + lane * 2);
    float2 bi = ((const float2*)bgi)[lane];
    float2 bo = ((const float2*)bgo)[lane];
    float2 acc;
    acc.x = bf2f((ushort_t)(xv & 0xffff)) + bi.x + bo.x;
    acc.y = bf2f((ushort_t)(xv >> 16)) + bi.y + bo.y;
    int p0 = g_off_in[n], p1 = g_off_in[n + 1];
    for (int p = p0; p < p1; ++p) {
        int2 se = g_lst_in[p];
        float wv = g_wbuf[se.y];
        unsigned int pv = *(const unsigned int*)(g_XWx_b + (size_t)se.x * 256 + lane * 2);
        acc.x += wv * bf2f((ushort_t)(pv & 0xffff));
        acc.y += wv * bf2f((ushort_t)(pv >> 16));
    }
    p0 = g_off_out[n]; p1 = g_off_out[n + 1];
    for (int p = p0; p < p1; ++p) {
        int2 se = g_lst_out[p];
        float wv = g_wbuf[(size_t)N_EDGES + se.y];
        unsigned int pv = *(const unsigned int*)(g_XWx_b + (size_t)se.x * 256 + 128 + lane * 2);
        acc.x += wv * bf2f((ushort_t)(pv & 0xffff));
        acc.y += wv * bf2f((ushort_t)(pv >> 16));
    }
    unsigned int pk = ((unsigned int)f2bf(acc.y) << 16) | (unsigned int)f2bf(acc.x);
    *(unsigned int*)(g_hb[cur ^ 1] + (size_t)n * 128 + lane * 2) = pk;
}

// ---------------- mean-pool partials (bf16 in, fp32 accumulate) ----------------
__global__ void pool_kernel(int fin, int side, const int* __restrict__ batch, int N) {
    const ushort_t* x = g_hb[fin];
    float* gsum = g_gsum[side];
    int n0 = blockIdx.x * 128;
    int d = threadIdx.x;  // 128 threads
    if (n0 >= N) return;
    int nend = min(n0 + 128, N);
    float acc = 0.f;
    int curg = batch[n0];
    for (int n = n0; n < nend; ++n) {
        int g = batch[n];
        if (g != curg) {
            atomicAdd(&gsum[curg * 128 + d], acc);
            acc = 0.f;
            curg = g;
        }
        acc += bf2f(x[(size_t)n * 128 + d]);
    }
    atomicAdd(&gsum[curg * 128 + d], acc);
}

__global__ void count_kernel(int side, const int* __restrict__ batch, int N) {
    int g = threadIdx.x;  // 128 threads
    int lo = 0, hi = N;
    while (lo < hi) { int mid = (lo + hi) >> 1; if (batch[mid] < g) lo = mid + 1; else hi = mid; }
    int a = lo;
    lo = 0; hi = N;
    while (lo < hi) { int mid = (lo + hi) >> 1; if (batch[mid] < g + 1) lo = mid + 1; else hi = mid; }
    g_cnt[side][g] = (float)(lo - a);
}

__global__ void zero_gsum_kernel() {
    int i = blockIdx.x * 256 + threadIdx.x;
    if (i < 2 * N_GRAPHS * NODE_DIM) ((float*)g_gsum)[i] = 0.f;
}

// ---------------- classifier ----------------
__global__ void hidden_kernel(const float* __restrict__ W0, const float* __restrict__ b0) {
    int g = blockIdx.x;
    int j = threadIdx.x;  // 128 x 128
    float inv_s = 1.0f / fmaxf(g_cnt[0][g], 1.0f);
    float inv_t = 1.0f / fmaxf(g_cnt[1][g], 1.0f);
    float acc = b0[j];
    for (int k = 0; k < 128; ++k) acc += g_gsum[0][g * 128 + k] * inv_s * W0[k * 128 + j];
    for (int k = 0; k < 128; ++k) acc += g_gsum[1][g * 128 + k] * inv_t * W0[(128 + k) * 128 + j];
    g_H[g * 128 + j] = fmaxf(acc, 0.f);
}

__global__ void loss_kernel(const float* __restrict__ W1, const float* __restrict__ b1,
                            const int* __restrict__ y, float* __restrict__ out) {
    int g = threadIdx.x;  // 128 threads
    float l0 = b1[0], l1 = b1[1];
    for (int j = 0; j < 128; ++j) {
        float hv = g_H[g * 128 + j];
        l0 += hv * W1[j * 2 + 0];
        l1 += hv * W1[j * 2 + 1];
    }
    float m = fmaxf(l0, l1);
    float lse = m + logf(expf(l0 - m) + expf(l1 - m));
    float ly = (y[g] == 0) ? l0 : l1;
    float c = -(ly - lse) * (1.0f / (float)N_GRAPHS);
    __shared__ float red[128];
    red[g] = c;
    __syncthreads();
    for (int s = 64; s; s >>= 1) {
        if (g < s) red[g] += red[g + s];
        __syncthreads();
    }
    if (g == 0) out[0] = red[0];
}

extern "C" void kernel_launch(void* const* d_in, const int* in_sizes, int n_in,
                              void* d_out, int out_size, void* d_ws, size_t ws_size,
                              hipStream_t stream) {
    const float* x_s      = (const float*)d_in[0];
    const float* x_t      = (const float*)d_in[1];
    const float* ea_s     = (const float*)d_in[2];
    const float* ea_t     = (const float*)d_in[3];
    const int*   ei_s     = (const int*)d_in[4];
    const int*   ei_t     = (const int*)d_in[5];
    const int*   batch_s  = (const int*)d_in[6];
    const int*   batch_t  = (const int*)d_in[7];
    const int*   y        = (const int*)d_in[8];
    const float* node_emb = (const float*)d_in[9];
    const float* edge_emb = (const float*)d_in[10];
    const float* W_in_0   = (const float*)d_in[11];
    const float* W_in_1   = (const float*)d_in[12];
    const float* W_out_0  = (const float*)d_in[13];
    const float* W_out_1  = (const float*)d_in[14];
    const float* Wg_in    = (const float*)d_in[15];
    const float* bg_in    = (const float*)d_in[16];
    const float* Wg_out   = (const float*)d_in[17];
    const float* bg_out   = (const float*)d_in[18];
    const float* cls_W0   = (const float*)d_in[19];
    const float* cls_b0   = (const float*)d_in[20];
    const float* cls_W1   = (const float*)d_in[21];
    const float* cls_b1   = (const float*)d_in[22];

    const int N = N_NODES, E = N_EDGES;

    zero_gsum_kernel<<<(2 * N_GRAPHS * NODE_DIM + 255) / 256, 256, 0, stream>>>();

    for (int side = 0; side < 2; ++side) {
        const float* xin   = side ? x_t : x_s;
        const float* eain  = side ? ea_t : ea_s;
        const int*   ei    = side ? ei_t : ei_s;
        const int*   batch = side ? batch_t : batch_s;
        const int* row = ei;
        const int* col = ei + E;

        node_embed_kernel<<<(N + 3) / 4, 256, 0, stream>>>(xin, node_emb, N);
        edge_embed_kernel<<<(2 * E + 255) / 256, 256, 0, stream>>>(eain, edge_emb, 2 * E);

        // ---- CSR build (once per side; edge_index constant across layers) ----
        csr_zero_kernel<<<(N + 255) / 256, 256, 0, stream>>>();
        csr_count_kernel<<<(E + 255) / 256, 256, 0, stream>>>(row, col, E);
        csr_bsum_kernel<<<dim3(SCAN_NBLK, 2), 256, 0, stream>>>();
        csr_bscan_kernel<<<2, 64, 0, stream>>>();
        csr_off_kernel<<<dim3(SCAN_NBLK, 2), 256, 0, stream>>>(E);
        csr_fill_kernel<<<(E + 255) / 256, 256, 0, stream>>>(row, col, E);

        int cur = 0;
        for (int k = 0; k < K_LAYERS; ++k) {
            const float* Wi0 = W_in_0 + (size_t)k * 320 * 64;
            const float* Wo0 = W_out_0 + (size_t)k * 320 * 64;
            assemble_wcat<<<256, 256, 0, stream>>>(Wi0, Wo0, Wg_in + (size_t)k * 128 * 128,
                                                   Wg_out + (size_t)k * 128 * 128);
            assemble_wmidt<<<32, 256, 0, stream>>>(Wi0, Wo0);
            gemm_xw_mfma<<<dim3((N + 63) / 64, 2), 256, 0, stream>>>(cur, N);
            edge_update_mfma<<<dim3((E + 255) / 256, 2), 256, 0, stream>>>(
                row, col, W_in_1 + (size_t)k * 64, W_out_1 + (size_t)k * 64,
                (k < K_LAYERS - 1) ? 1 : 0, E);
            aggregate_kernel<<<(N + 3) / 4, 256, 0, stream>>>(
                cur, bg_in + (size_t)k * 128, bg_out + (size_t)k * 128, N);
            cur ^= 1;
        }
        pool_kernel<<<(N + 127) / 128, 128, 0, stream>>>(cur, side, batch, N);
        count_kernel<<<1, 128, 0, stream>>>(side, batch, N);
    }

    hidden_kernel<<<128, 128, 0, stream>>>(cls_W0, cls_b0);
    loss_kernel<<<1, 128, 0, stream>>>(cls_W1, cls_b1, y, (float*)d_out);
}

// Round 9
// 1300.846 us; speedup vs baseline: 20.6914x; 1.2930x over previous
//
#include <hip/hip_runtime.h>
#include <hip/hip_bf16.h>

#define N_NODES 100000
#define N_EDGES 300000
#define N_GRAPHS 128
#define NODE_VOCAB 200
#define NODE_DIM 128
#define EDGE_DIM 64
#define K_LAYERS 3

#define SCAN_CHUNK 2048
#define SCAN_NBLK ((N_NODES + SCAN_CHUNK - 1) / SCAN_CHUNK)  // 49

typedef unsigned short ushort_t;
typedef __attribute__((ext_vector_type(8))) __bf16 bf16x8;
typedef __attribute__((ext_vector_type(4))) float f32x4;

__device__ inline ushort_t f2bf(float f) {
    unsigned int u = __float_as_uint(f);
    unsigned int r = (u + 0x7fff + ((u >> 16) & 1)) >> 16;
    return (ushort_t)r;
}
__device__ inline float bf2f(ushort_t u) {
    return __uint_as_float(((unsigned int)u) << 16);
}

// slot layout in the 32-col per-node scalar table (24 used):
//   dir D (0=in,1=out): base D*12; role A at +0, role C at +6; within role: off(k)+j,
//   off = {0,1,3}. Active cols at layer j:
#define MASK_J0 0x2CB2CBu
#define MASK_J1 0x514514u
#define MASK_J2 0x820820u

// ---------------- static device scratch (no reliance on ws_size) ----------------
__device__ ushort_t g_hb[2][(size_t)N_NODES * NODE_DIM];  // bf16 ping-pong node state
__device__ ushort_t g_XWx_b[(size_t)N_NODES * 256];       // bf16 [xi | xo]
__device__ ushort_t g_WcatT[256 * 128];                   // Wcat^T bf16 [n][k] (xi|xo only)
__device__ ushort_t g_QT[K_LAYERS][32][128];              // gate-chain vectors, bf16
__device__ float g_scal[(size_t)N_NODES * 32];            // per-node gate scalars
__device__ float g_bias[8][6];                            // e0 vocab bias [t][dir*3+k]
__device__ int  g_evoc[2 * N_EDGES];                      // edge vocab index
__device__ float g_wbuf[(size_t)2 * N_EDGES];
__device__ float g_gsum[2][N_GRAPHS * NODE_DIM];
__device__ float g_cnt[2][N_GRAPHS];
__device__ float g_H[N_GRAPHS * NODE_DIM];
// CSR (rebuilt per side; constant across layers)
__device__ int  g_deg_in[N_NODES];
__device__ int  g_deg_out[N_NODES];
__device__ int  g_off_in[N_NODES + 1];
__device__ int  g_off_out[N_NODES + 1];
__device__ int  g_cur_in[N_NODES];
__device__ int  g_cur_out[N_NODES];
__device__ int2 g_lst_in[N_EDGES];   // (src=row, e) keyed by col
__device__ int2 g_lst_out[N_EDGES];  // (src=col, e) keyed by row
__device__ int  g_bsum[2][SCAN_NBLK];
__device__ int  g_boff[2][SCAN_NBLK];

// ---------------- node argmax + embed (bf16 state out) ----------------
__global__ void node_embed_kernel(const float* __restrict__ x, const float* __restrict__ emb,
                                  int N) {
    int wave = threadIdx.x >> 6;
    int lane = threadIdx.x & 63;
    int n = blockIdx.x * 4 + wave;
    if (n >= N) return;
    const float* xr = x + (size_t)n * NODE_VOCAB;
    float v = xr[lane];
    int idx = lane;
    float nv = xr[lane + 64];
    if (nv > v) { v = nv; idx = lane + 64; }
    nv = xr[lane + 128];
    if (nv > v) { v = nv; idx = lane + 128; }
    if (lane < NODE_VOCAB - 192) {
        nv = xr[lane + 192];
        if (nv > v) { v = nv; idx = lane + 192; }
    }
    #pragma unroll
    for (int off = 32; off; off >>= 1) {
        float ov = __shfl_xor(v, off);
        int oi = __shfl_xor(idx, off);
        if (ov > v || (ov == v && oi < idx)) { v = ov; idx = oi; }
    }
    const float* er = emb + (size_t)idx * NODE_DIM;
    g_hb[0][(size_t)n * NODE_DIM + lane] = f2bf(er[lane]);
    g_hb[0][(size_t)n * NODE_DIM + 64 + lane] = f2bf(er[64 + lane]);
}

// ---------------- edge argmax -> vocab index only ----------------
__global__ void edge_voc_kernel(const float* __restrict__ ea, int M) {
    long idx = (long)blockIdx.x * 256 + threadIdx.x;
    if (idx >= M) return;
    const float* ar = ea + idx * 8;
    float4 v0 = *(const float4*)ar;
    float4 v1 = *(const float4*)(ar + 4);
    float vals[8] = {v0.x, v0.y, v0.z, v0.w, v1.x, v1.y, v1.z, v1.w};
    int best = 0;
    float bv = vals[0];
    #pragma unroll
    for (int i = 1; i < 8; ++i)
        if (vals[i] > bv) { bv = vals[i]; best = i; }
    g_evoc[idx] = best;
}

// ---------------- gate chain setup (once): QT, bias ----------------
__global__ void setup_gates_kernel(const float* __restrict__ Wi0, const float* __restrict__ Wi1,
                                   const float* __restrict__ Wo0, const float* __restrict__ Wo1,
                                   const float* __restrict__ eemb) {
    int t = threadIdx.x;  // 128
    for (int i = t; i < K_LAYERS * 32 * 128; i += 128) ((ushort_t*)g_QT)[i] = 0;
    __shared__ float u[64], un[64];
    __syncthreads();
    for (int D = 0; D < 2; ++D) {
        const float* W0 = D ? Wo0 : Wi0;
        const float* W1 = D ? Wo1 : Wi1;
        for (int k = 0; k < K_LAYERS; ++k) {
            int offk = (k == 0) ? 0 : (k == 1 ? 1 : 3);
            if (t < 64) u[t] = W1[k * 64 + t];
            __syncthreads();
            for (int j = k; j >= 0; --j) {
                const float* Wj = W0 + (size_t)j * 320 * 64;
                float qa = 0.f, qc = 0.f;
                for (int m = 0; m < 64; ++m) {
                    float um = u[m];
                    qa += Wj[t * 64 + m] * um;
                    qc += Wj[(192 + t) * 64 + m] * um;
                }
                g_QT[j][D * 12 + offk + j][t] = f2bf(qa);
                g_QT[j][D * 12 + 6 + offk + j][t] = f2bf(qc);
                float s = 0.f;
                if (t < 64) {
                    for (int m = 0; m < 64; ++m) s += Wj[(128 + t) * 64 + m] * u[m];
                }
                __syncthreads();
                if (t < 64) un[t] = s;
                __syncthreads();
                if (t < 64) u[t] = un[t];
                __syncthreads();
            }
            if (t < 8) {
                float s = 0.f;
                for (int m = 0; m < 64; ++m) s += eemb[t * 64 + m] * u[m];
                g_bias[t][D * 3 + k] = s;
            }
            __syncthreads();
        }
    }
}

// ---------------- CSR build ----------------
__global__ void csr_zero_kernel() {
    int i = blockIdx.x * 256 + threadIdx.x;
    if (i < N_NODES) { g_deg_in[i] = 0; g_deg_out[i] = 0; }
}

__global__ void csr_count_kernel(const int* __restrict__ row, const int* __restrict__ col,
                                 int E) {
    int e = blockIdx.x * 256 + threadIdx.x;
    if (e >= E) return;
    atomicAdd(&g_deg_in[col[e]], 1);
    atomicAdd(&g_deg_out[row[e]], 1);
}

__global__ void csr_bsum_kernel() {
    int which = blockIdx.y;
    const int* deg = which ? g_deg_out : g_deg_in;
    int b = blockIdx.x;
    int t = threadIdx.x;
    int base = b * SCAN_CHUNK;
    int s = 0;
    #pragma unroll
    for (int i = 0; i < SCAN_CHUNK / 256; ++i) {
        int idx = base + i * 256 + t;
        if (idx < N_NODES) s += deg[idx];
    }
    __shared__ int red[256];
    red[t] = s;
    __syncthreads();
    for (int d = 128; d; d >>= 1) {
        if (t < d) red[t] += red[t + d];
        __syncthreads();
    }
    if (t == 0) g_bsum[which][b] = red[0];
}

__global__ void csr_bscan_kernel() {
    int which = blockIdx.x;
    int t = threadIdx.x;  // 64 threads
    int v = (t < SCAN_NBLK) ? g_bsum[which][t] : 0;
    int orig = v;
    #pragma unroll
    for (int d = 1; d < 64; d <<= 1) {
        int u = __shfl_up(v, d, 64);
        if (t >= d) v += u;
    }
    if (t < SCAN_NBLK) g_boff[which][t] = v - orig;
}

__global__ void csr_off_kernel(int total) {
    int which = blockIdx.y;
    const int* deg = which ? g_deg_out : g_deg_in;
    int* off = which ? g_off_out : g_off_in;
    int* cur = which ? g_cur_out : g_cur_in;
    int b = blockIdx.x;
    int t = threadIdx.x;
    const int per = SCAN_CHUNK / 256;  // 8
    int lo = b * SCAN_CHUNK + t * per;
    int d8[per];
    int s = 0;
    #pragma unroll
    for (int i = 0; i < per; ++i) {
        int idx = lo + i;
        d8[i] = (idx < N_NODES) ? deg[idx] : 0;
        s += d8[i];
    }
    __shared__ int part[256];
    part[t] = s;
    __syncthreads();
    for (int d = 1; d < 256; d <<= 1) {
        int add = (t >= d) ? part[t - d] : 0;
        __syncthreads();
        part[t] += add;
        __syncthreads();
    }
    int run = g_boff[which][b] + part[t] - s;
    #pragma unroll
    for (int i = 0; i < per; ++i) {
        int idx = lo + i;
        if (idx < N_NODES) {
            off[idx] = run;
            cur[idx] = run;
            run += d8[i];
        }
    }
    if (b == 0 && t == 0) off[N_NODES] = total;
}

__global__ void csr_fill_kernel(const int* __restrict__ row, const int* __restrict__ col,
                                int E) {
    int e = blockIdx.x * 256 + threadIdx.x;
    if (e >= E) return;
    int r = row[e], c = col[e];
    int p = atomicAdd(&g_cur_in[c], 1);
    g_lst_in[p] = make_int2(r, e);
    int q = atomicAdd(&g_cur_out[r], 1);
    g_lst_out[q] = make_int2(c, e);
}

// ---------------- assemble Wcat^T (256 x 128, bf16): [xi | xo] ----------------
__global__ void assemble_wcat(const float* __restrict__ Wgi, const float* __restrict__ Wgo) {
    int idx = blockIdx.x * 256 + threadIdx.x;  // 32768
    int n = idx >> 7;
    int kd = idx & 127;
    float v = (n < 128) ? Wgi[kd * 128 + n] : Wgo[kd * 128 + (n - 128)];
    g_WcatT[n * 128 + kd] = f2bf(v);
}

// ---------------- node GEMM via MFMA: XWx(bf16) = x_bf16 (M x 128) @ Wcat (128 x 256) ----------------
__global__ __launch_bounds__(256) void gemm_xw_mfma(int cur, int M) {
    const ushort_t* __restrict__ hb = g_hb[cur];
    int m0 = blockIdx.x * 64;
    int t = threadIdx.x;
    int wave = t >> 6, lane = t & 63;
    int nbase = wave * 64;
    __shared__ ushort_t As[64 * 128];  // 16 KB, XOR-swizzled: elem k ^= (row&7)<<3

    #pragma unroll
    for (int i = 0; i < 4; ++i) {
        int idx = t + i * 256;           // 0..1023
        int m = idx >> 4, c = idx & 15;  // row, 16B-chunk (8 elems)
        int gm = m0 + m;
        uint4 v = make_uint4(0u, 0u, 0u, 0u);
        if (gm < M) v = *(const uint4*)(hb + (size_t)gm * 128 + c * 8);
        *(uint4*)&As[m * 128 + ((c * 8) ^ ((m & 7) << 3))] = v;
    }
    __syncthreads();

    int lr = lane & 15, lk = lane >> 4;
    f32x4 acc[4][4];
    #pragma unroll
    for (int i = 0; i < 4; ++i)
        #pragma unroll
        for (int j = 0; j < 4; ++j)
            acc[i][j] = (f32x4){0.f, 0.f, 0.f, 0.f};

    const ushort_t* Bbase = g_WcatT + (size_t)nbase * 128;
    #pragma unroll
    for (int ks = 0; ks < 4; ++ks) {
        bf16x8 a[4], b[4];
        int ke = ks * 32 + lk * 8;
        #pragma unroll
        for (int mt = 0; mt < 4; ++mt) {
            int row = mt * 16 + lr;
            a[mt] = *(const bf16x8*)&As[row * 128 + (ke ^ ((row & 7) << 3))];
        }
        #pragma unroll
        for (int nt = 0; nt < 4; ++nt) {
            b[nt] = *(const bf16x8*)(Bbase + (size_t)(nt * 16 + lr) * 128 + ke);
        }
        #pragma unroll
        for (int mt = 0; mt < 4; ++mt)
            #pragma unroll
            for (int nt = 0; nt < 4; ++nt)
                acc[mt][nt] = __builtin_amdgcn_mfma_f32_16x16x32_bf16(a[mt], b[nt], acc[mt][nt], 0, 0, 0);
    }

    #pragma unroll
    for (int mt = 0; mt < 4; ++mt) {
        #pragma unroll
        for (int r = 0; r < 4; ++r) {
            int gm = m0 + mt * 16 + lk * 4 + r;
            if (gm >= M) continue;
            #pragma unroll
            for (int nt = 0; nt < 4; ++nt) {
                int n = nbase + nt * 16 + lr;
                g_XWx_b[(size_t)gm * 256 + n] = f2bf(acc[mt][nt][r]);
            }
        }
    }
}

// ---------------- skinny GEMM: scal cols = x_bf16 (M x 128) @ QT[layer]^T (128 x 32) ----------------
// grid (ceil(M/256)) x 256 threads; wave w handles rows +w*64
__global__ __launch_bounds__(256) void gemm_scal_mfma(int cur, int layer, unsigned int mask,
                                                      int M) {
    const ushort_t* __restrict__ hb = g_hb[cur];
    int t = threadIdx.x;
    int wave = t >> 6, lane = t & 63;
    int lr = lane & 15, lk = lane >> 4;
    int m0 = blockIdx.x * 256 + wave * 64;
    const ushort_t* QT = &g_QT[layer][0][0];

    bf16x8 b[2][4];
    #pragma unroll
    for (int nt = 0; nt < 2; ++nt)
        #pragma unroll
        for (int ks = 0; ks < 4; ++ks)
            b[nt][ks] = *(const bf16x8*)&QT[(nt * 16 + lr) * 128 + ks * 32 + lk * 8];

    bf16x8 zero8;
    #pragma unroll
    for (int q = 0; q < 8; ++q) zero8[q] = (__bf16)0.0f;

    f32x4 acc[4][2];
    #pragma unroll
    for (int i = 0; i < 4; ++i)
        #pragma unroll
        for (int j = 0; j < 2; ++j)
            acc[i][j] = (f32x4){0.f, 0.f, 0.f, 0.f};

    #pragma unroll
    for (int mt = 0; mt < 4; ++mt) {
        int row = m0 + mt * 16 + lr;
        bool valid = row < M;
        const ushort_t* ar = hb + (size_t)row * 128 + lk * 8;
        #pragma unroll
        for (int ks = 0; ks < 4; ++ks) {
            bf16x8 a = valid ? *(const bf16x8*)(ar + ks * 32) : zero8;
            acc[mt][0] = __builtin_amdgcn_mfma_f32_16x16x32_bf16(a, b[0][ks], acc[mt][0], 0, 0, 0);
            acc[mt][1] = __builtin_amdgcn_mfma_f32_16x16x32_bf16(a, b[1][ks], acc[mt][1], 0, 0, 0);
        }
    }

    #pragma unroll
    for (int mt = 0; mt < 4; ++mt)
        #pragma unroll
        for (int r = 0; r < 4; ++r) {
            int gm = m0 + mt * 16 + lk * 4 + r;
            if (gm >= M) continue;
            #pragma unroll
            for (int nt = 0; nt < 2; ++nt) {
                int colc = nt * 16 + lr;
                if ((mask >> colc) & 1u)
                    g_scal[(size_t)gm * 32 + colc] = acc[mt][nt][r];
            }
        }
}

// ---------------- gate: w = sigmoid(bias[voc] + sum of node scalars) ----------------
__global__ void gate_kernel(int k, const int* __restrict__ row, const int* __restrict__ col,
                            int E) {
    long idx = (long)blockIdx.x * 256 + threadIdx.x;
    if (idx >= 2L * E) return;
    int dir = idx >= E;
    int e = dir ? (int)(idx - E) : (int)idx;
    int r = row[e], c = col[e];
    int nA = dir ? c : r;
    int nC = dir ? r : c;
    int offk = (k == 0) ? 0 : (k == 1 ? 1 : 3);
    int Ab = dir * 12 + offk;
    int Cb = dir * 12 + 6 + offk;
    float s = g_bias[g_evoc[idx]][dir * 3 + k];
    const float* sa = g_scal + (size_t)nA * 32;
    const float* sc = g_scal + (size_t)nC * 32;
    for (int j = 0; j <= k; ++j) s += sa[Ab + j] + sc[Cb + j];
    g_wbuf[idx] = 1.0f / (1.0f + expf(-s));
}

// ---------------- fused aggregate: x_next(bf16) = x + bgi + bgo + CSR-gathered in/out sums ----------------
__global__ __launch_bounds__(256) void aggregate_kernel(int cur, const float* __restrict__ bgi,
                                                        const float* __restrict__ bgo, int N) {
    int wave = threadIdx.x >> 6;
    int lane = threadIdx.x & 63;
    int n = blockIdx.x * 4 + wave;
    if (n >= N) return;
    unsigned int xv = *(const unsigned int*)(g_hb[cur] + (size_t)n * 128 + lane * 2);
    float2 bi = ((const float2*)bgi)[lane];
    float2 bo = ((const float2*)bgo)[lane];
    float2 acc;
    acc.x = bf2f((ushort_t)(xv & 0xffff)) + bi.x + bo.x;
    acc.y = bf2f((ushort_t)(xv >> 16)) + bi.y + bo.y;
    int p0 = g_off_in[n], p1 = g_off_in[n + 1];
    for (int p = p0; p < p1; ++p) {
        int2 se = g_lst_in[p];
        float wv = g_wbuf[se.y];
        unsigned int pv = *(const unsigned int*)(g_XWx_b + (size_t)se.x * 256 + lane * 2);
        acc.x += wv * bf2f((ushort_t)(pv & 0xffff));
        acc.y += wv * bf2f((ushort_t)(pv >> 16));
    }
    p0 = g_off_out[n]; p1 = g_off_out[n + 1];
    for (int p = p0; p < p1; ++p) {
        int2 se = g_lst_out[p];
        float wv = g_wbuf[(size_t)N_EDGES + se.y];
        unsigned int pv = *(const unsigned int*)(g_XWx_b + (size_t)se.x * 256 + 128 + lane * 2);
        acc.x += wv * bf2f((ushort_t)(pv & 0xffff));
        acc.y += wv * bf2f((ushort_t)(pv >> 16));
    }
    unsigned int pk = ((unsigned int)f2bf(acc.y) << 16) | (unsigned int)f2bf(acc.x);
    *(unsigned int*)(g_hb[cur ^ 1] + (size_t)n * 128 + lane * 2) = pk;
}

// ---------------- mean-pool partials (bf16 in, fp32 accumulate) ----------------
__global__ void pool_kernel(int fin, int side, const int* __restrict__ batch, int N) {
    const ushort_t* x = g_hb[fin];
    float* gsum = g_gsum[side];
    int n0 = blockIdx.x * 128;
    int d = threadIdx.x;  // 128 threads
    if (n0 >= N) return;
    int nend = min(n0 + 128, N);
    float acc = 0.f;
    int curg = batch[n0];
    for (int n = n0; n < nend; ++n) {
        int g = batch[n];
        if (g != curg) {
            atomicAdd(&gsum[curg * 128 + d], acc);
            acc = 0.f;
            curg = g;
        }
        acc += bf2f(x[(size_t)n * 128 + d]);
    }
    atomicAdd(&gsum[curg * 128 + d], acc);
}

__global__ void count_kernel(int side, const int* __restrict__ batch, int N) {
    int g = threadIdx.x;  // 128 threads
    int lo = 0, hi = N;
    while (lo < hi) { int mid = (lo + hi) >> 1; if (batch[mid] < g) lo = mid + 1; else hi = mid; }
    int a = lo;
    lo = 0; hi = N;
    while (lo < hi) { int mid = (lo + hi) >> 1; if (batch[mid] < g + 1) lo = mid + 1; else hi = mid; }
    g_cnt[side][g] = (float)(lo - a);
}

__global__ void zero_gsum_kernel() {
    int i = blockIdx.x * 256 + threadIdx.x;
    if (i < 2 * N_GRAPHS * NODE_DIM) ((float*)g_gsum)[i] = 0.f;
}

// ---------------- classifier ----------------
__global__ void hidden_kernel(const float* __restrict__ W0, const float* __restrict__ b0) {
    int g = blockIdx.x;
    int j = threadIdx.x;  // 128 x 128
    float inv_s = 1.0f / fmaxf(g_cnt[0][g], 1.0f);
    float inv_t = 1.0f / fmaxf(g_cnt[1][g], 1.0f);
    float acc = b0[j];
    for (int k = 0; k < 128; ++k) acc += g_gsum[0][g * 128 + k] * inv_s * W0[k * 128 + j];
    for (int k = 0; k < 128; ++k) acc += g_gsum[1][g * 128 + k] * inv_t * W0[(128 + k) * 128 + j];
    g_H[g * 128 + j] = fmaxf(acc, 0.f);
}

__global__ void loss_kernel(const float* __restrict__ W1, const float* __restrict__ b1,
                            const int* __restrict__ y, float* __restrict__ out) {
    int g = threadIdx.x;  // 128 threads
    float l0 = b1[0], l1 = b1[1];
    for (int j = 0; j < 128; ++j) {
        float hv = g_H[g * 128 + j];
        l0 += hv * W1[j * 2 + 0];
        l1 += hv * W1[j * 2 + 1];
    }
    float m = fmaxf(l0, l1);
    float lse = m + logf(expf(l0 - m) + expf(l1 - m));
    float ly = (y[g] == 0) ? l0 : l1;
    float c = -(ly - lse) * (1.0f / (float)N_GRAPHS);
    __shared__ float red[128];
    red[g] = c;
    __syncthreads();
    for (int s = 64; s; s >>= 1) {
        if (g < s) red[g] += red[g + s];
        __syncthreads();
    }
    if (g == 0) out[0] = red[0];
}

extern "C" void kernel_launch(void* const* d_in, const int* in_sizes, int n_in,
                              void* d_out, int out_size, void* d_ws, size_t ws_size,
                              hipStream_t stream) {
    const float* x_s      = (const float*)d_in[0];
    const float* x_t      = (const float*)d_in[1];
    const float* ea_s     = (const float*)d_in[2];
    const float* ea_t     = (const float*)d_in[3];
    const int*   ei_s     = (const int*)d_in[4];
    const int*   ei_t     = (const int*)d_in[5];
    const int*   batch_s  = (const int*)d_in[6];
    const int*   batch_t  = (const int*)d_in[7];
    const int*   y        = (const int*)d_in[8];
    const float* node_emb = (const float*)d_in[9];
    const float* edge_emb = (const float*)d_in[10];
    const float* W_in_0   = (const float*)d_in[11];
    const float* W_in_1   = (const float*)d_in[12];
    const float* W_out_0  = (const float*)d_in[13];
    const float* W_out_1  = (const float*)d_in[14];
    const float* Wg_in    = (const float*)d_in[15];
    const float* bg_in    = (const float*)d_in[16];
    const float* Wg_out   = (const float*)d_in[17];
    const float* bg_out   = (const float*)d_in[18];
    const float* cls_W0   = (const float*)d_in[19];
    const float* cls_b0   = (const float*)d_in[20];
    const float* cls_W1   = (const float*)d_in[21];
    const float* cls_b1   = (const float*)d_in[22];

    const int N = N_NODES, E = N_EDGES;
    static const unsigned int MASKS[3] = {MASK_J0, MASK_J1, MASK_J2};

    zero_gsum_kernel<<<(2 * N_GRAPHS * NODE_DIM + 255) / 256, 256, 0, stream>>>();
    setup_gates_kernel<<<1, 128, 0, stream>>>(W_in_0, W_in_1, W_out_0, W_out_1, edge_emb);

    for (int side = 0; side < 2; ++side) {
        const float* xin   = side ? x_t : x_s;
        const float* eain  = side ? ea_t : ea_s;
        const int*   ei    = side ? ei_t : ei_s;
        const int*   batch = side ? batch_t : batch_s;
        const int* row = ei;
        const int* col = ei + E;

        node_embed_kernel<<<(N + 3) / 4, 256, 0, stream>>>(xin, node_emb, N);
        edge_voc_kernel<<<(2 * E + 255) / 256, 256, 0, stream>>>(eain, 2 * E);

        // ---- CSR build (once per side; edge_index constant across layers) ----
        csr_zero_kernel<<<(N + 255) / 256, 256, 0, stream>>>();
        csr_count_kernel<<<(E + 255) / 256, 256, 0, stream>>>(row, col, E);
        csr_bsum_kernel<<<dim3(SCAN_NBLK, 2), 256, 0, stream>>>();
        csr_bscan_kernel<<<2, 64, 0, stream>>>();
        csr_off_kernel<<<dim3(SCAN_NBLK, 2), 256, 0, stream>>>(E);
        csr_fill_kernel<<<(E + 255) / 256, 256, 0, stream>>>(row, col, E);

        int cur = 0;
        for (int k = 0; k < K_LAYERS; ++k) {
            assemble_wcat<<<128, 256, 0, stream>>>(Wg_in + (size_t)k * 128 * 128,
                                                   Wg_out + (size_t)k * 128 * 128);
            gemm_xw_mfma<<<(N + 63) / 64, 256, 0, stream>>>(cur, N);
            gemm_scal_mfma<<<(N + 255) / 256, 256, 0, stream>>>(cur, k, MASKS[k], N);
            gate_kernel<<<(2 * E + 255) / 256, 256, 0, stream>>>(k, row, col, E);
            aggregate_kernel<<<(N + 3) / 4, 256, 0, stream>>>(
                cur, bg_in + (size_t)k * 128, bg_out + (size_t)k * 128, N);
            cur ^= 1;
        }
        pool_kernel<<<(N + 127) / 128, 128, 0, stream>>>(cur, side, batch, N);
        count_kernel<<<1, 128, 0, stream>>>(side, batch, N);
    }

    hidden_kernel<<<128, 128, 0, stream>>>(cls_W0, cls_b0);
    loss_kernel<<<1, 128, 0, stream>>>(cls_W1, cls_b1, y, (float*)d_out);
}

// Round 10
// 1111.712 us; speedup vs baseline: 24.2116x; 1.1701x over previous
//
#include <hip/hip_runtime.h>
#include <hip/hip_bf16.h>

#define N_NODES 100000
#define N_EDGES 300000
#define N_GRAPHS 128
#define NODE_VOCAB 200
#define NODE_DIM 128
#define EDGE_DIM 64
#define K_LAYERS 3

#define SCAN_CHUNK 2048
#define SCAN_NBLK ((N_NODES + SCAN_CHUNK - 1) / SCAN_CHUNK)  // 49

typedef unsigned short ushort_t;
typedef __attribute__((ext_vector_type(8))) __bf16 bf16x8;
typedef __attribute__((ext_vector_type(4))) float f32x4;

__device__ inline ushort_t f2bf(float f) {
    unsigned int u = __float_as_uint(f);
    unsigned int r = (u + 0x7fff + ((u >> 16) & 1)) >> 16;
    return (ushort_t)r;
}
__device__ inline float bf2f(ushort_t u) {
    return __uint_as_float(((unsigned int)u) << 16);
}
__device__ inline float bflo(unsigned int u) { return __uint_as_float(u << 16); }
__device__ inline float bfhi(unsigned int u) { return __uint_as_float(u & 0xffff0000u); }

// slot layout in the 32-col per-node scalar table (24 used):
//   dir D (0=in,1=out): base D*12; role A at +0, role C at +6; within role: off(k)+j,
//   off = {0,1,3}. Active cols at layer j:
#define MASK_J0 0x2CB2CBu
#define MASK_J1 0x514514u
#define MASK_J2 0x820820u

// ---------------- static device scratch (no reliance on ws_size) ----------------
__device__ ushort_t g_hb[2][(size_t)N_NODES * NODE_DIM];  // bf16 ping-pong node state
__device__ ushort_t g_XWx_b[(size_t)N_NODES * 256];       // bf16 [xi | xo]
__device__ ushort_t g_WcatT[256 * 128];                   // Wcat^T bf16 [n][k] (xi|xo only)
__device__ ushort_t g_QT[K_LAYERS][32][128];              // gate-chain vectors, bf16
__device__ float g_scal[(size_t)N_NODES * 32];            // per-node gate scalars
__device__ float g_bias[8][6];                            // e0 vocab bias [t][dir*3+k]
__device__ int  g_evoc[2 * N_EDGES];                      // edge vocab index
__device__ float g_wbuf[(size_t)2 * N_EDGES];
__device__ float g_gsum[2][N_GRAPHS * NODE_DIM];
__device__ float g_cnt[2][N_GRAPHS];
__device__ float g_H[N_GRAPHS * NODE_DIM];
// CSR (rebuilt per side; constant across layers)
__device__ int  g_deg_in[N_NODES];
__device__ int  g_deg_out[N_NODES];
__device__ int  g_off_in[N_NODES + 1];
__device__ int  g_off_out[N_NODES + 1];
__device__ int  g_cur_in[N_NODES];
__device__ int  g_cur_out[N_NODES];
__device__ int2 g_lst_in[N_EDGES];   // (src=row, e) keyed by col
__device__ int2 g_lst_out[N_EDGES];  // (src=col, e) keyed by row
__device__ int  g_bsum[2][SCAN_NBLK];
__device__ int  g_boff[2][SCAN_NBLK];

// ---------------- node argmax + embed (bf16 state out) ----------------
__global__ void node_embed_kernel(const float* __restrict__ x, const float* __restrict__ emb,
                                  int N) {
    int wave = threadIdx.x >> 6;
    int lane = threadIdx.x & 63;
    int n = blockIdx.x * 4 + wave;
    if (n >= N) return;
    const float* xr = x + (size_t)n * NODE_VOCAB;
    float v = xr[lane];
    int idx = lane;
    float nv = xr[lane + 64];
    if (nv > v) { v = nv; idx = lane + 64; }
    nv = xr[lane + 128];
    if (nv > v) { v = nv; idx = lane + 128; }
    if (lane < NODE_VOCAB - 192) {
        nv = xr[lane + 192];
        if (nv > v) { v = nv; idx = lane + 192; }
    }
    #pragma unroll
    for (int off = 32; off; off >>= 1) {
        float ov = __shfl_xor(v, off);
        int oi = __shfl_xor(idx, off);
        if (ov > v || (ov == v && oi < idx)) { v = ov; idx = oi; }
    }
    const float* er = emb + (size_t)idx * NODE_DIM;
    g_hb[0][(size_t)n * NODE_DIM + lane] = f2bf(er[lane]);
    g_hb[0][(size_t)n * NODE_DIM + 64 + lane] = f2bf(er[64 + lane]);
}

// ---------------- edge argmax -> vocab index only ----------------
__global__ void edge_voc_kernel(const float* __restrict__ ea, int M) {
    long idx = (long)blockIdx.x * 256 + threadIdx.x;
    if (idx >= M) return;
    const float* ar = ea + idx * 8;
    float4 v0 = *(const float4*)ar;
    float4 v1 = *(const float4*)(ar + 4);
    float vals[8] = {v0.x, v0.y, v0.z, v0.w, v1.x, v1.y, v1.z, v1.w};
    int best = 0;
    float bv = vals[0];
    #pragma unroll
    for (int i = 1; i < 8; ++i)
        if (vals[i] > bv) { bv = vals[i]; best = i; }
    g_evoc[idx] = best;
}

// ---------------- gate chain setup (once): QT, bias ----------------
__global__ void setup_gates_kernel(const float* __restrict__ Wi0, const float* __restrict__ Wi1,
                                   const float* __restrict__ Wo0, const float* __restrict__ Wo1,
                                   const float* __restrict__ eemb) {
    int t = threadIdx.x;  // 128
    for (int i = t; i < K_LAYERS * 32 * 128; i += 128) ((ushort_t*)g_QT)[i] = 0;
    __shared__ float u[64], un[64];
    __syncthreads();
    for (int D = 0; D < 2; ++D) {
        const float* W0 = D ? Wo0 : Wi0;
        const float* W1 = D ? Wo1 : Wi1;
        for (int k = 0; k < K_LAYERS; ++k) {
            int offk = (k == 0) ? 0 : (k == 1 ? 1 : 3);
            if (t < 64) u[t] = W1[k * 64 + t];
            __syncthreads();
            for (int j = k; j >= 0; --j) {
                const float* Wj = W0 + (size_t)j * 320 * 64;
                float qa = 0.f, qc = 0.f;
                for (int m = 0; m < 64; ++m) {
                    float um = u[m];
                    qa += Wj[t * 64 + m] * um;
                    qc += Wj[(192 + t) * 64 + m] * um;
                }
                g_QT[j][D * 12 + offk + j][t] = f2bf(qa);
                g_QT[j][D * 12 + 6 + offk + j][t] = f2bf(qc);
                float s = 0.f;
                if (t < 64) {
                    for (int m = 0; m < 64; ++m) s += Wj[(128 + t) * 64 + m] * u[m];
                }
                __syncthreads();
                if (t < 64) un[t] = s;
                __syncthreads();
                if (t < 64) u[t] = un[t];
                __syncthreads();
            }
            if (t < 8) {
                float s = 0.f;
                for (int m = 0; m < 64; ++m) s += eemb[t * 64 + m] * u[m];
                g_bias[t][D * 3 + k] = s;
            }
            __syncthreads();
        }
    }
}

// ---------------- CSR build ----------------
__global__ void csr_zero_kernel() {
    int i = blockIdx.x * 256 + threadIdx.x;
    if (i < N_NODES) { g_deg_in[i] = 0; g_deg_out[i] = 0; }
}

__global__ void csr_count_kernel(const int* __restrict__ row, const int* __restrict__ col,
                                 int E) {
    int e = blockIdx.x * 256 + threadIdx.x;
    if (e >= E) return;
    atomicAdd(&g_deg_in[col[e]], 1);
    atomicAdd(&g_deg_out[row[e]], 1);
}

__global__ void csr_bsum_kernel() {
    int which = blockIdx.y;
    const int* deg = which ? g_deg_out : g_deg_in;
    int b = blockIdx.x;
    int t = threadIdx.x;
    int base = b * SCAN_CHUNK;
    int s = 0;
    #pragma unroll
    for (int i = 0; i < SCAN_CHUNK / 256; ++i) {
        int idx = base + i * 256 + t;
        if (idx < N_NODES) s += deg[idx];
    }
    __shared__ int red[256];
    red[t] = s;
    __syncthreads();
    for (int d = 128; d; d >>= 1) {
        if (t < d) red[t] += red[t + d];
        __syncthreads();
    }
    if (t == 0) g_bsum[which][b] = red[0];
}

__global__ void csr_bscan_kernel() {
    int which = blockIdx.x;
    int t = threadIdx.x;  // 64 threads
    int v = (t < SCAN_NBLK) ? g_bsum[which][t] : 0;
    int orig = v;
    #pragma unroll
    for (int d = 1; d < 64; d <<= 1) {
        int u = __shfl_up(v, d, 64);
        if (t >= d) v += u;
    }
    if (t < SCAN_NBLK) g_boff[which][t] = v - orig;
}

__global__ void csr_off_kernel(int total) {
    int which = blockIdx.y;
    const int* deg = which ? g_deg_out : g_deg_in;
    int* off = which ? g_off_out : g_off_in;
    int* cur = which ? g_cur_out : g_cur_in;
    int b = blockIdx.x;
    int t = threadIdx.x;
    const int per = SCAN_CHUNK / 256;  // 8
    int lo = b * SCAN_CHUNK + t * per;
    int d8[per];
    int s = 0;
    #pragma unroll
    for (int i = 0; i < per; ++i) {
        int idx = lo + i;
        d8[i] = (idx < N_NODES) ? deg[idx] : 0;
        s += d8[i];
    }
    __shared__ int part[256];
    part[t] = s;
    __syncthreads();
    for (int d = 1; d < 256; d <<= 1) {
        int add = (t >= d) ? part[t - d] : 0;
        __syncthreads();
        part[t] += add;
        __syncthreads();
    }
    int run = g_boff[which][b] + part[t] - s;
    #pragma unroll
    for (int i = 0; i < per; ++i) {
        int idx = lo + i;
        if (idx < N_NODES) {
            off[idx] = run;
            cur[idx] = run;
            run += d8[i];
        }
    }
    if (b == 0 && t == 0) off[N_NODES] = total;
}

__global__ void csr_fill_kernel(const int* __restrict__ row, const int* __restrict__ col,
                                int E) {
    int e = blockIdx.x * 256 + threadIdx.x;
    if (e >= E) return;
    int r = row[e], c = col[e];
    int p = atomicAdd(&g_cur_in[c], 1);
    g_lst_in[p] = make_int2(r, e);
    int q = atomicAdd(&g_cur_out[r], 1);
    g_lst_out[q] = make_int2(c, e);
}

// ---------------- assemble Wcat^T (256 x 128, bf16): [xi | xo] ----------------
__global__ void assemble_wcat(const float* __restrict__ Wgi, const float* __restrict__ Wgo) {
    int idx = blockIdx.x * 256 + threadIdx.x;  // 32768
    int n = idx >> 7;
    int kd = idx & 127;
    float v = (n < 128) ? Wgi[kd * 128 + n] : Wgo[kd * 128 + (n - 128)];
    g_WcatT[n * 128 + kd] = f2bf(v);
}

// ---- fused node GEMM via MFMA: XWx(bf16) = x@Wcat (waves 0-3), scal = x@QT^T (wave 4) ----
// 320 threads = 5 waves; grid ceil(M/64)
__global__ __launch_bounds__(320) void gemm_xw_mfma(int cur, int layer, unsigned int mask,
                                                    int M) {
    const ushort_t* __restrict__ hb = g_hb[cur];
    int m0 = blockIdx.x * 64;
    int t = threadIdx.x;
    int wave = t >> 6, lane = t & 63;
    __shared__ ushort_t As[64 * 128];  // 16 KB, XOR-swizzled: elem k ^= (row&7)<<3

    for (int idx = t; idx < 1024; idx += 320) {
        int m = idx >> 4, c = idx & 15;  // row, 16B-chunk (8 elems)
        int gm = m0 + m;
        uint4 v = make_uint4(0u, 0u, 0u, 0u);
        if (gm < M) v = *(const uint4*)(hb + (size_t)gm * 128 + c * 8);
        *(uint4*)&As[m * 128 + ((c * 8) ^ ((m & 7) << 3))] = v;
    }
    __syncthreads();

    int lr = lane & 15, lk = lane >> 4;

    if (wave < 4) {
        int nbase = wave * 64;
        f32x4 acc[4][4];
        #pragma unroll
        for (int i = 0; i < 4; ++i)
            #pragma unroll
            for (int j = 0; j < 4; ++j)
                acc[i][j] = (f32x4){0.f, 0.f, 0.f, 0.f};

        const ushort_t* Bbase = g_WcatT + (size_t)nbase * 128;
        #pragma unroll
        for (int ks = 0; ks < 4; ++ks) {
            bf16x8 a[4], b[4];
            int ke = ks * 32 + lk * 8;
            #pragma unroll
            for (int mt = 0; mt < 4; ++mt) {
                int row = mt * 16 + lr;
                a[mt] = *(const bf16x8*)&As[row * 128 + (ke ^ ((row & 7) << 3))];
            }
            #pragma unroll
            for (int nt = 0; nt < 4; ++nt) {
                b[nt] = *(const bf16x8*)(Bbase + (size_t)(nt * 16 + lr) * 128 + ke);
            }
            #pragma unroll
            for (int mt = 0; mt < 4; ++mt)
                #pragma unroll
                for (int nt = 0; nt < 4; ++nt)
                    acc[mt][nt] = __builtin_amdgcn_mfma_f32_16x16x32_bf16(a[mt], b[nt], acc[mt][nt], 0, 0, 0);
        }

        #pragma unroll
        for (int mt = 0; mt < 4; ++mt) {
            #pragma unroll
            for (int r = 0; r < 4; ++r) {
                int gm = m0 + mt * 16 + lk * 4 + r;
                if (gm >= M) continue;
                #pragma unroll
                for (int nt = 0; nt < 4; ++nt) {
                    int n = nbase + nt * 16 + lr;
                    g_XWx_b[(size_t)gm * 256 + n] = f2bf(acc[mt][nt][r]);
                }
            }
        }
    } else {
        const ushort_t* QT = &g_QT[layer][0][0];
        f32x4 acc[4][2];
        #pragma unroll
        for (int i = 0; i < 4; ++i)
            #pragma unroll
            for (int j = 0; j < 2; ++j)
                acc[i][j] = (f32x4){0.f, 0.f, 0.f, 0.f};

        #pragma unroll
        for (int ks = 0; ks < 4; ++ks) {
            bf16x8 a[4], b[2];
            int ke = ks * 32 + lk * 8;
            #pragma unroll
            for (int mt = 0; mt < 4; ++mt) {
                int row = mt * 16 + lr;
                a[mt] = *(const bf16x8*)&As[row * 128 + (ke ^ ((row & 7) << 3))];
            }
            #pragma unroll
            for (int nt = 0; nt < 2; ++nt)
                b[nt] = *(const bf16x8*)&QT[(nt * 16 + lr) * 128 + ke];
            #pragma unroll
            for (int mt = 0; mt < 4; ++mt)
                #pragma unroll
                for (int nt = 0; nt < 2; ++nt)
                    acc[mt][nt] = __builtin_amdgcn_mfma_f32_16x16x32_bf16(a[mt], b[nt], acc[mt][nt], 0, 0, 0);
        }

        #pragma unroll
        for (int mt = 0; mt < 4; ++mt)
            #pragma unroll
            for (int r = 0; r < 4; ++r) {
                int gm = m0 + mt * 16 + lk * 4 + r;
                if (gm >= M) continue;
                #pragma unroll
                for (int nt = 0; nt < 2; ++nt) {
                    int colc = nt * 16 + lr;
                    if ((mask >> colc) & 1u)
                        g_scal[(size_t)gm * 32 + colc] = acc[mt][nt][r];
                }
            }
    }
}

// ---------------- gate: w = sigmoid(bias[voc] + sum of node scalars) ----------------
__global__ void gate_kernel(int k, const int* __restrict__ row, const int* __restrict__ col,
                            int E) {
    long idx = (long)blockIdx.x * 256 + threadIdx.x;
    if (idx >= 2L * E) return;
    int dir = idx >= E;
    int e = dir ? (int)(idx - E) : (int)idx;
    int r = row[e], c = col[e];
    int nA = dir ? c : r;
    int nC = dir ? r : c;
    int offk = (k == 0) ? 0 : (k == 1 ? 1 : 3);
    int Ab = dir * 12 + offk;
    int Cb = dir * 12 + 6 + offk;
    float s = g_bias[g_evoc[idx]][dir * 3 + k];
    const float* sa = g_scal + (size_t)nA * 32;
    const float* sc = g_scal + (size_t)nC * 32;
    for (int j = 0; j <= k; ++j) s += sa[Ab + j] + sc[Cb + j];
    g_wbuf[idx] = 1.0f / (1.0f + expf(-s));
}

// ------- fused aggregate, 4x16-lane gather groups: x_next(bf16) = x + b + in/out sums -------
__global__ __launch_bounds__(256) void aggregate_kernel(int cur, const float* __restrict__ bgi,
                                                        const float* __restrict__ bgo, int N) {
    int wv = threadIdx.x >> 6;
    int lane = threadIdx.x & 63;
    int grp = lane >> 4, li = lane & 15;
    int n = blockIdx.x * 4 + wv;
    if (n >= N) return;
    float acc[8];
    if (grp == 0) {
        uint4 xv = *(const uint4*)(g_hb[cur] + (size_t)n * 128 + li * 8);
        float4 b1 = *(const float4*)(bgi + li * 8);
        float4 b2 = *(const float4*)(bgi + li * 8 + 4);
        float4 c1 = *(const float4*)(bgo + li * 8);
        float4 c2 = *(const float4*)(bgo + li * 8 + 4);
        acc[0] = bflo(xv.x) + b1.x + c1.x;
        acc[1] = bfhi(xv.x) + b1.y + c1.y;
        acc[2] = bflo(xv.y) + b1.z + c1.z;
        acc[3] = bfhi(xv.y) + b1.w + c1.w;
        acc[4] = bflo(xv.z) + b2.x + c2.x;
        acc[5] = bfhi(xv.z) + b2.y + c2.y;
        acc[6] = bflo(xv.w) + b2.z + c2.z;
        acc[7] = bfhi(xv.w) + b2.w + c2.w;
    } else {
        #pragma unroll
        for (int q = 0; q < 8; ++q) acc[q] = 0.f;
    }
    int p0 = g_off_in[n], p1 = g_off_in[n + 1];
    for (int p = p0 + grp; p < p1; p += 4) {
        int2 se = g_lst_in[p];
        float wvv = g_wbuf[se.y];
        uint4 pv = *(const uint4*)(g_XWx_b + (size_t)se.x * 256 + li * 8);
        acc[0] += wvv * bflo(pv.x);
        acc[1] += wvv * bfhi(pv.x);
        acc[2] += wvv * bflo(pv.y);
        acc[3] += wvv * bfhi(pv.y);
        acc[4] += wvv * bflo(pv.z);
        acc[5] += wvv * bfhi(pv.z);
        acc[6] += wvv * bflo(pv.w);
        acc[7] += wvv * bfhi(pv.w);
    }
    p0 = g_off_out[n]; p1 = g_off_out[n + 1];
    for (int p = p0 + grp; p < p1; p += 4) {
        int2 se = g_lst_out[p];
        float wvv = g_wbuf[(size_t)N_EDGES + se.y];
        uint4 pv = *(const uint4*)(g_XWx_b + (size_t)se.x * 256 + 128 + li * 8);
        acc[0] += wvv * bflo(pv.x);
        acc[1] += wvv * bfhi(pv.x);
        acc[2] += wvv * bflo(pv.y);
        acc[3] += wvv * bfhi(pv.y);
        acc[4] += wvv * bflo(pv.z);
        acc[5] += wvv * bfhi(pv.z);
        acc[6] += wvv * bflo(pv.w);
        acc[7] += wvv * bfhi(pv.w);
    }
    #pragma unroll
    for (int q = 0; q < 8; ++q) {
        acc[q] += __shfl_xor(acc[q], 16);
        acc[q] += __shfl_xor(acc[q], 32);
    }
    if (grp == 0) {
        uint4 pk;
        pk.x = ((unsigned int)f2bf(acc[1]) << 16) | (unsigned int)f2bf(acc[0]);
        pk.y = ((unsigned int)f2bf(acc[3]) << 16) | (unsigned int)f2bf(acc[2]);
        pk.z = ((unsigned int)f2bf(acc[5]) << 16) | (unsigned int)f2bf(acc[4]);
        pk.w = ((unsigned int)f2bf(acc[7]) << 16) | (unsigned int)f2bf(acc[6]);
        *(uint4*)(g_hb[cur ^ 1] + (size_t)n * 128 + li * 8) = pk;
    }
}

// ---------------- mean-pool partials (bf16 in, fp32 accumulate) ----------------
__global__ void pool_kernel(int fin, int side, const int* __restrict__ batch, int N) {
    const ushort_t* x = g_hb[fin];
    float* gsum = g_gsum[side];
    int n0 = blockIdx.x * 128;
    int d = threadIdx.x;  // 128 threads
    if (n0 >= N) return;
    int nend = min(n0 + 128, N);
    float acc = 0.f;
    int curg = batch[n0];
    for (int n = n0; n < nend; ++n) {
        int g = batch[n];
        if (g != curg) {
            atomicAdd(&gsum[curg * 128 + d], acc);
            acc = 0.f;
            curg = g;
        }
        acc += bf2f(x[(size_t)n * 128 + d]);
    }
    atomicAdd(&gsum[curg * 128 + d], acc);
}

__global__ void count_kernel(int side, const int* __restrict__ batch, int N) {
    int g = threadIdx.x;  // 128 threads
    int lo = 0, hi = N;
    while (lo < hi) { int mid = (lo + hi) >> 1; if (batch[mid] < g) lo = mid + 1; else hi = mid; }
    int a = lo;
    lo = 0; hi = N;
    while (lo < hi) { int mid = (lo + hi) >> 1; if (batch[mid] < g + 1) lo = mid + 1; else hi = mid; }
    g_cnt[side][g] = (float)(lo - a);
}

__global__ void zero_gsum_kernel() {
    int i = blockIdx.x * 256 + threadIdx.x;
    if (i < 2 * N_GRAPHS * NODE_DIM) ((float*)g_gsum)[i] = 0.f;
}

// ---------------- classifier ----------------
__global__ void hidden_kernel(const float* __restrict__ W0, const float* __restrict__ b0) {
    int g = blockIdx.x;
    int j = threadIdx.x;  // 128 x 128
    float inv_s = 1.0f / fmaxf(g_cnt[0][g], 1.0f);
    float inv_t = 1.0f / fmaxf(g_cnt[1][g], 1.0f);
    float acc = b0[j];
    for (int k = 0; k < 128; ++k) acc += g_gsum[0][g * 128 + k] * inv_s * W0[k * 128 + j];
    for (int k = 0; k < 128; ++k) acc += g_gsum[1][g * 128 + k] * inv_t * W0[(128 + k) * 128 + j];
    g_H[g * 128 + j] = fmaxf(acc, 0.f);
}

__global__ void loss_kernel(const float* __restrict__ W1, const float* __restrict__ b1,
                            const int* __restrict__ y, float* __restrict__ out) {
    int g = threadIdx.x;  // 128 threads
    float l0 = b1[0], l1 = b1[1];
    for (int j = 0; j < 128; ++j) {
        float hv = g_H[g * 128 + j];
        l0 += hv * W1[j * 2 + 0];
        l1 += hv * W1[j * 2 + 1];
    }
    float m = fmaxf(l0, l1);
    float lse = m + logf(expf(l0 - m) + expf(l1 - m));
    float ly = (y[g] == 0) ? l0 : l1;
    float c = -(ly - lse) * (1.0f / (float)N_GRAPHS);
    __shared__ float red[128];
    red[g] = c;
    __syncthreads();
    for (int s = 64; s; s >>= 1) {
        if (g < s) red[g] += red[g + s];
        __syncthreads();
    }
    if (g == 0) out[0] = red[0];
}

extern "C" void kernel_launch(void* const* d_in, const int* in_sizes, int n_in,
                              void* d_out, int out_size, void* d_ws, size_t ws_size,
                              hipStream_t stream) {
    const float* x_s      = (const float*)d_in[0];
    const float* x_t      = (const float*)d_in[1];
    const float* ea_s     = (const float*)d_in[2];
    const float* ea_t     = (const float*)d_in[3];
    const int*   ei_s     = (const int*)d_in[4];
    const int*   ei_t     = (const int*)d_in[5];
    const int*   batch_s  = (const int*)d_in[6];
    const int*   batch_t  = (const int*)d_in[7];
    const int*   y        = (const int*)d_in[8];
    const float* node_emb = (const float*)d_in[9];
    const float* edge_emb = (const float*)d_in[10];
    const float* W_in_0   = (const float*)d_in[11];
    const float* W_in_1   = (const float*)d_in[12];
    const float* W_out_0  = (const float*)d_in[13];
    const float* W_out_1  = (const float*)d_in[14];
    const float* Wg_in    = (const float*)d_in[15];
    const float* bg_in    = (const float*)d_in[16];
    const float* Wg_out   = (const float*)d_in[17];
    const float* bg_out   = (const float*)d_in[18];
    const float* cls_W0   = (const float*)d_in[19];
    const float* cls_b0   = (const float*)d_in[20];
    const float* cls_W1   = (const float*)d_in[21];
    const float* cls_b1   = (const float*)d_in[22];

    const int N = N_NODES, E = N_EDGES;
    static const unsigned int MASKS[3] = {MASK_J0, MASK_J1, MASK_J2};

    zero_gsum_kernel<<<(2 * N_GRAPHS * NODE_DIM + 255) / 256, 256, 0, stream>>>();
    setup_gates_kernel<<<1, 128, 0, stream>>>(W_in_0, W_in_1, W_out_0, W_out_1, edge_emb);

    for (int side = 0; side < 2; ++side) {
        const float* xin   = side ? x_t : x_s;
        const float* eain  = side ? ea_t : ea_s;
        const int*   ei    = side ? ei_t : ei_s;
        const int*   batch = side ? batch_t : batch_s;
        const int* row = ei;
        const int* col = ei + E;

        node_embed_kernel<<<(N + 3) / 4, 256, 0, stream>>>(xin, node_emb, N);
        edge_voc_kernel<<<(2 * E + 255) / 256, 256, 0, stream>>>(eain, 2 * E);

        // ---- CSR build (once per side; edge_index constant across layers) ----
        csr_zero_kernel<<<(N + 255) / 256, 256, 0, stream>>>();
        csr_count_kernel<<<(E + 255) / 256, 256, 0, stream>>>(row, col, E);
        csr_bsum_kernel<<<dim3(SCAN_NBLK, 2), 256, 0, stream>>>();
        csr_bscan_kernel<<<2, 64, 0, stream>>>();
        csr_off_kernel<<<dim3(SCAN_NBLK, 2), 256, 0, stream>>>(E);
        csr_fill_kernel<<<(E + 255) / 256, 256, 0, stream>>>(row, col, E);

        int cur = 0;
        for (int k = 0; k < K_LAYERS; ++k) {
            assemble_wcat<<<128, 256, 0, stream>>>(Wg_in + (size_t)k * 128 * 128,
                                                   Wg_out + (size_t)k * 128 * 128);
            gemm_xw_mfma<<<(N + 63) / 64, 320, 0, stream>>>(cur, k, MASKS[k], N);
            gate_kernel<<<(2 * E + 255) / 256, 256, 0, stream>>>(k, row, col, E);
            aggregate_kernel<<<(N + 3) / 4, 256, 0, stream>>>(
                cur, bg_in + (size_t)k * 128, bg_out + (size_t)k * 128, N);
            cur ^= 1;
        }
        pool_kernel<<<(N + 127) / 128, 128, 0, stream>>>(cur, side, batch, N);
        count_kernel<<<1, 128, 0, stream>>>(side, batch, N);
    }

    hidden_kernel<<<128, 128, 0, stream>>>(cls_W0, cls_b0);
    loss_kernel<<<1, 128, 0, stream>>>(cls_W1, cls_b1, y, (float*)d_out);
}

// Round 11
// 973.343 us; speedup vs baseline: 27.6535x; 1.1422x over previous
//
#include <hip/hip_runtime.h>
#include <hip/hip_bf16.h>

#define N_NODES 100000
#define N_EDGES 300000
#define N_GRAPHS 128
#define NODE_VOCAB 200
#define NODE_DIM 128
#define EDGE_DIM 64
#define K_LAYERS 3

#define SCAN_CHUNK 2048
#define SCAN_NBLK ((N_NODES + SCAN_CHUNK - 1) / SCAN_CHUNK)  // 49

typedef unsigned short ushort_t;
typedef __attribute__((ext_vector_type(8))) __bf16 bf16x8;
typedef __attribute__((ext_vector_type(4))) float f32x4;

__device__ inline ushort_t f2bf(float f) {
    unsigned int u = __float_as_uint(f);
    unsigned int r = (u + 0x7fff + ((u >> 16) & 1)) >> 16;
    return (ushort_t)r;
}
__device__ inline float bf2f(ushort_t u) {
    return __uint_as_float(((unsigned int)u) << 16);
}
__device__ inline float bflo(unsigned int u) { return __uint_as_float(u << 16); }
__device__ inline float bfhi(unsigned int u) { return __uint_as_float(u & 0xffff0000u); }

// scal row layout (32 fp32 = 128B = 2 sectors):
//   sector 0: A-in slots 0-7, A-out slots 8-15; sector 1: C-in 16-23, C-out 24-31.
//   within each 8-block: layer-k gate reads cols off(k)+j (j=0..k), off = {0,2,4} (16B-aligned).
//   layer j WRITES cols off(k)+j for k>=j  ->  j0:{0,2,4} j1:{3,5} j2:{6} per block:
#define MASK_J0 0x15151515u
#define MASK_J1 0x28282828u
#define MASK_J2 0x40404040u

// ---------------- static device scratch (no reliance on ws_size) ----------------
__device__ ushort_t g_hb[2][(size_t)N_NODES * NODE_DIM];  // bf16 ping-pong node state
__device__ ushort_t g_XWx_b[(size_t)N_NODES * 256];       // bf16 [xi | xo]
__device__ ushort_t g_WcatT[256 * 128];                   // Wcat^T bf16 [n][k] (xi|xo only)
__device__ ushort_t g_QT[K_LAYERS][32][128];              // gate-chain vectors, bf16
__device__ float g_scal[(size_t)N_NODES * 32];            // per-node gate scalars
__device__ float g_bias[8][6];                            // e0 vocab bias [t][dir*3+k]
__device__ int  g_evoc[2 * N_EDGES];                      // edge vocab index
__device__ float g_gsum[2][N_GRAPHS * NODE_DIM];
__device__ float g_cnt[2][N_GRAPHS];
__device__ float g_H[N_GRAPHS * NODE_DIM];
// CSR (rebuilt per side; constant across layers)
__device__ int  g_deg_in[N_NODES];
__device__ int  g_deg_out[N_NODES];
__device__ int  g_off_in[N_NODES + 1];
__device__ int  g_off_out[N_NODES + 1];
__device__ int  g_cur_in[N_NODES];
__device__ int  g_cur_out[N_NODES];
__device__ int2 g_lst_in[N_EDGES];   // (src=row, voc) keyed by col
__device__ int2 g_lst_out[N_EDGES];  // (src=col, voc) keyed by row
__device__ int  g_bsum[2][SCAN_NBLK];
__device__ int  g_boff[2][SCAN_NBLK];

// ---------------- node argmax + embed (bf16 state out) ----------------
__global__ void node_embed_kernel(const float* __restrict__ x, const float* __restrict__ emb,
                                  int N) {
    int wave = threadIdx.x >> 6;
    int lane = threadIdx.x & 63;
    int n = blockIdx.x * 4 + wave;
    if (n >= N) return;
    const float* xr = x + (size_t)n * NODE_VOCAB;
    float v = xr[lane];
    int idx = lane;
    float nv = xr[lane + 64];
    if (nv > v) { v = nv; idx = lane + 64; }
    nv = xr[lane + 128];
    if (nv > v) { v = nv; idx = lane + 128; }
    if (lane < NODE_VOCAB - 192) {
        nv = xr[lane + 192];
        if (nv > v) { v = nv; idx = lane + 192; }
    }
    #pragma unroll
    for (int off = 32; off; off >>= 1) {
        float ov = __shfl_xor(v, off);
        int oi = __shfl_xor(idx, off);
        if (ov > v || (ov == v && oi < idx)) { v = ov; idx = oi; }
    }
    const float* er = emb + (size_t)idx * NODE_DIM;
    g_hb[0][(size_t)n * NODE_DIM + lane] = f2bf(er[lane]);
    g_hb[0][(size_t)n * NODE_DIM + 64 + lane] = f2bf(er[64 + lane]);
}

// ---------------- edge argmax -> vocab index only ----------------
__global__ void edge_voc_kernel(const float* __restrict__ ea, int M) {
    long idx = (long)blockIdx.x * 256 + threadIdx.x;
    if (idx >= M) return;
    const float* ar = ea + idx * 8;
    float4 v0 = *(const float4*)ar;
    float4 v1 = *(const float4*)(ar + 4);
    float vals[8] = {v0.x, v0.y, v0.z, v0.w, v1.x, v1.y, v1.z, v1.w};
    int best = 0;
    float bv = vals[0];
    #pragma unroll
    for (int i = 1; i < 8; ++i)
        if (vals[i] > bv) { bv = vals[i]; best = i; }
    g_evoc[idx] = best;
}

// ---------------- zero QT ----------------
__global__ void zero_qt_kernel() {
    int i = blockIdx.x * 256 + threadIdx.x;
    if (i < K_LAYERS * 32 * 128) ((ushort_t*)g_QT)[i] = 0;
}

// ---------------- gate chain setup: 6 blocks = (dir, k) pairs ----------------
__global__ void setup_gates_kernel(const float* __restrict__ Wi0, const float* __restrict__ Wi1,
                                   const float* __restrict__ Wo0, const float* __restrict__ Wo1,
                                   const float* __restrict__ eemb) {
    int b = blockIdx.x;  // 0..5
    int D = b / 3, k = b % 3;
    int t = threadIdx.x;  // 128
    const float* W0 = D ? Wo0 : Wi0;
    const float* W1 = D ? Wo1 : Wi1;
    __shared__ float u[64], un[64];
    if (t < 64) u[t] = W1[k * 64 + t];
    __syncthreads();
    int offk = (k == 0) ? 0 : (k == 1 ? 2 : 4);
    for (int j = k; j >= 0; --j) {
        const float* Wj = W0 + (size_t)j * 320 * 64;
        float qa = 0.f, qc = 0.f;
        for (int m = 0; m < 64; ++m) {
            float um = u[m];
            qa += Wj[t * 64 + m] * um;
            qc += Wj[(192 + t) * 64 + m] * um;
        }
        g_QT[j][(D ? 8 : 0) + offk + j][t] = f2bf(qa);
        g_QT[j][(D ? 24 : 16) + offk + j][t] = f2bf(qc);
        float s = 0.f;
        if (t < 64) {
            for (int m = 0; m < 64; ++m) s += Wj[(128 + t) * 64 + m] * u[m];
        }
        __syncthreads();
        if (t < 64) un[t] = s;
        __syncthreads();
        if (t < 64) u[t] = un[t];
        __syncthreads();
    }
    if (t < 8) {
        float s = 0.f;
        for (int m = 0; m < 64; ++m) s += eemb[t * 64 + m] * u[m];
        g_bias[t][D * 3 + k] = s;
    }
}

// ---------------- CSR build ----------------
__global__ void csr_zero_kernel() {
    int i = blockIdx.x * 256 + threadIdx.x;
    if (i < N_NODES) { g_deg_in[i] = 0; g_deg_out[i] = 0; }
}

__global__ void csr_count_kernel(const int* __restrict__ row, const int* __restrict__ col,
                                 int E) {
    int e = blockIdx.x * 256 + threadIdx.x;
    if (e >= E) return;
    atomicAdd(&g_deg_in[col[e]], 1);
    atomicAdd(&g_deg_out[row[e]], 1);
}

__global__ void csr_bsum_kernel() {
    int which = blockIdx.y;
    const int* deg = which ? g_deg_out : g_deg_in;
    int b = blockIdx.x;
    int t = threadIdx.x;
    int base = b * SCAN_CHUNK;
    int s = 0;
    #pragma unroll
    for (int i = 0; i < SCAN_CHUNK / 256; ++i) {
        int idx = base + i * 256 + t;
        if (idx < N_NODES) s += deg[idx];
    }
    __shared__ int red[256];
    red[t] = s;
    __syncthreads();
    for (int d = 128; d; d >>= 1) {
        if (t < d) red[t] += red[t + d];
        __syncthreads();
    }
    if (t == 0) g_bsum[which][b] = red[0];
}

__global__ void csr_bscan_kernel() {
    int which = blockIdx.x;
    int t = threadIdx.x;  // 64 threads
    int v = (t < SCAN_NBLK) ? g_bsum[which][t] : 0;
    int orig = v;
    #pragma unroll
    for (int d = 1; d < 64; d <<= 1) {
        int u = __shfl_up(v, d, 64);
        if (t >= d) v += u;
    }
    if (t < SCAN_NBLK) g_boff[which][t] = v - orig;
}

__global__ void csr_off_kernel(int total) {
    int which = blockIdx.y;
    const int* deg = which ? g_deg_out : g_deg_in;
    int* off = which ? g_off_out : g_off_in;
    int* cur = which ? g_cur_out : g_cur_in;
    int b = blockIdx.x;
    int t = threadIdx.x;
    const int per = SCAN_CHUNK / 256;  // 8
    int lo = b * SCAN_CHUNK + t * per;
    int d8[per];
    int s = 0;
    #pragma unroll
    for (int i = 0; i < per; ++i) {
        int idx = lo + i;
        d8[i] = (idx < N_NODES) ? deg[idx] : 0;
        s += d8[i];
    }
    __shared__ int part[256];
    part[t] = s;
    __syncthreads();
    for (int d = 1; d < 256; d <<= 1) {
        int add = (t >= d) ? part[t - d] : 0;
        __syncthreads();
        part[t] += add;
        __syncthreads();
    }
    int run = g_boff[which][b] + part[t] - s;
    #pragma unroll
    for (int i = 0; i < per; ++i) {
        int idx = lo + i;
        if (idx < N_NODES) {
            off[idx] = run;
            cur[idx] = run;
            run += d8[i];
        }
    }
    if (b == 0 && t == 0) off[N_NODES] = total;
}

// fill lists with (src, voc) — voc pre-gathered so aggregate avoids the evoc hop
__global__ void csr_fill_kernel(const int* __restrict__ row, const int* __restrict__ col,
                                int E) {
    int e = blockIdx.x * 256 + threadIdx.x;
    if (e >= E) return;
    int r = row[e], c = col[e];
    int p = atomicAdd(&g_cur_in[c], 1);
    g_lst_in[p] = make_int2(r, g_evoc[e]);
    int q = atomicAdd(&g_cur_out[r], 1);
    g_lst_out[q] = make_int2(c, g_evoc[E + e]);
}

// ---------------- assemble Wcat^T (256 x 128, bf16): [xi | xo] ----------------
__global__ void assemble_wcat(const float* __restrict__ Wgi, const float* __restrict__ Wgo) {
    int idx = blockIdx.x * 256 + threadIdx.x;  // 32768
    int n = idx >> 7;
    int kd = idx & 127;
    float v = (n < 128) ? Wgi[kd * 128 + n] : Wgo[kd * 128 + (n - 128)];
    g_WcatT[n * 128 + kd] = f2bf(v);
}

// ---- fused node GEMM via MFMA: XWx(bf16) = x@Wcat (waves 0-3), scal = x@QT^T (wave 4) ----
// 320 threads = 5 waves; grid ceil(M/64)
__global__ __launch_bounds__(320) void gemm_xw_mfma(int cur, int layer, unsigned int mask,
                                                    int M) {
    const ushort_t* __restrict__ hb = g_hb[cur];
    int m0 = blockIdx.x * 64;
    int t = threadIdx.x;
    int wave = t >> 6, lane = t & 63;
    __shared__ ushort_t As[64 * 128];  // 16 KB, XOR-swizzled: elem k ^= (row&7)<<3

    for (int idx = t; idx < 1024; idx += 320) {
        int m = idx >> 4, c = idx & 15;  // row, 16B-chunk (8 elems)
        int gm = m0 + m;
        uint4 v = make_uint4(0u, 0u, 0u, 0u);
        if (gm < M) v = *(const uint4*)(hb + (size_t)gm * 128 + c * 8);
        *(uint4*)&As[m * 128 + ((c * 8) ^ ((m & 7) << 3))] = v;
    }
    __syncthreads();

    int lr = lane & 15, lk = lane >> 4;

    if (wave < 4) {
        int nbase = wave * 64;
        f32x4 acc[4][4];
        #pragma unroll
        for (int i = 0; i < 4; ++i)
            #pragma unroll
            for (int j = 0; j < 4; ++j)
                acc[i][j] = (f32x4){0.f, 0.f, 0.f, 0.f};

        const ushort_t* Bbase = g_WcatT + (size_t)nbase * 128;
        #pragma unroll
        for (int ks = 0; ks < 4; ++ks) {
            bf16x8 a[4], b[4];
            int ke = ks * 32 + lk * 8;
            #pragma unroll
            for (int mt = 0; mt < 4; ++mt) {
                int row = mt * 16 + lr;
                a[mt] = *(const bf16x8*)&As[row * 128 + (ke ^ ((row & 7) << 3))];
            }
            #pragma unroll
            for (int nt = 0; nt < 4; ++nt) {
                b[nt] = *(const bf16x8*)(Bbase + (size_t)(nt * 16 + lr) * 128 + ke);
            }
            #pragma unroll
            for (int mt = 0; mt < 4; ++mt)
                #pragma unroll
                for (int nt = 0; nt < 4; ++nt)
                    acc[mt][nt] = __builtin_amdgcn_mfma_f32_16x16x32_bf16(a[mt], b[nt], acc[mt][nt], 0, 0, 0);
        }

        #pragma unroll
        for (int mt = 0; mt < 4; ++mt) {
            #pragma unroll
            for (int r = 0; r < 4; ++r) {
                int gm = m0 + mt * 16 + lk * 4 + r;
                if (gm >= M) continue;
                #pragma unroll
                for (int nt = 0; nt < 4; ++nt) {
                    int n = nbase + nt * 16 + lr;
                    g_XWx_b[(size_t)gm * 256 + n] = f2bf(acc[mt][nt][r]);
                }
            }
        }
    } else {
        const ushort_t* QT = &g_QT[layer][0][0];
        f32x4 acc[4][2];
        #pragma unroll
        for (int i = 0; i < 4; ++i)
            #pragma unroll
            for (int j = 0; j < 2; ++j)
                acc[i][j] = (f32x4){0.f, 0.f, 0.f, 0.f};

        #pragma unroll
        for (int ks = 0; ks < 4; ++ks) {
            bf16x8 a[4], b[2];
            int ke = ks * 32 + lk * 8;
            #pragma unroll
            for (int mt = 0; mt < 4; ++mt) {
                int row = mt * 16 + lr;
                a[mt] = *(const bf16x8*)&As[row * 128 + (ke ^ ((row & 7) << 3))];
            }
            #pragma unroll
            for (int nt = 0; nt < 2; ++nt)
                b[nt] = *(const bf16x8*)&QT[(nt * 16 + lr) * 128 + ke];
            #pragma unroll
            for (int mt = 0; mt < 4; ++mt)
                #pragma unroll
                for (int nt = 0; nt < 2; ++nt)
                    acc[mt][nt] = __builtin_amdgcn_mfma_f32_16x16x32_bf16(a[mt], b[nt], acc[mt][nt], 0, 0, 0);
        }

        #pragma unroll
        for (int mt = 0; mt < 4; ++mt)
            #pragma unroll
            for (int r = 0; r < 4; ++r) {
                int gm = m0 + mt * 16 + lk * 4 + r;
                if (gm >= M) continue;
                #pragma unroll
                for (int nt = 0; nt < 2; ++nt) {
                    int colc = nt * 16 + lr;
                    if ((mask >> colc) & 1u)
                        g_scal[(size_t)gm * 32 + colc] = acc[mt][nt][r];
                }
            }
    }
}

// ------- fused aggregate + inline gate, 4x16-lane gather groups -------
// x_next(bf16) = x + b + sum_in sigmoid(gate)*xi[src] + sum_out sigmoid(gate)*xo[src]
__global__ __launch_bounds__(256) void aggregate_kernel(int cur, int k,
                                                        const float* __restrict__ bgi,
                                                        const float* __restrict__ bgo, int N) {
    int wv = threadIdx.x >> 6;
    int lane = threadIdx.x & 63;
    int grp = lane >> 4, li = lane & 15;
    int n = blockIdx.x * 4 + wv;
    if (n >= N) return;
    // bias shuffle registers: lane l holds bias[l&7][dir*3+k]
    float bias_in = g_bias[lane & 7][k];
    float bias_out = g_bias[lane & 7][3 + k];
    // C-sums for this node (read once)
    const float* srow = g_scal + (size_t)n * 32;
    float cin, cout;
    if (k == 0) {
        cin = srow[16]; cout = srow[24];
    } else if (k == 1) {
        float2 a = *(const float2*)(srow + 18);
        float2 b = *(const float2*)(srow + 26);
        cin = a.x + a.y; cout = b.x + b.y;
    } else {
        float4 a = *(const float4*)(srow + 20);
        float4 b = *(const float4*)(srow + 28);
        cin = a.x + a.y + a.z; cout = b.x + b.y + b.z;
    }
    float acc[8];
    if (grp == 0) {
        uint4 xv = *(const uint4*)(g_hb[cur] + (size_t)n * 128 + li * 8);
        float4 b1 = *(const float4*)(bgi + li * 8);
        float4 b2 = *(const float4*)(bgi + li * 8 + 4);
        float4 c1 = *(const float4*)(bgo + li * 8);
        float4 c2 = *(const float4*)(bgo + li * 8 + 4);
        acc[0] = bflo(xv.x) + b1.x + c1.x;
        acc[1] = bfhi(xv.x) + b1.y + c1.y;
        acc[2] = bflo(xv.y) + b1.z + c1.z;
        acc[3] = bfhi(xv.y) + b1.w + c1.w;
        acc[4] = bflo(xv.z) + b2.x + c2.x;
        acc[5] = bfhi(xv.z) + b2.y + c2.y;
        acc[6] = bflo(xv.w) + b2.z + c2.z;
        acc[7] = bfhi(xv.w) + b2.w + c2.w;
    } else {
        #pragma unroll
        for (int q = 0; q < 8; ++q) acc[q] = 0.f;
    }
    int p0 = g_off_in[n], p1 = g_off_in[n + 1];
    for (int p = p0 + grp; p < p1; p += 4) {
        int2 se = g_lst_in[p];
        const float* arow = g_scal + (size_t)se.x * 32;
        float asum;
        if (k == 0) asum = arow[0];
        else if (k == 1) { float2 t2 = *(const float2*)(arow + 2); asum = t2.x + t2.y; }
        else { float4 t4 = *(const float4*)(arow + 4); asum = t4.x + t4.y + t4.z; }
        float s = __shfl(bias_in, se.y) + asum + cin;
        float wvv = 1.0f / (1.0f + __expf(-s));
        uint4 pv = *(const uint4*)(g_XWx_b + (size_t)se.x * 256 + li * 8);
        acc[0] += wvv * bflo(pv.x);
        acc[1] += wvv * bfhi(pv.x);
        acc[2] += wvv * bflo(pv.y);
        acc[3] += wvv * bfhi(pv.y);
        acc[4] += wvv * bflo(pv.z);
        acc[5] += wvv * bfhi(pv.z);
        acc[6] += wvv * bflo(pv.w);
        acc[7] += wvv * bfhi(pv.w);
    }
    p0 = g_off_out[n]; p1 = g_off_out[n + 1];
    for (int p = p0 + grp; p < p1; p += 4) {
        int2 se = g_lst_out[p];
        const float* arow = g_scal + (size_t)se.x * 32;
        float asum;
        if (k == 0) asum = arow[8];
        else if (k == 1) { float2 t2 = *(const float2*)(arow + 10); asum = t2.x + t2.y; }
        else { float4 t4 = *(const float4*)(arow + 12); asum = t4.x + t4.y + t4.z; }
        float s = __shfl(bias_out, se.y) + asum + cout;
        float wvv = 1.0f / (1.0f + __expf(-s));
        uint4 pv = *(const uint4*)(g_XWx_b + (size_t)se.x * 256 + 128 + li * 8);
        acc[0] += wvv * bflo(pv.x);
        acc[1] += wvv * bfhi(pv.x);
        acc[2] += wvv * bflo(pv.y);
        acc[3] += wvv * bfhi(pv.y);
        acc[4] += wvv * bflo(pv.z);
        acc[5] += wvv * bfhi(pv.z);
        acc[6] += wvv * bflo(pv.w);
        acc[7] += wvv * bfhi(pv.w);
    }
    #pragma unroll
    for (int q = 0; q < 8; ++q) {
        acc[q] += __shfl_xor(acc[q], 16);
        acc[q] += __shfl_xor(acc[q], 32);
    }
    if (grp == 0) {
        uint4 pk;
        pk.x = ((unsigned int)f2bf(acc[1]) << 16) | (unsigned int)f2bf(acc[0]);
        pk.y = ((unsigned int)f2bf(acc[3]) << 16) | (unsigned int)f2bf(acc[2]);
        pk.z = ((unsigned int)f2bf(acc[5]) << 16) | (unsigned int)f2bf(acc[4]);
        pk.w = ((unsigned int)f2bf(acc[7]) << 16) | (unsigned int)f2bf(acc[6]);
        *(uint4*)(g_hb[cur ^ 1] + (size_t)n * 128 + li * 8) = pk;
    }
}

// ---------------- mean-pool partials (bf16 in, fp32 accumulate) ----------------
__global__ void pool_kernel(int fin, int side, const int* __restrict__ batch, int N) {
    const ushort_t* x = g_hb[fin];
    float* gsum = g_gsum[side];
    int n0 = blockIdx.x * 128;
    int d = threadIdx.x;  // 128 threads
    if (n0 >= N) return;
    int nend = min(n0 + 128, N);
    float acc = 0.f;
    int curg = batch[n0];
    for (int n = n0; n < nend; ++n) {
        int g = batch[n];
        if (g != curg) {
            atomicAdd(&gsum[curg * 128 + d], acc);
            acc = 0.f;
            curg = g;
        }
        acc += bf2f(x[(size_t)n * 128 + d]);
    }
    atomicAdd(&gsum[curg * 128 + d], acc);
}

__global__ void count_kernel(int side, const int* __restrict__ batch, int N) {
    int g = threadIdx.x;  // 128 threads
    int lo = 0, hi = N;
    while (lo < hi) { int mid = (lo + hi) >> 1; if (batch[mid] < g) lo = mid + 1; else hi = mid; }
    int a = lo;
    lo = 0; hi = N;
    while (lo < hi) { int mid = (lo + hi) >> 1; if (batch[mid] < g + 1) lo = mid + 1; else hi = mid; }
    g_cnt[side][g] = (float)(lo - a);
}

__global__ void zero_gsum_kernel() {
    int i = blockIdx.x * 256 + threadIdx.x;
    if (i < 2 * N_GRAPHS * NODE_DIM) ((float*)g_gsum)[i] = 0.f;
}

// ---------------- classifier ----------------
__global__ void hidden_kernel(const float* __restrict__ W0, const float* __restrict__ b0) {
    int g = blockIdx.x;
    int j = threadIdx.x;  // 128 x 128
    float inv_s = 1.0f / fmaxf(g_cnt[0][g], 1.0f);
    float inv_t = 1.0f / fmaxf(g_cnt[1][g], 1.0f);
    float acc = b0[j];
    for (int k = 0; k < 128; ++k) acc += g_gsum[0][g * 128 + k] * inv_s * W0[k * 128 + j];
    for (int k = 0; k < 128; ++k) acc += g_gsum[1][g * 128 + k] * inv_t * W0[(128 + k) * 128 + j];
    g_H[g * 128 + j] = fmaxf(acc, 0.f);
}

__global__ void loss_kernel(const float* __restrict__ W1, const float* __restrict__ b1,
                            const int* __restrict__ y, float* __restrict__ out) {
    int g = threadIdx.x;  // 128 threads
    float l0 = b1[0], l1 = b1[1];
    for (int j = 0; j < 128; ++j) {
        float hv = g_H[g * 128 + j];
        l0 += hv * W1[j * 2 + 0];
        l1 += hv * W1[j * 2 + 1];
    }
    float m = fmaxf(l0, l1);
    float lse = m + logf(expf(l0 - m) + expf(l1 - m));
    float ly = (y[g] == 0) ? l0 : l1;
    float c = -(ly - lse) * (1.0f / (float)N_GRAPHS);
    __shared__ float red[128];
    red[g] = c;
    __syncthreads();
    for (int s = 64; s; s >>= 1) {
        if (g < s) red[g] += red[g + s];
        __syncthreads();
    }
    if (g == 0) out[0] = red[0];
}

extern "C" void kernel_launch(void* const* d_in, const int* in_sizes, int n_in,
                              void* d_out, int out_size, void* d_ws, size_t ws_size,
                              hipStream_t stream) {
    const float* x_s      = (const float*)d_in[0];
    const float* x_t      = (const float*)d_in[1];
    const float* ea_s     = (const float*)d_in[2];
    const float* ea_t     = (const float*)d_in[3];
    const int*   ei_s     = (const int*)d_in[4];
    const int*   ei_t     = (const int*)d_in[5];
    const int*   batch_s  = (const int*)d_in[6];
    const int*   batch_t  = (const int*)d_in[7];
    const int*   y        = (const int*)d_in[8];
    const float* node_emb = (const float*)d_in[9];
    const float* edge_emb = (const float*)d_in[10];
    const float* W_in_0   = (const float*)d_in[11];
    const float* W_in_1   = (const float*)d_in[12];
    const float* W_out_0  = (const float*)d_in[13];
    const float* W_out_1  = (const float*)d_in[14];
    const float* Wg_in    = (const float*)d_in[15];
    const float* bg_in    = (const float*)d_in[16];
    const float* Wg_out   = (const float*)d_in[17];
    const float* bg_out   = (const float*)d_in[18];
    const float* cls_W0   = (const float*)d_in[19];
    const float* cls_b0   = (const float*)d_in[20];
    const float* cls_W1   = (const float*)d_in[21];
    const float* cls_b1   = (const float*)d_in[22];

    const int N = N_NODES, E = N_EDGES;
    static const unsigned int MASKS[3] = {MASK_J0, MASK_J1, MASK_J2};

    zero_gsum_kernel<<<(2 * N_GRAPHS * NODE_DIM + 255) / 256, 256, 0, stream>>>();
    zero_qt_kernel<<<(K_LAYERS * 32 * 128 + 255) / 256, 256, 0, stream>>>();
    setup_gates_kernel<<<6, 128, 0, stream>>>(W_in_0, W_in_1, W_out_0, W_out_1, edge_emb);

    for (int side = 0; side < 2; ++side) {
        const float* xin   = side ? x_t : x_s;
        const float* eain  = side ? ea_t : ea_s;
        const int*   ei    = side ? ei_t : ei_s;
        const int*   batch = side ? batch_t : batch_s;
        const int* row = ei;
        const int* col = ei + E;

        node_embed_kernel<<<(N + 3) / 4, 256, 0, stream>>>(xin, node_emb, N);
        edge_voc_kernel<<<(2 * E + 255) / 256, 256, 0, stream>>>(eain, 2 * E);

        // ---- CSR build (once per side; edge_index constant across layers) ----
        csr_zero_kernel<<<(N + 255) / 256, 256, 0, stream>>>();
        csr_count_kernel<<<(E + 255) / 256, 256, 0, stream>>>(row, col, E);
        csr_bsum_kernel<<<dim3(SCAN_NBLK, 2), 256, 0, stream>>>();
        csr_bscan_kernel<<<2, 64, 0, stream>>>();
        csr_off_kernel<<<dim3(SCAN_NBLK, 2), 256, 0, stream>>>(E);
        csr_fill_kernel<<<(E + 255) / 256, 256, 0, stream>>>(row, col, E);

        int cur = 0;
        for (int k = 0; k < K_LAYERS; ++k) {
            assemble_wcat<<<128, 256, 0, stream>>>(Wg_in + (size_t)k * 128 * 128,
                                                   Wg_out + (size_t)k * 128 * 128);
            gemm_xw_mfma<<<(N + 63) / 64, 320, 0, stream>>>(cur, k, MASKS[k], N);
            aggregate_kernel<<<(N + 3) / 4, 256, 0, stream>>>(
                cur, k, bg_in + (size_t)k * 128, bg_out + (size_t)k * 128, N);
            cur ^= 1;
        }
        pool_kernel<<<(N + 127) / 128, 128, 0, stream>>>(cur, side, batch, N);
        count_kernel<<<1, 128, 0, stream>>>(side, batch, N);
    }

    hidden_kernel<<<128, 128, 0, stream>>>(cls_W0, cls_b0);
    loss_kernel<<<1, 128, 0, stream>>>(cls_W1, cls_b1, y, (float*)d_out);
}

// Round 12
// 922.403 us; speedup vs baseline: 29.1807x; 1.0552x over previous
//
#include <hip/hip_runtime.h>
#include <hip/hip_bf16.h>

#define N_NODES 100000
#define N_EDGES 300000
#define N_GRAPHS 128
#define NODE_VOCAB 200
#define NODE_DIM 128
#define EDGE_DIM 64
#define K_LAYERS 3

#define SCAN_CHUNK 2048
#define SCAN_NBLK ((N_NODES + SCAN_CHUNK - 1) / SCAN_CHUNK)  // 49

typedef unsigned short ushort_t;
typedef __attribute__((ext_vector_type(8))) __bf16 bf16x8;
typedef __attribute__((ext_vector_type(4))) float f32x4;

__device__ inline ushort_t f2bf(float f) {
    unsigned int u = __float_as_uint(f);
    unsigned int r = (u + 0x7fff + ((u >> 16) & 1)) >> 16;
    return (ushort_t)r;
}
__device__ inline float bf2f(ushort_t u) {
    return __uint_as_float(((unsigned int)u) << 16);
}
__device__ inline float bflo(unsigned int u) { return __uint_as_float(u << 16); }
__device__ inline float bfhi(unsigned int u) { return __uint_as_float(u & 0xffff0000u); }

// scal row layout (32 fp32 = 128B):
//   A-in slots 0-7, A-out 8-15, C-in 16-23, C-out 24-31.
//   within each 8-block: layer-k gate reads cols off(k)+j (j=0..k), off = {0,2,4}.
//   layer j WRITES cols off(k)+j for k>=j  ->  j0:{0,2,4} j1:{3,5} j2:{6} per block:
#define MASK_J0 0x15151515u
#define MASK_J1 0x28282828u
#define MASK_J2 0x40404040u

// ---------------- static device scratch (no reliance on ws_size) ----------------
__device__ ushort_t g_hb[2][(size_t)N_NODES * NODE_DIM];  // bf16 ping-pong node state
__device__ ushort_t g_XWx_b[(size_t)N_NODES * 256];       // bf16 [xi | xo]
__device__ ushort_t g_WcatT[256 * 128];                   // Wcat^T bf16 [n][k] (xi|xo only)
__device__ ushort_t g_QT[K_LAYERS][32][128];              // gate-chain vectors, bf16
__device__ float g_scal[(size_t)N_NODES * 32];            // per-node gate scalars
__device__ float g_bias[8][6];                            // e0 vocab bias [t][dir*3+k]
__device__ int  g_evoc[2 * N_EDGES];                      // edge vocab index
__device__ float g_gsum[2][N_GRAPHS * NODE_DIM];
__device__ float g_cnt[2][N_GRAPHS];
__device__ float g_H[N_GRAPHS * NODE_DIM];
// CSR (rebuilt per side; constant across layers)
__device__ int  g_deg_in[N_NODES];
__device__ int  g_deg_out[N_NODES];
__device__ int  g_off_in[N_NODES + 1];
__device__ int  g_off_out[N_NODES + 1];
__device__ int  g_cur_in[N_NODES];
__device__ int  g_cur_out[N_NODES];
__device__ int2 g_lst_in[N_EDGES];   // (src=row, voc) keyed by col
__device__ int2 g_lst_out[N_EDGES];  // (src=col, voc) keyed by row
__device__ int  g_bsum[2][SCAN_NBLK];
__device__ int  g_boff[2][SCAN_NBLK];

// ---------------- node argmax + embed (bf16 state out) ----------------
__global__ void node_embed_kernel(const float* __restrict__ x, const float* __restrict__ emb,
                                  int N) {
    int wave = threadIdx.x >> 6;
    int lane = threadIdx.x & 63;
    int n = blockIdx.x * 4 + wave;
    if (n >= N) return;
    const float* xr = x + (size_t)n * NODE_VOCAB;
    float v = xr[lane];
    int idx = lane;
    float nv = xr[lane + 64];
    if (nv > v) { v = nv; idx = lane + 64; }
    nv = xr[lane + 128];
    if (nv > v) { v = nv; idx = lane + 128; }
    if (lane < NODE_VOCAB - 192) {
        nv = xr[lane + 192];
        if (nv > v) { v = nv; idx = lane + 192; }
    }
    #pragma unroll
    for (int off = 32; off; off >>= 1) {
        float ov = __shfl_xor(v, off);
        int oi = __shfl_xor(idx, off);
        if (ov > v || (ov == v && oi < idx)) { v = ov; idx = oi; }
    }
    const float* er = emb + (size_t)idx * NODE_DIM;
    g_hb[0][(size_t)n * NODE_DIM + lane] = f2bf(er[lane]);
    g_hb[0][(size_t)n * NODE_DIM + 64 + lane] = f2bf(er[64 + lane]);
}

// ---------------- edge argmax -> vocab index only ----------------
__global__ void edge_voc_kernel(const float* __restrict__ ea, int M) {
    long idx = (long)blockIdx.x * 256 + threadIdx.x;
    if (idx >= M) return;
    const float* ar = ea + idx * 8;
    float4 v0 = *(const float4*)ar;
    float4 v1 = *(const float4*)(ar + 4);
    float vals[8] = {v0.x, v0.y, v0.z, v0.w, v1.x, v1.y, v1.z, v1.w};
    int best = 0;
    float bv = vals[0];
    #pragma unroll
    for (int i = 1; i < 8; ++i)
        if (vals[i] > bv) { bv = vals[i]; best = i; }
    g_evoc[idx] = best;
}

// ---------------- zero QT ----------------
__global__ void zero_qt_kernel() {
    int i = blockIdx.x * 256 + threadIdx.x;
    if (i < K_LAYERS * 32 * 128) ((ushort_t*)g_QT)[i] = 0;
}

// ---------------- gate chain setup: 6 blocks = (dir, k) pairs ----------------
__global__ void setup_gates_kernel(const float* __restrict__ Wi0, const float* __restrict__ Wi1,
                                   const float* __restrict__ Wo0, const float* __restrict__ Wo1,
                                   const float* __restrict__ eemb) {
    int b = blockIdx.x;  // 0..5
    int D = b / 3, k = b % 3;
    int t = threadIdx.x;  // 128
    const float* W0 = D ? Wo0 : Wi0;
    const float* W1 = D ? Wo1 : Wi1;
    __shared__ float u[64], un[64];
    if (t < 64) u[t] = W1[k * 64 + t];
    __syncthreads();
    int offk = (k == 0) ? 0 : (k == 1 ? 2 : 4);
    for (int j = k; j >= 0; --j) {
        const float* Wj = W0 + (size_t)j * 320 * 64;
        float qa = 0.f, qc = 0.f;
        for (int m = 0; m < 64; ++m) {
            float um = u[m];
            qa += Wj[t * 64 + m] * um;
            qc += Wj[(192 + t) * 64 + m] * um;
        }
        g_QT[j][(D ? 8 : 0) + offk + j][t] = f2bf(qa);
        g_QT[j][(D ? 24 : 16) + offk + j][t] = f2bf(qc);
        float s = 0.f;
        if (t < 64) {
            for (int m = 0; m < 64; ++m) s += Wj[(128 + t) * 64 + m] * u[m];
        }
        __syncthreads();
        if (t < 64) un[t] = s;
        __syncthreads();
        if (t < 64) u[t] = un[t];
        __syncthreads();
    }
    if (t < 8) {
        float s = 0.f;
        for (int m = 0; m < 64; ++m) s += eemb[t * 64 + m] * u[m];
        g_bias[t][D * 3 + k] = s;
    }
}

// ---------------- CSR build ----------------
__global__ void csr_zero_kernel() {
    int i = blockIdx.x * 256 + threadIdx.x;
    if (i < N_NODES) { g_deg_in[i] = 0; g_deg_out[i] = 0; }
}

__global__ void csr_count_kernel(const int* __restrict__ row, const int* __restrict__ col,
                                 int E) {
    int e = blockIdx.x * 256 + threadIdx.x;
    if (e >= E) return;
    atomicAdd(&g_deg_in[col[e]], 1);
    atomicAdd(&g_deg_out[row[e]], 1);
}

__global__ void csr_bsum_kernel() {
    int which = blockIdx.y;
    const int* deg = which ? g_deg_out : g_deg_in;
    int b = blockIdx.x;
    int t = threadIdx.x;
    int base = b * SCAN_CHUNK;
    int s = 0;
    #pragma unroll
    for (int i = 0; i < SCAN_CHUNK / 256; ++i) {
        int idx = base + i * 256 + t;
        if (idx < N_NODES) s += deg[idx];
    }
    __shared__ int red[256];
    red[t] = s;
    __syncthreads();
    for (int d = 128; d; d >>= 1) {
        if (t < d) red[t] += red[t + d];
        __syncthreads();
    }
    if (t == 0) g_bsum[which][b] = red[0];
}

__global__ void csr_bscan_kernel() {
    int which = blockIdx.x;
    int t = threadIdx.x;  // 64 threads
    int v = (t < SCAN_NBLK) ? g_bsum[which][t] : 0;
    int orig = v;
    #pragma unroll
    for (int d = 1; d < 64; d <<= 1) {
        int u = __shfl_up(v, d, 64);
        if (t >= d) v += u;
    }
    if (t < SCAN_NBLK) g_boff[which][t] = v - orig;
}

__global__ void csr_off_kernel(int total) {
    int which = blockIdx.y;
    const int* deg = which ? g_deg_out : g_deg_in;
    int* off = which ? g_off_out : g_off_in;
    int* cur = which ? g_cur_out : g_cur_in;
    int b = blockIdx.x;
    int t = threadIdx.x;
    const int per = SCAN_CHUNK / 256;  // 8
    int lo = b * SCAN_CHUNK + t * per;
    int d8[per];
    int s = 0;
    #pragma unroll
    for (int i = 0; i < per; ++i) {
        int idx = lo + i;
        d8[i] = (idx < N_NODES) ? deg[idx] : 0;
        s += d8[i];
    }
    __shared__ int part[256];
    part[t] = s;
    __syncthreads();
    for (int d = 1; d < 256; d <<= 1) {
        int add = (t >= d) ? part[t - d] : 0;
        __syncthreads();
        part[t] += add;
        __syncthreads();
    }
    int run = g_boff[which][b] + part[t] - s;
    #pragma unroll
    for (int i = 0; i < per; ++i) {
        int idx = lo + i;
        if (idx < N_NODES) {
            off[idx] = run;
            cur[idx] = run;
            run += d8[i];
        }
    }
    if (b == 0 && t == 0) off[N_NODES] = total;
}

// fill lists with (src, voc)
__global__ void csr_fill_kernel(const int* __restrict__ row, const int* __restrict__ col,
                                int E) {
    int e = blockIdx.x * 256 + threadIdx.x;
    if (e >= E) return;
    int r = row[e], c = col[e];
    int p = atomicAdd(&g_cur_in[c], 1);
    g_lst_in[p] = make_int2(r, g_evoc[e]);
    int q = atomicAdd(&g_cur_out[r], 1);
    g_lst_out[q] = make_int2(c, g_evoc[E + e]);
}

// ---------------- assemble Wcat^T (256 x 128, bf16): [xi | xo] ----------------
__global__ void assemble_wcat(const float* __restrict__ Wgi, const float* __restrict__ Wgo) {
    int idx = blockIdx.x * 256 + threadIdx.x;  // 32768
    int n = idx >> 7;
    int kd = idx & 127;
    float v = (n < 128) ? Wgi[kd * 128 + n] : Wgo[kd * 128 + (n - 128)];
    g_WcatT[n * 128 + kd] = f2bf(v);
}

// ---- fused node GEMM via MFMA (swapped operands: D[n][m], lane holds 4 consecutive cols) ----
// XWx(bf16) = x@Wcat (waves 0-3), scal = x@QT^T (wave 4). 320 threads; grid ceil(M/64)
__global__ __launch_bounds__(320) void gemm_xw_mfma(int cur, int layer, unsigned int mask,
                                                    int M) {
    const ushort_t* __restrict__ hb = g_hb[cur];
    int m0 = blockIdx.x * 64;
    int t = threadIdx.x;
    int wave = t >> 6, lane = t & 63;
    __shared__ ushort_t As[64 * 128];  // 16 KB, XOR-swizzled: elem k ^= (row&7)<<3

    for (int idx = t; idx < 1024; idx += 320) {
        int m = idx >> 4, c = idx & 15;  // row, 16B-chunk (8 elems)
        int gm = m0 + m;
        uint4 v = make_uint4(0u, 0u, 0u, 0u);
        if (gm < M) v = *(const uint4*)(hb + (size_t)gm * 128 + c * 8);
        *(uint4*)&As[m * 128 + ((c * 8) ^ ((m & 7) << 3))] = v;
    }
    __syncthreads();

    int lr = lane & 15, lk = lane >> 4;

    if (wave < 4) {
        int nbase = wave * 64;
        f32x4 acc[4][4];  // [nt][mt], D[n][m]
        #pragma unroll
        for (int i = 0; i < 4; ++i)
            #pragma unroll
            for (int j = 0; j < 4; ++j)
                acc[i][j] = (f32x4){0.f, 0.f, 0.f, 0.f};

        const ushort_t* Bbase = g_WcatT + (size_t)nbase * 128;
        #pragma unroll
        for (int ks = 0; ks < 4; ++ks) {
            bf16x8 a[4], b[4];
            int ke = ks * 32 + lk * 8;
            #pragma unroll
            for (int mt = 0; mt < 4; ++mt) {
                int row = mt * 16 + lr;
                a[mt] = *(const bf16x8*)&As[row * 128 + (ke ^ ((row & 7) << 3))];
            }
            #pragma unroll
            for (int nt = 0; nt < 4; ++nt) {
                b[nt] = *(const bf16x8*)(Bbase + (size_t)(nt * 16 + lr) * 128 + ke);
            }
            #pragma unroll
            for (int nt = 0; nt < 4; ++nt)
                #pragma unroll
                for (int mt = 0; mt < 4; ++mt)
                    acc[nt][mt] = __builtin_amdgcn_mfma_f32_16x16x32_bf16(b[nt], a[mt], acc[nt][mt], 0, 0, 0);
        }

        // D[n][m]: lane holds node gm = m0+mt*16+lr, cols n0 = nbase+nt*16+lk*4 .. +3
        #pragma unroll
        for (int mt = 0; mt < 4; ++mt) {
            int gm = m0 + mt * 16 + lr;
            if (gm >= M) continue;
            #pragma unroll
            for (int nt = 0; nt < 4; ++nt) {
                int n0 = nbase + nt * 16 + lk * 4;
                f32x4 av = acc[nt][mt];
                uint2 pk;
                pk.x = ((unsigned int)f2bf(av[1]) << 16) | (unsigned int)f2bf(av[0]);
                pk.y = ((unsigned int)f2bf(av[3]) << 16) | (unsigned int)f2bf(av[2]);
                *(uint2*)&g_XWx_b[(size_t)gm * 256 + n0] = pk;
            }
        }
    } else {
        const ushort_t* QT = &g_QT[layer][0][0];
        f32x4 acc[2][4];  // [nt][mt], D[qcol][m]
        #pragma unroll
        for (int i = 0; i < 2; ++i)
            #pragma unroll
            for (int j = 0; j < 4; ++j)
                acc[i][j] = (f32x4){0.f, 0.f, 0.f, 0.f};

        #pragma unroll
        for (int ks = 0; ks < 4; ++ks) {
            bf16x8 a[4], b[2];
            int ke = ks * 32 + lk * 8;
            #pragma unroll
            for (int mt = 0; mt < 4; ++mt) {
                int row = mt * 16 + lr;
                a[mt] = *(const bf16x8*)&As[row * 128 + (ke ^ ((row & 7) << 3))];
            }
            #pragma unroll
            for (int nt = 0; nt < 2; ++nt)
                b[nt] = *(const bf16x8*)&QT[(nt * 16 + lr) * 128 + ke];
            #pragma unroll
            for (int nt = 0; nt < 2; ++nt)
                #pragma unroll
                for (int mt = 0; mt < 4; ++mt)
                    acc[nt][mt] = __builtin_amdgcn_mfma_f32_16x16x32_bf16(b[nt], a[mt], acc[nt][mt], 0, 0, 0);
        }

        #pragma unroll
        for (int mt = 0; mt < 4; ++mt) {
            int gm = m0 + mt * 16 + lr;
            if (gm >= M) continue;
            #pragma unroll
            for (int nt = 0; nt < 2; ++nt) {
                #pragma unroll
                for (int r = 0; r < 4; ++r) {
                    int colc = nt * 16 + lk * 4 + r;
                    if ((mask >> colc) & 1u)
                        g_scal[(size_t)gm * 32 + colc] = acc[nt][mt][r];
                }
            }
        }
    }
}

// ------- two-phase fused aggregate + inline gate -------
// phase A: lane e computes gate for edge e (LDS stash); phase B: 4x16-lane groups gather rows.
__global__ __launch_bounds__(256) void aggregate_kernel(int cur, int k,
                                                        const float* __restrict__ bgi,
                                                        const float* __restrict__ bgo, int N) {
    __shared__ float sW[4][64];
    __shared__ int sS[4][64];
    int wv = threadIdx.x >> 6;
    int lane = threadIdx.x & 63;
    int grp = lane >> 4, li = lane & 15;
    int n = blockIdx.x * 4 + wv;
    if (n >= N) return;
    float bias_in = g_bias[lane & 7][k];
    float bias_out = g_bias[lane & 7][3 + k];
    // C-sums for this node (broadcast loads)
    const float* srow = g_scal + (size_t)n * 32;
    float cin, cout;
    if (k == 0) {
        cin = srow[16]; cout = srow[24];
    } else if (k == 1) {
        cin = srow[18] + srow[19]; cout = srow[26] + srow[27];
    } else {
        cin = srow[20] + srow[21] + srow[22];
        cout = srow[28] + srow[29] + srow[30];
    }
    int pin0 = g_off_in[n], din = g_off_in[n + 1] - pin0;
    int pout0 = g_off_out[n], dout = g_off_out[n + 1] - pout0;
    int tot = din + dout;

    float acc[8];
    if (grp == 0) {
        uint4 xv = *(const uint4*)(g_hb[cur] + (size_t)n * 128 + li * 8);
        float4 b1 = *(const float4*)(bgi + li * 8);
        float4 b2 = *(const float4*)(bgi + li * 8 + 4);
        float4 c1 = *(const float4*)(bgo + li * 8);
        float4 c2 = *(const float4*)(bgo + li * 8 + 4);
        acc[0] = bflo(xv.x) + b1.x + c1.x;
        acc[1] = bfhi(xv.x) + b1.y + c1.y;
        acc[2] = bflo(xv.y) + b1.z + c1.z;
        acc[3] = bfhi(xv.y) + b1.w + c1.w;
        acc[4] = bflo(xv.z) + b2.x + c2.x;
        acc[5] = bfhi(xv.z) + b2.y + c2.y;
        acc[6] = bflo(xv.w) + b2.z + c2.z;
        acc[7] = bfhi(xv.w) + b2.w + c2.w;
    } else {
        #pragma unroll
        for (int q = 0; q < 8; ++q) acc[q] = 0.f;
    }

    for (int base = 0; base < tot; base += 64) {
        int cnt = min(64, tot - base);
        // ---- phase A: one lane per edge ----
        if (lane < cnt) {
            int q = base + lane;
            int2 se;
            int dir;
            if (q < din) { se = g_lst_in[pin0 + q]; dir = 0; }
            else         { se = g_lst_out[pout0 + q - din]; dir = 1; }
            const float* arow = g_scal + (size_t)se.x * 32 + dir * 8;
            float asum;
            if (k == 0) asum = arow[0];
            else if (k == 1) asum = arow[2] + arow[3];
            else asum = arow[4] + arow[5] + arow[6];
            float bi = __shfl(bias_in, se.y);
            float bo = __shfl(bias_out, se.y);
            float s = (dir ? bo : bi) + asum + (dir ? cout : cin);
            sW[wv][lane] = 1.0f / (1.0f + __expf(-s));
            sS[wv][lane] = se.x * 2 + dir;
        }
        // wave-synchronous: same wave wrote, same wave reads (no barrier needed)
        // ---- phase B: groups gather rows ----
        for (int e = grp; e < cnt; e += 4) {
            float wvv = sW[wv][e];
            int sv = sS[wv][e];
            const ushort_t* src = g_XWx_b + (size_t)(sv >> 1) * 256 + (sv & 1) * 128 + li * 8;
            uint4 pv = *(const uint4*)src;
            acc[0] += wvv * bflo(pv.x);
            acc[1] += wvv * bfhi(pv.x);
            acc[2] += wvv * bflo(pv.y);
            acc[3] += wvv * bfhi(pv.y);
            acc[4] += wvv * bflo(pv.z);
            acc[5] += wvv * bfhi(pv.z);
            acc[6] += wvv * bflo(pv.w);
            acc[7] += wvv * bfhi(pv.w);
        }
    }
    #pragma unroll
    for (int q = 0; q < 8; ++q) {
        acc[q] += __shfl_xor(acc[q], 16);
        acc[q] += __shfl_xor(acc[q], 32);
    }
    if (grp == 0) {
        uint4 pk;
        pk.x = ((unsigned int)f2bf(acc[1]) << 16) | (unsigned int)f2bf(acc[0]);
        pk.y = ((unsigned int)f2bf(acc[3]) << 16) | (unsigned int)f2bf(acc[2]);
        pk.z = ((unsigned int)f2bf(acc[5]) << 16) | (unsigned int)f2bf(acc[4]);
        pk.w = ((unsigned int)f2bf(acc[7]) << 16) | (unsigned int)f2bf(acc[6]);
        *(uint4*)(g_hb[cur ^ 1] + (size_t)n * 128 + li * 8) = pk;
    }
}

// ---------------- mean-pool partials (bf16 in, fp32 accumulate) ----------------
__global__ void pool_kernel(int fin, int side, const int* __restrict__ batch, int N) {
    const ushort_t* x = g_hb[fin];
    float* gsum = g_gsum[side];
    int n0 = blockIdx.x * 128;
    int d = threadIdx.x;  // 128 threads
    if (n0 >= N) return;
    int nend = min(n0 + 128, N);
    float acc = 0.f;
    int curg = batch[n0];
    for (int n = n0; n < nend; ++n) {
        int g = batch[n];
        if (g != curg) {
            atomicAdd(&gsum[curg * 128 + d], acc);
            acc = 0.f;
            curg = g;
        }
        acc += bf2f(x[(size_t)n * 128 + d]);
    }
    atomicAdd(&gsum[curg * 128 + d], acc);
}

__global__ void count_kernel(int side, const int* __restrict__ batch, int N) {
    int g = threadIdx.x;  // 128 threads
    int lo = 0, hi = N;
    while (lo < hi) { int mid = (lo + hi) >> 1; if (batch[mid] < g) lo = mid + 1; else hi = mid; }
    int a = lo;
    lo = 0; hi = N;
    while (lo < hi) { int mid = (lo + hi) >> 1; if (batch[mid] < g + 1) lo = mid + 1; else hi = mid; }
    g_cnt[side][g] = (float)(lo - a);
}

__global__ void zero_gsum_kernel() {
    int i = blockIdx.x * 256 + threadIdx.x;
    if (i < 2 * N_GRAPHS * NODE_DIM) ((float*)g_gsum)[i] = 0.f;
}

// ---------------- classifier ----------------
__global__ void hidden_kernel(const float* __restrict__ W0, const float* __restrict__ b0) {
    int g = blockIdx.x;
    int j = threadIdx.x;  // 128 x 128
    float inv_s = 1.0f / fmaxf(g_cnt[0][g], 1.0f);
    float inv_t = 1.0f / fmaxf(g_cnt[1][g], 1.0f);
    float acc = b0[j];
    for (int k = 0; k < 128; ++k) acc += g_gsum[0][g * 128 + k] * inv_s * W0[k * 128 + j];
    for (int k = 0; k < 128; ++k) acc += g_gsum[1][g * 128 + k] * inv_t * W0[(128 + k) * 128 + j];
    g_H[g * 128 + j] = fmaxf(acc, 0.f);
}

__global__ void loss_kernel(const float* __restrict__ W1, const float* __restrict__ b1,
                            const int* __restrict__ y, float* __restrict__ out) {
    int g = threadIdx.x;  // 128 threads
    float l0 = b1[0], l1 = b1[1];
    for (int j = 0; j < 128; ++j) {
        float hv = g_H[g * 128 + j];
        l0 += hv * W1[j * 2 + 0];
        l1 += hv * W1[j * 2 + 1];
    }
    float m = fmaxf(l0, l1);
    float lse = m + logf(expf(l0 - m) + expf(l1 - m));
    float ly = (y[g] == 0) ? l0 : l1;
    float c = -(ly - lse) * (1.0f / (float)N_GRAPHS);
    __shared__ float red[128];
    red[g] = c;
    __syncthreads();
    for (int s = 64; s; s >>= 1) {
        if (g < s) red[g] += red[g + s];
        __syncthreads();
    }
    if (g == 0) out[0] = red[0];
}

extern "C" void kernel_launch(void* const* d_in, const int* in_sizes, int n_in,
                              void* d_out, int out_size, void* d_ws, size_t ws_size,
                              hipStream_t stream) {
    const float* x_s      = (const float*)d_in[0];
    const float* x_t      = (const float*)d_in[1];
    const float* ea_s     = (const float*)d_in[2];
    const float* ea_t     = (const float*)d_in[3];
    const int*   ei_s     = (const int*)d_in[4];
    const int*   ei_t     = (const int*)d_in[5];
    const int*   batch_s  = (const int*)d_in[6];
    const int*   batch_t  = (const int*)d_in[7];
    const int*   y        = (const int*)d_in[8];
    const float* node_emb = (const float*)d_in[9];
    const float* edge_emb = (const float*)d_in[10];
    const float* W_in_0   = (const float*)d_in[11];
    const float* W_in_1   = (const float*)d_in[12];
    const float* W_out_0  = (const float*)d_in[13];
    const float* W_out_1  = (const float*)d_in[14];
    const float* Wg_in    = (const float*)d_in[15];
    const float* bg_in    = (const float*)d_in[16];
    const float* Wg_out   = (const float*)d_in[17];
    const float* bg_out   = (const float*)d_in[18];
    const float* cls_W0   = (const float*)d_in[19];
    const float* cls_b0   = (const float*)d_in[20];
    const float* cls_W1   = (const float*)d_in[21];
    const float* cls_b1   = (const float*)d_in[22];

    const int N = N_NODES, E = N_EDGES;
    static const unsigned int MASKS[3] = {MASK_J0, MASK_J1, MASK_J2};

    zero_gsum_kernel<<<(2 * N_GRAPHS * NODE_DIM + 255) / 256, 256, 0, stream>>>();
    zero_qt_kernel<<<(K_LAYERS * 32 * 128 + 255) / 256, 256, 0, stream>>>();
    setup_gates_kernel<<<6, 128, 0, stream>>>(W_in_0, W_in_1, W_out_0, W_out_1, edge_emb);

    for (int side = 0; side < 2; ++side) {
        const float* xin   = side ? x_t : x_s;
        const float* eain  = side ? ea_t : ea_s;
        const int*   ei    = side ? ei_t : ei_s;
        const int*   batch = side ? batch_t : batch_s;
        const int* row = ei;
        const int* col = ei + E;

        node_embed_kernel<<<(N + 3) / 4, 256, 0, stream>>>(xin, node_emb, N);
        edge_voc_kernel<<<(2 * E + 255) / 256, 256, 0, stream>>>(eain, 2 * E);

        // ---- CSR build (once per side; edge_index constant across layers) ----
        csr_zero_kernel<<<(N + 255) / 256, 256, 0, stream>>>();
        csr_count_kernel<<<(E + 255) / 256, 256, 0, stream>>>(row, col, E);
        csr_bsum_kernel<<<dim3(SCAN_NBLK, 2), 256, 0, stream>>>();
        csr_bscan_kernel<<<2, 64, 0, stream>>>();
        csr_off_kernel<<<dim3(SCAN_NBLK, 2), 256, 0, stream>>>(E);
        csr_fill_kernel<<<(E + 255) / 256, 256, 0, stream>>>(row, col, E);

        int cur = 0;
        for (int k = 0; k < K_LAYERS; ++k) {
            assemble_wcat<<<128, 256, 0, stream>>>(Wg_in + (size_t)k * 128 * 128,
                                                   Wg_out + (size_t)k * 128 * 128);
            gemm_xw_mfma<<<(N + 63) / 64, 320, 0, stream>>>(cur, k, MASKS[k], N);
            aggregate_kernel<<<(N + 3) / 4, 256, 0, stream>>>(
                cur, k, bg_in + (size_t)k * 128, bg_out + (size_t)k * 128, N);
            cur ^= 1;
        }
        pool_kernel<<<(N + 127) / 128, 128, 0, stream>>>(cur, side, batch, N);
        count_kernel<<<1, 128, 0, stream>>>(side, batch, N);
    }

    hidden_kernel<<<128, 128, 0, stream>>>(cls_W0, cls_b0);
    loss_kernel<<<1, 128, 0, stream>>>(cls_W1, cls_b1, y, (float*)d_out);
}

// Round 13
// 899.103 us; speedup vs baseline: 29.9369x; 1.0259x over previous
//
#include <hip/hip_runtime.h>
#include <hip/hip_bf16.h>

#define N_NODES 100000
#define N_EDGES 300000
#define N_GRAPHS 128
#define NODE_VOCAB 200
#define NODE_DIM 128
#define EDGE_DIM 64
#define K_LAYERS 3

#define SCAN_CHUNK 2048
#define SCAN_NBLK ((N_NODES + SCAN_CHUNK - 1) / SCAN_CHUNK)  // 49

typedef unsigned short ushort_t;
typedef __attribute__((ext_vector_type(8))) __bf16 bf16x8;
typedef __attribute__((ext_vector_type(4))) float f32x4;

__device__ inline ushort_t f2bf(float f) {
    unsigned int u = __float_as_uint(f);
    unsigned int r = (u + 0x7fff + ((u >> 16) & 1)) >> 16;
    return (ushort_t)r;
}
__device__ inline float bf2f(ushort_t u) {
    return __uint_as_float(((unsigned int)u) << 16);
}
__device__ inline float bflo(unsigned int u) { return __uint_as_float(u << 16); }
__device__ inline float bfhi(unsigned int u) { return __uint_as_float(u & 0xffff0000u); }

// scal row layout (32 fp32 = 128B):
//   A-in slots 0-7, A-out 8-15, C-in 16-23, C-out 24-31.
//   within each 8-block: layer-k gate reads cols off(k)+j (j=0..k), off = {0,2,4}.
//   layer j WRITES cols off(k)+j for k>=j  ->  j0:{0,2,4} j1:{3,5} j2:{6} per block:
#define MASK_J0 0x15151515u
#define MASK_J1 0x28282828u
#define MASK_J2 0x40404040u

// ---------------- static device scratch (no reliance on ws_size) ----------------
__device__ ushort_t g_hb[2][(size_t)N_NODES * NODE_DIM];  // bf16 ping-pong node state
__device__ ushort_t g_XWx_b[(size_t)N_NODES * 256];       // bf16 [xi | xo]
__device__ ushort_t g_WcatT[K_LAYERS][256 * 128];         // Wcat^T bf16 [k][n][kd]
__device__ ushort_t g_QT[K_LAYERS][32][128];              // gate-chain vectors, bf16
__device__ float g_scal[(size_t)N_NODES * 32];            // per-node gate scalars
__device__ float g_bias[8][6];                            // e0 vocab bias [t][dir*3+k]
__device__ int  g_evoc[2 * N_EDGES];                      // edge vocab index
__device__ float g_gsum[2][N_GRAPHS * NODE_DIM];
__device__ float g_cnt[2][N_GRAPHS];
__device__ float g_H[N_GRAPHS * NODE_DIM];
// CSR (rebuilt per side; constant across layers)
__device__ int  g_deg_in[N_NODES];
__device__ int  g_deg_out[N_NODES];
__device__ int  g_off_in[N_NODES + 1];
__device__ int  g_off_out[N_NODES + 1];
__device__ int  g_cur_in[N_NODES];
__device__ int  g_cur_out[N_NODES];
__device__ int2 g_lst_in[N_EDGES];   // (src=row, voc) keyed by col
__device__ int2 g_lst_out[N_EDGES];  // (src=col, voc) keyed by row
__device__ int  g_bsum[2][SCAN_NBLK];
__device__ int  g_boff[2][SCAN_NBLK];

// ---------------- node argmax + embed (bf16 state out) ----------------
__global__ void node_embed_kernel(const float* __restrict__ x, const float* __restrict__ emb,
                                  int N) {
    int wave = threadIdx.x >> 6;
    int lane = threadIdx.x & 63;
    int n = blockIdx.x * 4 + wave;
    if (n >= N) return;
    const float* xr = x + (size_t)n * NODE_VOCAB;
    float v = xr[lane];
    int idx = lane;
    float nv = xr[lane + 64];
    if (nv > v) { v = nv; idx = lane + 64; }
    nv = xr[lane + 128];
    if (nv > v) { v = nv; idx = lane + 128; }
    if (lane < NODE_VOCAB - 192) {
        nv = xr[lane + 192];
        if (nv > v) { v = nv; idx = lane + 192; }
    }
    #pragma unroll
    for (int off = 32; off; off >>= 1) {
        float ov = __shfl_xor(v, off);
        int oi = __shfl_xor(idx, off);
        if (ov > v || (ov == v && oi < idx)) { v = ov; idx = oi; }
    }
    const float* er = emb + (size_t)idx * NODE_DIM;
    g_hb[0][(size_t)n * NODE_DIM + lane] = f2bf(er[lane]);
    g_hb[0][(size_t)n * NODE_DIM + 64 + lane] = f2bf(er[64 + lane]);
}

// ---------------- edge argmax -> vocab index only ----------------
__global__ void edge_voc_kernel(const float* __restrict__ ea, int M) {
    long idx = (long)blockIdx.x * 256 + threadIdx.x;
    if (idx >= M) return;
    const float* ar = ea + idx * 8;
    float4 v0 = *(const float4*)ar;
    float4 v1 = *(const float4*)(ar + 4);
    float vals[8] = {v0.x, v0.y, v0.z, v0.w, v1.x, v1.y, v1.z, v1.w};
    int best = 0;
    float bv = vals[0];
    #pragma unroll
    for (int i = 1; i < 8; ++i)
        if (vals[i] > bv) { bv = vals[i]; best = i; }
    g_evoc[idx] = best;
}

// ---------------- zero QT ----------------
__global__ void zero_qt_kernel() {
    int i = blockIdx.x * 256 + threadIdx.x;
    if (i < K_LAYERS * 32 * 128) ((ushort_t*)g_QT)[i] = 0;
}

// ---------------- gate chain setup: 6 blocks = (dir, k) pairs ----------------
__global__ void setup_gates_kernel(const float* __restrict__ Wi0, const float* __restrict__ Wi1,
                                   const float* __restrict__ Wo0, const float* __restrict__ Wo1,
                                   const float* __restrict__ eemb) {
    int b = blockIdx.x;  // 0..5
    int D = b / 3, k = b % 3;
    int t = threadIdx.x;  // 128
    const float* W0 = D ? Wo0 : Wi0;
    const float* W1 = D ? Wo1 : Wi1;
    __shared__ float u[64], un[64];
    if (t < 64) u[t] = W1[k * 64 + t];
    __syncthreads();
    int offk = (k == 0) ? 0 : (k == 1 ? 2 : 4);
    for (int j = k; j >= 0; --j) {
        const float* Wj = W0 + (size_t)j * 320 * 64;
        float qa = 0.f, qc = 0.f;
        for (int m = 0; m < 64; ++m) {
            float um = u[m];
            qa += Wj[t * 64 + m] * um;
            qc += Wj[(192 + t) * 64 + m] * um;
        }
        g_QT[j][(D ? 8 : 0) + offk + j][t] = f2bf(qa);
        g_QT[j][(D ? 24 : 16) + offk + j][t] = f2bf(qc);
        float s = 0.f;
        if (t < 64) {
            for (int m = 0; m < 64; ++m) s += Wj[(128 + t) * 64 + m] * u[m];
        }
        __syncthreads();
        if (t < 64) un[t] = s;
        __syncthreads();
        if (t < 64) u[t] = un[t];
        __syncthreads();
    }
    if (t < 8) {
        float s = 0.f;
        for (int m = 0; m < 64; ++m) s += eemb[t * 64 + m] * u[m];
        g_bias[t][D * 3 + k] = s;
    }
}

// ---------------- CSR build ----------------
__global__ void csr_zero_kernel() {
    int i = blockIdx.x * 256 + threadIdx.x;
    if (i < N_NODES) { g_deg_in[i] = 0; g_deg_out[i] = 0; }
}

__global__ void csr_count_kernel(const int* __restrict__ row, const int* __restrict__ col,
                                 int E) {
    int e = blockIdx.x * 256 + threadIdx.x;
    if (e >= E) return;
    atomicAdd(&g_deg_in[col[e]], 1);
    atomicAdd(&g_deg_out[row[e]], 1);
}

__global__ void csr_bsum_kernel() {
    int which = blockIdx.y;
    const int* deg = which ? g_deg_out : g_deg_in;
    int b = blockIdx.x;
    int t = threadIdx.x;
    int base = b * SCAN_CHUNK;
    int s = 0;
    #pragma unroll
    for (int i = 0; i < SCAN_CHUNK / 256; ++i) {
        int idx = base + i * 256 + t;
        if (idx < N_NODES) s += deg[idx];
    }
    __shared__ int red[256];
    red[t] = s;
    __syncthreads();
    for (int d = 128; d; d >>= 1) {
        if (t < d) red[t] += red[t + d];
        __syncthreads();
    }
    if (t == 0) g_bsum[which][b] = red[0];
}

__global__ void csr_bscan_kernel() {
    int which = blockIdx.x;
    int t = threadIdx.x;  // 64 threads
    int v = (t < SCAN_NBLK) ? g_bsum[which][t] : 0;
    int orig = v;
    #pragma unroll
    for (int d = 1; d < 64; d <<= 1) {
        int u = __shfl_up(v, d, 64);
        if (t >= d) v += u;
    }
    if (t < SCAN_NBLK) g_boff[which][t] = v - orig;
}

__global__ void csr_off_kernel(int total) {
    int which = blockIdx.y;
    const int* deg = which ? g_deg_out : g_deg_in;
    int* off = which ? g_off_out : g_off_in;
    int* cur = which ? g_cur_out : g_cur_in;
    int b = blockIdx.x;
    int t = threadIdx.x;
    const int per = SCAN_CHUNK / 256;  // 8
    int lo = b * SCAN_CHUNK + t * per;
    int d8[per];
    int s = 0;
    #pragma unroll
    for (int i = 0; i < per; ++i) {
        int idx = lo + i;
        d8[i] = (idx < N_NODES) ? deg[idx] : 0;
        s += d8[i];
    }
    __shared__ int part[256];
    part[t] = s;
    __syncthreads();
    for (int d = 1; d < 256; d <<= 1) {
        int add = (t >= d) ? part[t - d] : 0;
        __syncthreads();
        part[t] += add;
        __syncthreads();
    }
    int run = g_boff[which][b] + part[t] - s;
    #pragma unroll
    for (int i = 0; i < per; ++i) {
        int idx = lo + i;
        if (idx < N_NODES) {
            off[idx] = run;
            cur[idx] = run;
            run += d8[i];
        }
    }
    if (b == 0 && t == 0) off[N_NODES] = total;
}

// fill lists with (src, voc)
__global__ void csr_fill_kernel(const int* __restrict__ row, const int* __restrict__ col,
                                int E) {
    int e = blockIdx.x * 256 + threadIdx.x;
    if (e >= E) return;
    int r = row[e], c = col[e];
    int p = atomicAdd(&g_cur_in[c], 1);
    g_lst_in[p] = make_int2(r, g_evoc[e]);
    int q = atomicAdd(&g_cur_out[r], 1);
    g_lst_out[q] = make_int2(c, g_evoc[E + e]);
}

// ---------------- assemble Wcat^T for ALL layers (k x 256 x 128, bf16): [xi | xo] ----------------
__global__ void assemble_wcat_all(const float* __restrict__ Wgi, const float* __restrict__ Wgo) {
    int idx = blockIdx.x * 256 + threadIdx.x;  // 3*32768
    if (idx >= K_LAYERS * 32768) return;
    int k = idx >> 15;
    int rem = idx & 32767;
    int n = rem >> 7;
    int kd = rem & 127;
    float v = (n < 128) ? Wgi[(size_t)k * 16384 + kd * 128 + n]
                        : Wgo[(size_t)k * 16384 + kd * 128 + (n - 128)];
    g_WcatT[k][n * 128 + kd] = f2bf(v);
}

// ---- fused node GEMM via MFMA (swapped operands: D[n][m], lane holds 4 consecutive cols) ----
// XWx(bf16) = x@Wcat (waves 0-3), scal = x@QT^T (wave 4). 320 threads; grid ceil(M/64)
__global__ __launch_bounds__(320) void gemm_xw_mfma(int cur, int layer, unsigned int mask,
                                                    int M) {
    const ushort_t* __restrict__ hb = g_hb[cur];
    int m0 = blockIdx.x * 64;
    int t = threadIdx.x;
    int wave = t >> 6, lane = t & 63;
    __shared__ ushort_t As[64 * 128];  // 16 KB, XOR-swizzled: elem k ^= (row&7)<<3

    for (int idx = t; idx < 1024; idx += 320) {
        int m = idx >> 4, c = idx & 15;  // row, 16B-chunk (8 elems)
        int gm = m0 + m;
        uint4 v = make_uint4(0u, 0u, 0u, 0u);
        if (gm < M) v = *(const uint4*)(hb + (size_t)gm * 128 + c * 8);
        *(uint4*)&As[m * 128 + ((c * 8) ^ ((m & 7) << 3))] = v;
    }
    __syncthreads();

    int lr = lane & 15, lk = lane >> 4;

    if (wave < 4) {
        int nbase = wave * 64;
        f32x4 acc[4][4];  // [nt][mt], D[n][m]
        #pragma unroll
        for (int i = 0; i < 4; ++i)
            #pragma unroll
            for (int j = 0; j < 4; ++j)
                acc[i][j] = (f32x4){0.f, 0.f, 0.f, 0.f};

        const ushort_t* Bbase = &g_WcatT[layer][0] + (size_t)nbase * 128;
        #pragma unroll
        for (int ks = 0; ks < 4; ++ks) {
            bf16x8 a[4], b[4];
            int ke = ks * 32 + lk * 8;
            #pragma unroll
            for (int mt = 0; mt < 4; ++mt) {
                int row = mt * 16 + lr;
                a[mt] = *(const bf16x8*)&As[row * 128 + (ke ^ ((row & 7) << 3))];
            }
            #pragma unroll
            for (int nt = 0; nt < 4; ++nt) {
                b[nt] = *(const bf16x8*)(Bbase + (size_t)(nt * 16 + lr) * 128 + ke);
            }
            #pragma unroll
            for (int nt = 0; nt < 4; ++nt)
                #pragma unroll
                for (int mt = 0; mt < 4; ++mt)
                    acc[nt][mt] = __builtin_amdgcn_mfma_f32_16x16x32_bf16(b[nt], a[mt], acc[nt][mt], 0, 0, 0);
        }

        // D[n][m]: lane holds node gm = m0+mt*16+lr, cols n0 = nbase+nt*16+lk*4 .. +3
        #pragma unroll
        for (int mt = 0; mt < 4; ++mt) {
            int gm = m0 + mt * 16 + lr;
            if (gm >= M) continue;
            #pragma unroll
            for (int nt = 0; nt < 4; ++nt) {
                int n0 = nbase + nt * 16 + lk * 4;
                f32x4 av = acc[nt][mt];
                uint2 pk;
                pk.x = ((unsigned int)f2bf(av[1]) << 16) | (unsigned int)f2bf(av[0]);
                pk.y = ((unsigned int)f2bf(av[3]) << 16) | (unsigned int)f2bf(av[2]);
                *(uint2*)&g_XWx_b[(size_t)gm * 256 + n0] = pk;
            }
        }
    } else {
        const ushort_t* QT = &g_QT[layer][0][0];
        f32x4 acc[2][4];  // [nt][mt], D[qcol][m]
        #pragma unroll
        for (int i = 0; i < 2; ++i)
            #pragma unroll
            for (int j = 0; j < 4; ++j)
                acc[i][j] = (f32x4){0.f, 0.f, 0.f, 0.f};

        #pragma unroll
        for (int ks = 0; ks < 4; ++ks) {
            bf16x8 a[4], b[2];
            int ke = ks * 32 + lk * 8;
            #pragma unroll
            for (int mt = 0; mt < 4; ++mt) {
                int row = mt * 16 + lr;
                a[mt] = *(const bf16x8*)&As[row * 128 + (ke ^ ((row & 7) << 3))];
            }
            #pragma unroll
            for (int nt = 0; nt < 2; ++nt)
                b[nt] = *(const bf16x8*)&QT[(nt * 16 + lr) * 128 + ke];
            #pragma unroll
            for (int nt = 0; nt < 2; ++nt)
                #pragma unroll
                for (int mt = 0; mt < 4; ++mt)
                    acc[nt][mt] = __builtin_amdgcn_mfma_f32_16x16x32_bf16(b[nt], a[mt], acc[nt][mt], 0, 0, 0);
        }

        #pragma unroll
        for (int mt = 0; mt < 4; ++mt) {
            int gm = m0 + mt * 16 + lr;
            if (gm >= M) continue;
            #pragma unroll
            for (int nt = 0; nt < 2; ++nt) {
                #pragma unroll
                for (int r = 0; r < 4; ++r) {
                    int colc = nt * 16 + lk * 4 + r;
                    if ((mask >> colc) & 1u)
                        g_scal[(size_t)gm * 32 + colc] = acc[nt][mt][r];
                }
            }
        }
    }
}

// ------- fused aggregate + inline gate: ONE NODE PER 16-LANE GROUP (4 nodes/wave) -------
// per chunk of 16 edges: lane li computes gate for edge li; then group iterates edges,
// broadcasting (gate, src*2+dir) via wave shuffles, gathering 256B rows 16B/lane.
__global__ __launch_bounds__(256) void aggregate_kernel(int cur, int k,
                                                        const float* __restrict__ bgi,
                                                        const float* __restrict__ bgo, int N) {
    int tid = threadIdx.x;
    int wv = tid >> 6;
    int lane = tid & 63;
    int grp = lane >> 4, li = lane & 15;
    int n = blockIdx.x * 16 + wv * 4 + grp;
    bool valid = n < N;

    int pin0 = 0, din = 0, pout0 = 0, dout = 0;
    float cin = 0.f, cout = 0.f;
    if (valid) {
        pin0 = g_off_in[n];  din = g_off_in[n + 1] - pin0;
        pout0 = g_off_out[n]; dout = g_off_out[n + 1] - pout0;
        const float* srow = g_scal + (size_t)n * 32;
        if (k == 0) {
            cin = srow[16]; cout = srow[24];
        } else if (k == 1) {
            cin = srow[18] + srow[19]; cout = srow[26] + srow[27];
        } else {
            cin = srow[20] + srow[21] + srow[22];
            cout = srow[28] + srow[29] + srow[30];
        }
    }
    int tot = din + dout;

    float acc[8];
    {
        float4 b1 = *(const float4*)(bgi + li * 8);
        float4 b2 = *(const float4*)(bgi + li * 8 + 4);
        float4 c1 = *(const float4*)(bgo + li * 8);
        float4 c2 = *(const float4*)(bgo + li * 8 + 4);
        uint4 xv = make_uint4(0u, 0u, 0u, 0u);
        if (valid) xv = *(const uint4*)(g_hb[cur] + (size_t)n * 128 + li * 8);
        acc[0] = bflo(xv.x) + b1.x + c1.x;
        acc[1] = bfhi(xv.x) + b1.y + c1.y;
        acc[2] = bflo(xv.y) + b1.z + c1.z;
        acc[3] = bfhi(xv.y) + b1.w + c1.w;
        acc[4] = bflo(xv.z) + b2.x + c2.x;
        acc[5] = bfhi(xv.z) + b2.y + c2.y;
        acc[6] = bflo(xv.w) + b2.z + c2.z;
        acc[7] = bfhi(xv.w) + b2.w + c2.w;
    }

    for (int base = 0; base < tot; base += 16) {
        int cnt = min(16, tot - base);
        float gate = 0.f;
        int sv = 0;
        if (li < cnt) {
            int q = base + li;
            int2 se;
            int dir;
            if (q < din) { se = g_lst_in[pin0 + q]; dir = 0; }
            else         { se = g_lst_out[pout0 + q - din]; dir = 1; }
            const float* arow = g_scal + (size_t)se.x * 32 + dir * 8;
            float asum;
            if (k == 0) asum = arow[0];
            else if (k == 1) asum = arow[2] + arow[3];
            else asum = arow[4] + arow[5] + arow[6];
            float s = g_bias[se.y][dir * 3 + k] + asum + (dir ? cout : cin);
            gate = 1.0f / (1.0f + __expf(-s));
            sv = se.x * 2 + dir;
        }
        for (int e = 0; e < cnt; ++e) {
            float wvv = __shfl(gate, grp * 16 + e);
            int s2 = __shfl(sv, grp * 16 + e);
            uint4 pv = *(const uint4*)(g_XWx_b + (size_t)(s2 >> 1) * 256 + (s2 & 1) * 128 + li * 8);
            acc[0] += wvv * bflo(pv.x);
            acc[1] += wvv * bfhi(pv.x);
            acc[2] += wvv * bflo(pv.y);
            acc[3] += wvv * bfhi(pv.y);
            acc[4] += wvv * bflo(pv.z);
            acc[5] += wvv * bfhi(pv.z);
            acc[6] += wvv * bflo(pv.w);
            acc[7] += wvv * bfhi(pv.w);
        }
    }

    if (valid) {
        uint4 pk;
        pk.x = ((unsigned int)f2bf(acc[1]) << 16) | (unsigned int)f2bf(acc[0]);
        pk.y = ((unsigned int)f2bf(acc[3]) << 16) | (unsigned int)f2bf(acc[2]);
        pk.z = ((unsigned int)f2bf(acc[5]) << 16) | (unsigned int)f2bf(acc[4]);
        pk.w = ((unsigned int)f2bf(acc[7]) << 16) | (unsigned int)f2bf(acc[6]);
        *(uint4*)(g_hb[cur ^ 1] + (size_t)n * 128 + li * 8) = pk;
    }
}

// ---------------- mean-pool partials (bf16 in, fp32 accumulate) ----------------
__global__ void pool_kernel(int fin, int side, const int* __restrict__ batch, int N) {
    const ushort_t* x = g_hb[fin];
    float* gsum = g_gsum[side];
    int n0 = blockIdx.x * 128;
    int d = threadIdx.x;  // 128 threads
    if (n0 >= N) return;
    int nend = min(n0 + 128, N);
    float acc = 0.f;
    int curg = batch[n0];
    for (int n = n0; n < nend; ++n) {
        int g = batch[n];
        if (g != curg) {
            atomicAdd(&gsum[curg * 128 + d], acc);
            acc = 0.f;
            curg = g;
        }
        acc += bf2f(x[(size_t)n * 128 + d]);
    }
    atomicAdd(&gsum[curg * 128 + d], acc);
}

__global__ void count_kernel(int side, const int* __restrict__ batch, int N) {
    int g = threadIdx.x;  // 128 threads
    int lo = 0, hi = N;
    while (lo < hi) { int mid = (lo + hi) >> 1; if (batch[mid] < g) lo = mid + 1; else hi = mid; }
    int a = lo;
    lo = 0; hi = N;
    while (lo < hi) { int mid = (lo + hi) >> 1; if (batch[mid] < g + 1) lo = mid + 1; else hi = mid; }
    g_cnt[side][g] = (float)(lo - a);
}

__global__ void zero_gsum_kernel() {
    int i = blockIdx.x * 256 + threadIdx.x;
    if (i < 2 * N_GRAPHS * NODE_DIM) ((float*)g_gsum)[i] = 0.f;
}

// ---------------- classifier ----------------
__global__ void hidden_kernel(const float* __restrict__ W0, const float* __restrict__ b0) {
    int g = blockIdx.x;
    int j = threadIdx.x;  // 128 x 128
    float inv_s = 1.0f / fmaxf(g_cnt[0][g], 1.0f);
    float inv_t = 1.0f / fmaxf(g_cnt[1][g], 1.0f);
    float acc = b0[j];
    for (int k = 0; k < 128; ++k) acc += g_gsum[0][g * 128 + k] * inv_s * W0[k * 128 + j];
    for (int k = 0; k < 128; ++k) acc += g_gsum[1][g * 128 + k] * inv_t * W0[(128 + k) * 128 + j];
    g_H[g * 128 + j] = fmaxf(acc, 0.f);
}

__global__ void loss_kernel(const float* __restrict__ W1, const float* __restrict__ b1,
                            const int* __restrict__ y, float* __restrict__ out) {
    int g = threadIdx.x;  // 128 threads
    float l0 = b1[0], l1 = b1[1];
    for (int j = 0; j < 128; ++j) {
        float hv = g_H[g * 128 + j];
        l0 += hv * W1[j * 2 + 0];
        l1 += hv * W1[j * 2 + 1];
    }
    float m = fmaxf(l0, l1);
    float lse = m + logf(expf(l0 - m) + expf(l1 - m));
    float ly = (y[g] == 0) ? l0 : l1;
    float c = -(ly - lse) * (1.0f / (float)N_GRAPHS);
    __shared__ float red[128];
    red[g] = c;
    __syncthreads();
    for (int s = 64; s; s >>= 1) {
        if (g < s) red[g] += red[g + s];
        __syncthreads();
    }
    if (g == 0) out[0] = red[0];
}

extern "C" void kernel_launch(void* const* d_in, const int* in_sizes, int n_in,
                              void* d_out, int out_size, void* d_ws, size_t ws_size,
                              hipStream_t stream) {
    const float* x_s      = (const float*)d_in[0];
    const float* x_t      = (const float*)d_in[1];
    const float* ea_s     = (const float*)d_in[2];
    const float* ea_t     = (const float*)d_in[3];
    const int*   ei_s     = (const int*)d_in[4];
    const int*   ei_t     = (const int*)d_in[5];
    const int*   batch_s  = (const int*)d_in[6];
    const int*   batch_t  = (const int*)d_in[7];
    const int*   y        = (const int*)d_in[8];
    const float* node_emb = (const float*)d_in[9];
    const float* edge_emb = (const float*)d_in[10];
    const float* W_in_0   = (const float*)d_in[11];
    const float* W_in_1   = (const float*)d_in[12];
    const float* W_out_0  = (const float*)d_in[13];
    const float* W_out_1  = (const float*)d_in[14];
    const float* Wg_in    = (const float*)d_in[15];
    const float* bg_in    = (const float*)d_in[16];
    const float* Wg_out   = (const float*)d_in[17];
    const float* bg_out   = (const float*)d_in[18];
    const float* cls_W0   = (const float*)d_in[19];
    const float* cls_b0   = (const float*)d_in[20];
    const float* cls_W1   = (const float*)d_in[21];
    const float* cls_b1   = (const float*)d_in[22];

    const int N = N_NODES, E = N_EDGES;
    static const unsigned int MASKS[3] = {MASK_J0, MASK_J1, MASK_J2};

    zero_gsum_kernel<<<(2 * N_GRAPHS * NODE_DIM + 255) / 256, 256, 0, stream>>>();
    zero_qt_kernel<<<(K_LAYERS * 32 * 128 + 255) / 256, 256, 0, stream>>>();
    setup_gates_kernel<<<6, 128, 0, stream>>>(W_in_0, W_in_1, W_out_0, W_out_1, edge_emb);
    assemble_wcat_all<<<(K_LAYERS * 32768 + 255) / 256, 256, 0, stream>>>(Wg_in, Wg_out);

    for (int side = 0; side < 2; ++side) {
        const float* xin   = side ? x_t : x_s;
        const float* eain  = side ? ea_t : ea_s;
        const int*   ei    = side ? ei_t : ei_s;
        const int*   batch = side ? batch_t : batch_s;
        const int* row = ei;
        const int* col = ei + E;

        node_embed_kernel<<<(N + 3) / 4, 256, 0, stream>>>(xin, node_emb, N);
        edge_voc_kernel<<<(2 * E + 255) / 256, 256, 0, stream>>>(eain, 2 * E);

        // ---- CSR build (once per side; edge_index constant across layers) ----
        csr_zero_kernel<<<(N + 255) / 256, 256, 0, stream>>>();
        csr_count_kernel<<<(E + 255) / 256, 256, 0, stream>>>(row, col, E);
        csr_bsum_kernel<<<dim3(SCAN_NBLK, 2), 256, 0, stream>>>();
        csr_bscan_kernel<<<2, 64, 0, stream>>>();
        csr_off_kernel<<<dim3(SCAN_NBLK, 2), 256, 0, stream>>>(E);
        csr_fill_kernel<<<(E + 255) / 256, 256, 0, stream>>>(row, col, E);

        int cur = 0;
        for (int k = 0; k < K_LAYERS; ++k) {
            gemm_xw_mfma<<<(N + 63) / 64, 320, 0, stream>>>(cur, k, MASKS[k], N);
            aggregate_kernel<<<(N + 15) / 16, 256, 0, stream>>>(
                cur, k, bg_in + (size_t)k * 128, bg_out + (size_t)k * 128, N);
            cur ^= 1;
        }
        pool_kernel<<<(N + 127) / 128, 128, 0, stream>>>(cur, side, batch, N);
        count_kernel<<<1, 128, 0, stream>>>(side, batch, N);
    }

    hidden_kernel<<<128, 128, 0, stream>>>(cls_W0, cls_b0);
    loss_kernel<<<1, 128, 0, stream>>>(cls_W1, cls_b1, y, (float*)d_out);
}

// Round 14
// 889.295 us; speedup vs baseline: 30.2671x; 1.0110x over previous
//
#include <hip/hip_runtime.h>
#include <hip/hip_bf16.h>

#define N_NODES 100000
#define N_EDGES 300000
#define N_GRAPHS 128
#define NODE_VOCAB 200
#define NODE_DIM 128
#define EDGE_DIM 64
#define K_LAYERS 3

#define SCAN_CHUNK 2048
#define SCAN_NBLK ((N_NODES + SCAN_CHUNK - 1) / SCAN_CHUNK)  // 49

typedef unsigned short ushort_t;
typedef __attribute__((ext_vector_type(8))) __bf16 bf16x8;
typedef __attribute__((ext_vector_type(4))) float f32x4;

__device__ inline ushort_t f2bf(float f) {
    unsigned int u = __float_as_uint(f);
    unsigned int r = (u + 0x7fff + ((u >> 16) & 1)) >> 16;
    return (ushort_t)r;
}
__device__ inline float bf2f(ushort_t u) {
    return __uint_as_float(((unsigned int)u) << 16);
}
__device__ inline float bflo(unsigned int u) { return __uint_as_float(u << 16); }
__device__ inline float bfhi(unsigned int u) { return __uint_as_float(u & 0xffff0000u); }

// scal row layout (32 fp32 = 128B):
//   A-in slots 0-7, A-out 8-15, C-in 16-23, C-out 24-31.
//   within each 8-block: layer-k gate reads cols off(k)+j (j=0..k), off = {0,2,4}.
//   layer j WRITES cols off(k)+j for k>=j  ->  j0:{0,2,4} j1:{3,5} j2:{6} per block:
#define MASK_J0 0x15151515u
#define MASK_J1 0x28282828u
#define MASK_J2 0x40404040u

// ---------------- static device scratch (no reliance on ws_size) ----------------
__device__ ushort_t g_hb[2][(size_t)N_NODES * NODE_DIM];  // bf16 ping-pong node state
__device__ ushort_t g_XWx_b[(size_t)N_NODES * 256];       // bf16 [xi | xo]
__device__ ushort_t g_WcatT[K_LAYERS][256 * 128];         // Wcat^T bf16 [k][n][kd]
__device__ ushort_t g_QT[K_LAYERS][32][128];              // gate-chain vectors, bf16
__device__ float g_scal[(size_t)N_NODES * 32];            // per-node gate scalars
__device__ float g_bias[8][6];                            // e0 vocab bias [t][dir*3+k]
__device__ int  g_evoc[2 * N_EDGES];                      // edge vocab index
__device__ float g_gsum[2][N_GRAPHS * NODE_DIM];
__device__ float g_cnt[2][N_GRAPHS];
__device__ float g_H[N_GRAPHS * NODE_DIM];
// CSR (rebuilt per side; constant across layers)
__device__ int  g_deg_in[N_NODES];
__device__ int  g_deg_out[N_NODES];
__device__ int  g_off_in[N_NODES + 1];
__device__ int  g_off_out[N_NODES + 1];
__device__ int  g_cur_in[N_NODES];
__device__ int  g_cur_out[N_NODES];
__device__ int2 g_lst_in[N_EDGES];   // (src=row, voc) keyed by col
__device__ int2 g_lst_out[N_EDGES];  // (src=col, voc) keyed by row
__device__ int  g_bsum[2][SCAN_NBLK];
__device__ int  g_boff[2][SCAN_NBLK];

// ---------------- node argmax + embed (bf16 state out) ----------------
__global__ void node_embed_kernel(const float* __restrict__ x, const float* __restrict__ emb,
                                  int N) {
    int wave = threadIdx.x >> 6;
    int lane = threadIdx.x & 63;
    int n = blockIdx.x * 4 + wave;
    if (n >= N) return;
    const float* xr = x + (size_t)n * NODE_VOCAB;
    float v = xr[lane];
    int idx = lane;
    float nv = xr[lane + 64];
    if (nv > v) { v = nv; idx = lane + 64; }
    nv = xr[lane + 128];
    if (nv > v) { v = nv; idx = lane + 128; }
    if (lane < NODE_VOCAB - 192) {
        nv = xr[lane + 192];
        if (nv > v) { v = nv; idx = lane + 192; }
    }
    #pragma unroll
    for (int off = 32; off; off >>= 1) {
        float ov = __shfl_xor(v, off);
        int oi = __shfl_xor(idx, off);
        if (ov > v || (ov == v && oi < idx)) { v = ov; idx = oi; }
    }
    const float* er = emb + (size_t)idx * NODE_DIM;
    g_hb[0][(size_t)n * NODE_DIM + lane] = f2bf(er[lane]);
    g_hb[0][(size_t)n * NODE_DIM + 64 + lane] = f2bf(er[64 + lane]);
}

// ---------------- edge argmax -> vocab index only ----------------
__global__ void edge_voc_kernel(const float* __restrict__ ea, int M) {
    long idx = (long)blockIdx.x * 256 + threadIdx.x;
    if (idx >= M) return;
    const float* ar = ea + idx * 8;
    float4 v0 = *(const float4*)ar;
    float4 v1 = *(const float4*)(ar + 4);
    float vals[8] = {v0.x, v0.y, v0.z, v0.w, v1.x, v1.y, v1.z, v1.w};
    int best = 0;
    float bv = vals[0];
    #pragma unroll
    for (int i = 1; i < 8; ++i)
        if (vals[i] > bv) { bv = vals[i]; best = i; }
    g_evoc[idx] = best;
}

// ---------------- zero QT ----------------
__global__ void zero_qt_kernel() {
    int i = blockIdx.x * 256 + threadIdx.x;
    if (i < K_LAYERS * 32 * 128) ((ushort_t*)g_QT)[i] = 0;
}

// ---------------- gate chain setup: 6 blocks = (dir, k) pairs ----------------
__global__ void setup_gates_kernel(const float* __restrict__ Wi0, const float* __restrict__ Wi1,
                                   const float* __restrict__ Wo0, const float* __restrict__ Wo1,
                                   const float* __restrict__ eemb) {
    int b = blockIdx.x;  // 0..5
    int D = b / 3, k = b % 3;
    int t = threadIdx.x;  // 128
    const float* W0 = D ? Wo0 : Wi0;
    const float* W1 = D ? Wo1 : Wi1;
    __shared__ float u[64], un[64];
    if (t < 64) u[t] = W1[k * 64 + t];
    __syncthreads();
    int offk = (k == 0) ? 0 : (k == 1 ? 2 : 4);
    for (int j = k; j >= 0; --j) {
        const float* Wj = W0 + (size_t)j * 320 * 64;
        float qa = 0.f, qc = 0.f;
        for (int m = 0; m < 64; ++m) {
            float um = u[m];
            qa += Wj[t * 64 + m] * um;
            qc += Wj[(192 + t) * 64 + m] * um;
        }
        g_QT[j][(D ? 8 : 0) + offk + j][t] = f2bf(qa);
        g_QT[j][(D ? 24 : 16) + offk + j][t] = f2bf(qc);
        float s = 0.f;
        if (t < 64) {
            for (int m = 0; m < 64; ++m) s += Wj[(128 + t) * 64 + m] * u[m];
        }
        __syncthreads();
        if (t < 64) un[t] = s;
        __syncthreads();
        if (t < 64) u[t] = un[t];
        __syncthreads();
    }
    if (t < 8) {
        float s = 0.f;
        for (int m = 0; m < 64; ++m) s += eemb[t * 64 + m] * u[m];
        g_bias[t][D * 3 + k] = s;
    }
}

// ---------------- CSR build ----------------
__global__ void csr_zero_kernel() {
    int i = blockIdx.x * 256 + threadIdx.x;
    if (i < N_NODES) { g_deg_in[i] = 0; g_deg_out[i] = 0; }
}

__global__ void csr_count_kernel(const int* __restrict__ row, const int* __restrict__ col,
                                 int E) {
    int e = blockIdx.x * 256 + threadIdx.x;
    if (e >= E) return;
    atomicAdd(&g_deg_in[col[e]], 1);
    atomicAdd(&g_deg_out[row[e]], 1);
}

__global__ void csr_bsum_kernel() {
    int which = blockIdx.y;
    const int* deg = which ? g_deg_out : g_deg_in;
    int b = blockIdx.x;
    int t = threadIdx.x;
    int base = b * SCAN_CHUNK;
    int s = 0;
    #pragma unroll
    for (int i = 0; i < SCAN_CHUNK / 256; ++i) {
        int idx = base + i * 256 + t;
        if (idx < N_NODES) s += deg[idx];
    }
    __shared__ int red[256];
    red[t] = s;
    __syncthreads();
    for (int d = 128; d; d >>= 1) {
        if (t < d) red[t] += red[t + d];
        __syncthreads();
    }
    if (t == 0) g_bsum[which][b] = red[0];
}

__global__ void csr_bscan_kernel() {
    int which = blockIdx.x;
    int t = threadIdx.x;  // 64 threads
    int v = (t < SCAN_NBLK) ? g_bsum[which][t] : 0;
    int orig = v;
    #pragma unroll
    for (int d = 1; d < 64; d <<= 1) {
        int u = __shfl_up(v, d, 64);
        if (t >= d) v += u;
    }
    if (t < SCAN_NBLK) g_boff[which][t] = v - orig;
}

__global__ void csr_off_kernel(int total) {
    int which = blockIdx.y;
    const int* deg = which ? g_deg_out : g_deg_in;
    int* off = which ? g_off_out : g_off_in;
    int* cur = which ? g_cur_out : g_cur_in;
    int b = blockIdx.x;
    int t = threadIdx.x;
    const int per = SCAN_CHUNK / 256;  // 8
    int lo = b * SCAN_CHUNK + t * per;
    int d8[per];
    int s = 0;
    #pragma unroll
    for (int i = 0; i < per; ++i) {
        int idx = lo + i;
        d8[i] = (idx < N_NODES) ? deg[idx] : 0;
        s += d8[i];
    }
    __shared__ int part[256];
    part[t] = s;
    __syncthreads();
    for (int d = 1; d < 256; d <<= 1) {
        int add = (t >= d) ? part[t - d] : 0;
        __syncthreads();
        part[t] += add;
        __syncthreads();
    }
    int run = g_boff[which][b] + part[t] - s;
    #pragma unroll
    for (int i = 0; i < per; ++i) {
        int idx = lo + i;
        if (idx < N_NODES) {
            off[idx] = run;
            cur[idx] = run;
            run += d8[i];
        }
    }
    if (b == 0 && t == 0) off[N_NODES] = total;
}

// fill lists with (src, voc)
__global__ void csr_fill_kernel(const int* __restrict__ row, const int* __restrict__ col,
                                int E) {
    int e = blockIdx.x * 256 + threadIdx.x;
    if (e >= E) return;
    int r = row[e], c = col[e];
    int p = atomicAdd(&g_cur_in[c], 1);
    g_lst_in[p] = make_int2(r, g_evoc[e]);
    int q = atomicAdd(&g_cur_out[r], 1);
    g_lst_out[q] = make_int2(c, g_evoc[E + e]);
}

// ---------------- assemble Wcat^T for ALL layers (k x 256 x 128, bf16): [xi | xo] ----------------
__global__ void assemble_wcat_all(const float* __restrict__ Wgi, const float* __restrict__ Wgo) {
    int idx = blockIdx.x * 256 + threadIdx.x;  // 3*32768
    if (idx >= K_LAYERS * 32768) return;
    int k = idx >> 15;
    int rem = idx & 32767;
    int n = rem >> 7;
    int kd = rem & 127;
    float v = (n < 128) ? Wgi[(size_t)k * 16384 + kd * 128 + n]
                        : Wgo[(size_t)k * 16384 + kd * 128 + (n - 128)];
    g_WcatT[k][n * 128 + kd] = f2bf(v);
}

// ---- fused node GEMM via MFMA (swapped operands, LDS-staged coalesced output) ----
// XWx(bf16) = x@Wcat (waves 0-3), scal = x@QT^T (wave 4). 320 threads; grid ceil(M/64)
#define OS_LD 264  // padded row of out-stage LDS (256 + 8 ushorts -> 2-way bank alias only)
__global__ __launch_bounds__(320) void gemm_xw_mfma(int cur, int layer, unsigned int mask,
                                                    int M) {
    const ushort_t* __restrict__ hb = g_hb[cur];
    int m0 = blockIdx.x * 64;
    int t = threadIdx.x;
    int wave = t >> 6, lane = t & 63;
    __shared__ ushort_t As[64 * 128];   // 16 KB, XOR-swizzled: elem k ^= (row&7)<<3
    __shared__ ushort_t Os[64 * OS_LD]; // ~33 KB output stage

    for (int idx = t; idx < 1024; idx += 320) {
        int m = idx >> 4, c = idx & 15;  // row, 16B-chunk (8 elems)
        int gm = m0 + m;
        uint4 v = make_uint4(0u, 0u, 0u, 0u);
        if (gm < M) v = *(const uint4*)(hb + (size_t)gm * 128 + c * 8);
        *(uint4*)&As[m * 128 + ((c * 8) ^ ((m & 7) << 3))] = v;
    }
    __syncthreads();

    int lr = lane & 15, lk = lane >> 4;

    if (wave < 4) {
        int nbase = wave * 64;
        f32x4 acc[4][4];  // [nt][mt], D[n][m]
        #pragma unroll
        for (int i = 0; i < 4; ++i)
            #pragma unroll
            for (int j = 0; j < 4; ++j)
                acc[i][j] = (f32x4){0.f, 0.f, 0.f, 0.f};

        const ushort_t* Bbase = &g_WcatT[layer][0] + (size_t)nbase * 128;
        #pragma unroll
        for (int ks = 0; ks < 4; ++ks) {
            bf16x8 a[4], b[4];
            int ke = ks * 32 + lk * 8;
            #pragma unroll
            for (int mt = 0; mt < 4; ++mt) {
                int row = mt * 16 + lr;
                a[mt] = *(const bf16x8*)&As[row * 128 + (ke ^ ((row & 7) << 3))];
            }
            #pragma unroll
            for (int nt = 0; nt < 4; ++nt) {
                b[nt] = *(const bf16x8*)(Bbase + (size_t)(nt * 16 + lr) * 128 + ke);
            }
            #pragma unroll
            for (int nt = 0; nt < 4; ++nt)
                #pragma unroll
                for (int mt = 0; mt < 4; ++mt)
                    acc[nt][mt] = __builtin_amdgcn_mfma_f32_16x16x32_bf16(b[nt], a[mt], acc[nt][mt], 0, 0, 0);
        }

        // D[n][m]: lane holds row (m0+mt*16+lr), cols nbase+nt*16+lk*4 .. +3 -> LDS stage
        #pragma unroll
        for (int mt = 0; mt < 4; ++mt) {
            int mloc = mt * 16 + lr;
            #pragma unroll
            for (int nt = 0; nt < 4; ++nt) {
                int n0 = nbase + nt * 16 + lk * 4;
                f32x4 av = acc[nt][mt];
                uint2 pk;
                pk.x = ((unsigned int)f2bf(av[1]) << 16) | (unsigned int)f2bf(av[0]);
                pk.y = ((unsigned int)f2bf(av[3]) << 16) | (unsigned int)f2bf(av[2]);
                *(uint2*)&Os[mloc * OS_LD + n0] = pk;
            }
        }
    } else {
        const ushort_t* QT = &g_QT[layer][0][0];
        f32x4 acc[2][4];  // [nt][mt], D[qcol][m]
        #pragma unroll
        for (int i = 0; i < 2; ++i)
            #pragma unroll
            for (int j = 0; j < 4; ++j)
                acc[i][j] = (f32x4){0.f, 0.f, 0.f, 0.f};

        #pragma unroll
        for (int ks = 0; ks < 4; ++ks) {
            bf16x8 a[4], b[2];
            int ke = ks * 32 + lk * 8;
            #pragma unroll
            for (int mt = 0; mt < 4; ++mt) {
                int row = mt * 16 + lr;
                a[mt] = *(const bf16x8*)&As[row * 128 + (ke ^ ((row & 7) << 3))];
            }
            #pragma unroll
            for (int nt = 0; nt < 2; ++nt)
                b[nt] = *(const bf16x8*)&QT[(nt * 16 + lr) * 128 + ke];
            #pragma unroll
            for (int nt = 0; nt < 2; ++nt)
                #pragma unroll
                for (int mt = 0; mt < 4; ++mt)
                    acc[nt][mt] = __builtin_amdgcn_mfma_f32_16x16x32_bf16(b[nt], a[mt], acc[nt][mt], 0, 0, 0);
        }

        #pragma unroll
        for (int mt = 0; mt < 4; ++mt) {
            int gm = m0 + mt * 16 + lr;
            if (gm >= M) continue;
            #pragma unroll
            for (int nt = 0; nt < 2; ++nt) {
                #pragma unroll
                for (int r = 0; r < 4; ++r) {
                    int colc = nt * 16 + lk * 4 + r;
                    if ((mask >> colc) & 1u)
                        g_scal[(size_t)gm * 32 + colc] = acc[nt][mt][r];
                }
            }
        }
    }
    __syncthreads();
    // coalesced copy-out: 64 rows x 512B, fully sequential global stores
    for (int idx = t; idx < 64 * 32; idx += 320) {  // 32 uint4-chunks per row
        int m = idx >> 5, c8 = idx & 31;
        if (m0 + m < M)
            *(uint4*)&g_XWx_b[(size_t)(m0 + m) * 256 + c8 * 8] = *(uint4*)&Os[m * OS_LD + c8 * 8];
    }
}

// ------- fused aggregate + inline gate: ONE NODE PER 16-LANE GROUP, 2-way unrolled gather -------
__global__ __launch_bounds__(256) void aggregate_kernel(int cur, int k,
                                                        const float* __restrict__ bgi,
                                                        const float* __restrict__ bgo, int N) {
    int tid = threadIdx.x;
    int wv = tid >> 6;
    int lane = tid & 63;
    int grp = lane >> 4, li = lane & 15;
    int n = blockIdx.x * 16 + wv * 4 + grp;
    bool valid = n < N;

    int pin0 = 0, din = 0, pout0 = 0, dout = 0;
    float cin = 0.f, cout = 0.f;
    if (valid) {
        pin0 = g_off_in[n];  din = g_off_in[n + 1] - pin0;
        pout0 = g_off_out[n]; dout = g_off_out[n + 1] - pout0;
        const float* srow = g_scal + (size_t)n * 32;
        if (k == 0) {
            cin = srow[16]; cout = srow[24];
        } else if (k == 1) {
            cin = srow[18] + srow[19]; cout = srow[26] + srow[27];
        } else {
            cin = srow[20] + srow[21] + srow[22];
            cout = srow[28] + srow[29] + srow[30];
        }
    }
    int tot = din + dout;

    float acc[8];
    {
        float4 b1 = *(const float4*)(bgi + li * 8);
        float4 b2 = *(const float4*)(bgi + li * 8 + 4);
        float4 c1 = *(const float4*)(bgo + li * 8);
        float4 c2 = *(const float4*)(bgo + li * 8 + 4);
        uint4 xv = make_uint4(0u, 0u, 0u, 0u);
        if (valid) xv = *(const uint4*)(g_hb[cur] + (size_t)n * 128 + li * 8);
        acc[0] = bflo(xv.x) + b1.x + c1.x;
        acc[1] = bfhi(xv.x) + b1.y + c1.y;
        acc[2] = bflo(xv.y) + b1.z + c1.z;
        acc[3] = bfhi(xv.y) + b1.w + c1.w;
        acc[4] = bflo(xv.z) + b2.x + c2.x;
        acc[5] = bfhi(xv.z) + b2.y + c2.y;
        acc[6] = bflo(xv.w) + b2.z + c2.z;
        acc[7] = bfhi(xv.w) + b2.w + c2.w;
    }

    for (int base = 0; base < tot; base += 16) {
        int cnt = min(16, tot - base);
        float gate = 0.f;
        int sv = 0;
        if (li < cnt) {
            int q = base + li;
            int2 se;
            int dir;
            if (q < din) { se = g_lst_in[pin0 + q]; dir = 0; }
            else         { se = g_lst_out[pout0 + q - din]; dir = 1; }
            const float* arow = g_scal + (size_t)se.x * 32 + dir * 8;
            float asum;
            if (k == 0) asum = arow[0];
            else if (k == 1) asum = arow[2] + arow[3];
            else asum = arow[4] + arow[5] + arow[6];
            float s = g_bias[se.y][dir * 3 + k] + asum + (dir ? cout : cin);
            gate = 1.0f / (1.0f + __expf(-s));
            sv = se.x * 2 + dir;
        }
        int e = 0;
        for (; e + 2 <= cnt; e += 2) {
            float w0 = __shfl(gate, grp * 16 + e);
            int a0 = __shfl(sv, grp * 16 + e);
            float w1 = __shfl(gate, grp * 16 + e + 1);
            int a1 = __shfl(sv, grp * 16 + e + 1);
            uint4 p0 = *(const uint4*)(g_XWx_b + (size_t)(a0 >> 1) * 256 + (a0 & 1) * 128 + li * 8);
            uint4 p1 = *(const uint4*)(g_XWx_b + (size_t)(a1 >> 1) * 256 + (a1 & 1) * 128 + li * 8);
            acc[0] += w0 * bflo(p0.x);
            acc[1] += w0 * bfhi(p0.x);
            acc[2] += w0 * bflo(p0.y);
            acc[3] += w0 * bfhi(p0.y);
            acc[4] += w0 * bflo(p0.z);
            acc[5] += w0 * bfhi(p0.z);
            acc[6] += w0 * bflo(p0.w);
            acc[7] += w0 * bfhi(p0.w);
            acc[0] += w1 * bflo(p1.x);
            acc[1] += w1 * bfhi(p1.x);
            acc[2] += w1 * bflo(p1.y);
            acc[3] += w1 * bfhi(p1.y);
            acc[4] += w1 * bflo(p1.z);
            acc[5] += w1 * bfhi(p1.z);
            acc[6] += w1 * bflo(p1.w);
            acc[7] += w1 * bfhi(p1.w);
        }
        if (e < cnt) {
            float w0 = __shfl(gate, grp * 16 + e);
            int a0 = __shfl(sv, grp * 16 + e);
            uint4 p0 = *(const uint4*)(g_XWx_b + (size_t)(a0 >> 1) * 256 + (a0 & 1) * 128 + li * 8);
            acc[0] += w0 * bflo(p0.x);
            acc[1] += w0 * bfhi(p0.x);
            acc[2] += w0 * bflo(p0.y);
            acc[3] += w0 * bfhi(p0.y);
            acc[4] += w0 * bflo(p0.z);
            acc[5] += w0 * bfhi(p0.z);
            acc[6] += w0 * bflo(p0.w);
            acc[7] += w0 * bfhi(p0.w);
        }
    }

    if (valid) {
        uint4 pk;
        pk.x = ((unsigned int)f2bf(acc[1]) << 16) | (unsigned int)f2bf(acc[0]);
        pk.y = ((unsigned int)f2bf(acc[3]) << 16) | (unsigned int)f2bf(acc[2]);
        pk.z = ((unsigned int)f2bf(acc[5]) << 16) | (unsigned int)f2bf(acc[4]);
        pk.w = ((unsigned int)f2bf(acc[7]) << 16) | (unsigned int)f2bf(acc[6]);
        *(uint4*)(g_hb[cur ^ 1] + (size_t)n * 128 + li * 8) = pk;
    }
}

// ---------------- mean-pool partials (bf16 in, fp32 accumulate) ----------------
__global__ void pool_kernel(int fin, int side, const int* __restrict__ batch, int N) {
    const ushort_t* x = g_hb[fin];
    float* gsum = g_gsum[side];
    int n0 = blockIdx.x * 128;
    int d = threadIdx.x;  // 128 threads
    if (n0 >= N) return;
    int nend = min(n0 + 128, N);
    float acc = 0.f;
    int curg = batch[n0];
    for (int n = n0; n < nend; ++n) {
        int g = batch[n];
        if (g != curg) {
            atomicAdd(&gsum[curg * 128 + d], acc);
            acc = 0.f;
            curg = g;
        }
        acc += bf2f(x[(size_t)n * 128 + d]);
    }
    atomicAdd(&gsum[curg * 128 + d], acc);
}

__global__ void count_kernel(int side, const int* __restrict__ batch, int N) {
    int g = threadIdx.x;  // 128 threads
    int lo = 0, hi = N;
    while (lo < hi) { int mid = (lo + hi) >> 1; if (batch[mid] < g) lo = mid + 1; else hi = mid; }
    int a = lo;
    lo = 0; hi = N;
    while (lo < hi) { int mid = (lo + hi) >> 1; if (batch[mid] < g + 1) lo = mid + 1; else hi = mid; }
    g_cnt[side][g] = (float)(lo - a);
}

__global__ void zero_gsum_kernel() {
    int i = blockIdx.x * 256 + threadIdx.x;
    if (i < 2 * N_GRAPHS * NODE_DIM) ((float*)g_gsum)[i] = 0.f;
}

// ---------------- classifier ----------------
__global__ void hidden_kernel(const float* __restrict__ W0, const float* __restrict__ b0) {
    int g = blockIdx.x;
    int j = threadIdx.x;  // 128 x 128
    float inv_s = 1.0f / fmaxf(g_cnt[0][g], 1.0f);
    float inv_t = 1.0f / fmaxf(g_cnt[1][g], 1.0f);
    float acc = b0[j];
    for (int k = 0; k < 128; ++k) acc += g_gsum[0][g * 128 + k] * inv_s * W0[k * 128 + j];
    for (int k = 0; k < 128; ++k) acc += g_gsum[1][g * 128 + k] * inv_t * W0[(128 + k) * 128 + j];
    g_H[g * 128 + j] = fmaxf(acc, 0.f);
}

__global__ void loss_kernel(const float* __restrict__ W1, const float* __restrict__ b1,
                            const int* __restrict__ y, float* __restrict__ out) {
    int g = threadIdx.x;  // 128 threads
    float l0 = b1[0], l1 = b1[1];
    for (int j = 0; j < 128; ++j) {
        float hv = g_H[g * 128 + j];
        l0 += hv * W1[j * 2 + 0];
        l1 += hv * W1[j * 2 + 1];
    }
    float m = fmaxf(l0, l1);
    float lse = m + logf(expf(l0 - m) + expf(l1 - m));
    float ly = (y[g] == 0) ? l0 : l1;
    float c = -(ly - lse) * (1.0f / (float)N_GRAPHS);
    __shared__ float red[128];
    red[g] = c;
    __syncthreads();
    for (int s = 64; s; s >>= 1) {
        if (g < s) red[g] += red[g + s];
        __syncthreads();
    }
    if (g == 0) out[0] = red[0];
}

extern "C" void kernel_launch(void* const* d_in, const int* in_sizes, int n_in,
                              void* d_out, int out_size, void* d_ws, size_t ws_size,
                              hipStream_t stream) {
    const float* x_s      = (const float*)d_in[0];
    const float* x_t      = (const float*)d_in[1];
    const float* ea_s     = (const float*)d_in[2];
    const float* ea_t     = (const float*)d_in[3];
    const int*   ei_s     = (const int*)d_in[4];
    const int*   ei_t     = (const int*)d_in[5];
    const int*   batch_s  = (const int*)d_in[6];
    const int*   batch_t  = (const int*)d_in[7];
    const int*   y        = (const int*)d_in[8];
    const float* node_emb = (const float*)d_in[9];
    const float* edge_emb = (const float*)d_in[10];
    const float* W_in_0   = (const float*)d_in[11];
    const float* W_in_1   = (const float*)d_in[12];
    const float* W_out_0  = (const float*)d_in[13];
    const float* W_out_1  = (const float*)d_in[14];
    const float* Wg_in    = (const float*)d_in[15];
    const float* bg_in    = (const float*)d_in[16];
    const float* Wg_out   = (const float*)d_in[17];
    const float* bg_out   = (const float*)d_in[18];
    const float* cls_W0   = (const float*)d_in[19];
    const float* cls_b0   = (const float*)d_in[20];
    const float* cls_W1   = (const float*)d_in[21];
    const float* cls_b1   = (const float*)d_in[22];

    const int N = N_NODES, E = N_EDGES;
    static const unsigned int MASKS[3] = {MASK_J0, MASK_J1, MASK_J2};

    zero_gsum_kernel<<<(2 * N_GRAPHS * NODE_DIM + 255) / 256, 256, 0, stream>>>();
    zero_qt_kernel<<<(K_LAYERS * 32 * 128 + 255) / 256, 256, 0, stream>>>();
    setup_gates_kernel<<<6, 128, 0, stream>>>(W_in_0, W_in_1, W_out_0, W_out_1, edge_emb);
    assemble_wcat_all<<<(K_LAYERS * 32768 + 255) / 256, 256, 0, stream>>>(Wg_in, Wg_out);

    for (int side = 0; side < 2; ++side) {
        const float* xin   = side ? x_t : x_s;
        const float* eain  = side ? ea_t : ea_s;
        const int*   ei    = side ? ei_t : ei_s;
        const int*   batch = side ? batch_t : batch_s;
        const int* row = ei;
        const int* col = ei + E;

        node_embed_kernel<<<(N + 3) / 4, 256, 0, stream>>>(xin, node_emb, N);
        edge_voc_kernel<<<(2 * E + 255) / 256, 256, 0, stream>>>(eain, 2 * E);

        // ---- CSR build (once per side; edge_index constant across layers) ----
        csr_zero_kernel<<<(N + 255) / 256, 256, 0, stream>>>();
        csr_count_kernel<<<(E + 255) / 256, 256, 0, stream>>>(row, col, E);
        csr_bsum_kernel<<<dim3(SCAN_NBLK, 2), 256, 0, stream>>>();
        csr_bscan_kernel<<<2, 64, 0, stream>>>();
        csr_off_kernel<<<dim3(SCAN_NBLK, 2), 256, 0, stream>>>(E);
        csr_fill_kernel<<<(E + 255) / 256, 256, 0, stream>>>(row, col, E);

        int cur = 0;
        for (int k = 0; k < K_LAYERS; ++k) {
            gemm_xw_mfma<<<(N + 63) / 64, 320, 0, stream>>>(cur, k, MASKS[k], N);
            aggregate_kernel<<<(N + 15) / 16, 256, 0, stream>>>(
                cur, k, bg_in + (size_t)k * 128, bg_out + (size_t)k * 128, N);
            cur ^= 1;
        }
        pool_kernel<<<(N + 127) / 128, 128, 0, stream>>>(cur, side, batch, N);
        count_kernel<<<1, 128, 0, stream>>>(side, batch, N);
    }

    hidden_kernel<<<128, 128, 0, stream>>>(cls_W0, cls_b0);
    loss_kernel<<<1, 128, 0, stream>>>(cls_W1, cls_b1, y, (float*)d_out);
}